// Round 16
// baseline (2164.966 us; speedup 1.0000x reference)
//
#include <hip/hip_runtime.h>
#include <hip/hip_bf16.h>

#define BB 64
#define TT 32
#define VV 12000
#define EE 512
#define FF 2048
#define CDIM 128
#define HH 1024
#define LL 49
#define XKLEN 2688   /* E + F + C */
#define XGLEN 640    /* E + C : per-step gathered input */

typedef __attribute__((ext_vector_type(8))) short bf16x8;
typedef __attribute__((ext_vector_type(4))) float f32x4;

__device__ __forceinline__ unsigned short bf16_rn(float x) {
  unsigned u = __float_as_uint(x);
  u += 0x7FFFu + ((u >> 16) & 1u);
  return (unsigned short)(u >> 16);
}
__device__ __forceinline__ float bf16_tof(unsigned short h) {
  return __uint_as_float(((unsigned)h) << 16);
}
__device__ __forceinline__ void split2(float x, short& hi, short& lo) {
  unsigned short h = bf16_rn(x);
  float r = x - bf16_tof(h);
  hi = (short)h;
  lo = (short)bf16_rn(r);
}
__device__ __forceinline__ bf16x8 cvt8(const float* f) {
  bf16x8 o;
#pragma unroll
  for (int e = 0; e < 8; ++e) o[e] = (short)bf16_rn(f[e]);
  return o;
}

// ---------------------------------------------------------------------------
// D1: hU tile + partial scores. Grid 256 (XCD-swizzled: id=(bid&7)*32+bid>>3,
// nt=id>>2, mh=id&3). 16 b-rows per block. partS: [64 nt][64 b][49 l]
// ---------------------------------------------------------------------------
__global__ __launch_bounds__(256) void hupart_k(
    const short* __restrict__ hHi, const short* __restrict__ hLi,
    const short* __restrict__ attUt,   // [1024][1024] bf16 = att_U^T
    const float* __restrict__ featp,   // [B*L][1024] f32
    const float* __restrict__ att_v,
    float* __restrict__ partS)         // [64 nt][64 b][49 l]
{
  __shared__ float red[4][64][5];
  __shared__ float hu_s[16][17];
  __shared__ float av_s[16];
  const int tid = threadIdx.x;
  const int w = tid >> 6, lane = tid & 63;
  const int r = lane & 15, kg = lane >> 4;
  const int bid = blockIdx.x;
  const int id = (bid & 7) * 32 + (bid >> 3);
  const int nt = id >> 2, mh = id & 3;
  const int kb = w * 256;

  if (tid < 16) av_s[tid] = att_v[nt * 16 + tid];

  const short* wp  = attUt + (size_t)(nt * 16 + r) * HH + kb + kg * 8;
  const short* ap  = hHi + (size_t)(mh * 16 + r) * HH + kb + kg * 8;
  const short* alp = hLi + (size_t)(mh * 16 + r) * HH + kb + kg * 8;
  f32x4 acc = {};
#pragma unroll
  for (int k0 = 0; k0 < 256; k0 += 32) {
    bf16x8 bf = *(const bf16x8*)(wp + k0);
    bf16x8 af = *(const bf16x8*)(ap + k0);
    acc = __builtin_amdgcn_mfma_f32_16x16x32_bf16(af, bf, acc, 0, 0, 0);
    bf16x8 alf = *(const bf16x8*)(alp + k0);
    acc = __builtin_amdgcn_mfma_f32_16x16x32_bf16(alf, bf, acc, 0, 0, 0);
  }
#pragma unroll
  for (int q = 0; q < 4; ++q)
    red[w][lane][q] = acc[q];
  __syncthreads();

  {
    const int bl = tid >> 4, a = tid & 15;
    const int sl = (bl >> 2) * 16 + a;
    const int ii = bl & 3;
    hu_s[bl][a] = red[0][sl][ii] + red[1][sl][ii] + red[2][sl][ii] + red[3][sl][ii];
  }
  __syncthreads();

  for (int task = tid; task < 16 * LL; task += 256) {
    const int bl = task / LL, l = task - bl * LL;
    const int b = mh * 16 + bl;
    const float* fp = featp + ((size_t)b * LL + l) * HH + nt * 16;
    float s = 0.f;
#pragma unroll
    for (int a = 0; a < 16; ++a)
      s += tanhf(fp[a] + hu_s[bl][a]) * av_s[a];
    partS[(size_t)nt * 3136 + (size_t)mh * 784 + task] = s;
  }
}

// ---------------------------------------------------------------------------
// D2: softmax + ctx-weighted-sum + gates MFMA ([xg|h] segments) + LSTM.
// Grid 256 (XCD-swizzled). featCtx: [nt][3136][64]. h out to hall[t].
// ---------------------------------------------------------------------------
__global__ __launch_bounds__(256) void glstm3_k(
    const short* __restrict__ xgH, const short* __restrict__ xgL,  // [2048][640]
    const short* __restrict__ hHi, const short* __restrict__ hLi,  // [64][1024]
    const short* __restrict__ Wxg,      // [4096][640]
    const short* __restrict__ Whb,      // [4096][1024]
    const short* __restrict__ featCtx,  // [64][3136][64] bf16
    const float* __restrict__ partS,    // [64 nt][64 b][49 l]
    const float* __restrict__ bg,
    float* __restrict__ cbuf,
    short* __restrict__ hHo, short* __restrict__ hLo,
    float* __restrict__ w_out, int t)
{
  __shared__ float sw[16][52];
  __shared__ float ctx_p[2][16][72];
  __shared__ float red[3][64][17];
  const int tid = threadIdx.x;
  const int w = tid >> 6, lane = tid & 63;
  const int r = lane & 15, kg = lane >> 4;
  const int bid = blockIdx.x;
  const int id = (bid & 7) * 32 + (bid >> 3);
  const int nt = id >> 2, mq = id & 3;

  // Phase A: raw scores (coalesced nt-major reads)
  for (int idx = tid; idx < 16 * LL; idx += 256) {
    const float* ps = partS + (size_t)mq * 784 + idx;
    float s = 0.f;
#pragma unroll 8
    for (int a = 0; a < 64; ++a) s += ps[(size_t)a * 3136];
    sw[idx / LL][idx % LL] = s;
  }
  __syncthreads();
#pragma unroll
  for (int i = 0; i < 4; ++i) {
    const int bl = w * 4 + i;
    float v = (lane < LL) ? sw[bl][lane] : -1e30f;
    float m = v;
#pragma unroll
    for (int off = 32; off > 0; off >>= 1) m = fmaxf(m, __shfl_xor(m, off));
    float e = (lane < LL) ? expf(v - m) : 0.f;
    float s = e;
#pragma unroll
    for (int off = 32; off > 0; off >>= 1) s += __shfl_xor(s, off);
    float ww = e / s;
    if (lane < LL) {
      sw[bl][lane] = ww;
      if (nt == 0)
        w_out[((size_t)(mq * 16 + bl) * TT + t) * LL + lane] = ww;
    }
  }
  __syncthreads();

  // Phase B: ctx partials; 16B loads, 2-way l-split.
  {
    const int bl = tid >> 4, tsub = tid & 15;
    const int e8 = (tsub & 7) * 8, lpar = tsub >> 3;
    const size_t base =
        ((size_t)nt * 3136 + (size_t)(mq * 16 + bl) * LL) * 64 + e8;
    float s[8] = {};
    for (int l = lpar; l < LL; l += 2) {
      bf16x8 v = *(const bf16x8*)&featCtx[base + (size_t)l * 64];
      const float wl = sw[bl][l];
#pragma unroll
      for (int e = 0; e < 8; ++e)
        s[e] += wl * bf16_tof((unsigned short)v[e]);
    }
#pragma unroll
    for (int e = 0; e < 8; ++e)
      ctx_p[lpar][bl][e8 + e] = s[e];
  }

  // Phase C: gates MFMA over [xg(640) | h(1024)], K split 4 waves x 13 chunks
  const int brow = mq * 16 + r;
  const size_t xgrow = (size_t)t * 64 + brow;
  f32x4 acc0 = {}, acc1 = {}, acc2 = {}, acc3 = {};
#pragma unroll
  for (int c = 0; c < 13; ++c) {
    const int gk = (w * 13 + c) * 32;
    const short *a_h, *a_l, *w0p, *w1p, *w2p, *w3p;
    if (gk < XGLEN) {
      a_h = xgH + xgrow * XGLEN + gk + kg * 8;
      a_l = xgL + xgrow * XGLEN + gk + kg * 8;
      w0p = Wxg + (size_t)(0 * 1024 + nt * 16 + r) * XGLEN + gk + kg * 8;
      w1p = Wxg + (size_t)(1 * 1024 + nt * 16 + r) * XGLEN + gk + kg * 8;
      w2p = Wxg + (size_t)(2 * 1024 + nt * 16 + r) * XGLEN + gk + kg * 8;
      w3p = Wxg + (size_t)(3 * 1024 + nt * 16 + r) * XGLEN + gk + kg * 8;
    } else {
      const int hk = gk - XGLEN;
      a_h = hHi + (size_t)brow * HH + hk + kg * 8;
      a_l = hLi + (size_t)brow * HH + hk + kg * 8;
      w0p = Whb + (size_t)(0 * 1024 + nt * 16 + r) * HH + hk + kg * 8;
      w1p = Whb + (size_t)(1 * 1024 + nt * 16 + r) * HH + hk + kg * 8;
      w2p = Whb + (size_t)(2 * 1024 + nt * 16 + r) * HH + hk + kg * 8;
      w3p = Whb + (size_t)(3 * 1024 + nt * 16 + r) * HH + hk + kg * 8;
    }
    bf16x8 af  = *(const bf16x8*)a_h;
    bf16x8 alf = *(const bf16x8*)a_l;
    bf16x8 b0 = *(const bf16x8*)w0p;
    acc0 = __builtin_amdgcn_mfma_f32_16x16x32_bf16(af,  b0, acc0, 0, 0, 0);
    acc0 = __builtin_amdgcn_mfma_f32_16x16x32_bf16(alf, b0, acc0, 0, 0, 0);
    bf16x8 b1 = *(const bf16x8*)w1p;
    acc1 = __builtin_amdgcn_mfma_f32_16x16x32_bf16(af,  b1, acc1, 0, 0, 0);
    acc1 = __builtin_amdgcn_mfma_f32_16x16x32_bf16(alf, b1, acc1, 0, 0, 0);
    bf16x8 b2 = *(const bf16x8*)w2p;
    acc2 = __builtin_amdgcn_mfma_f32_16x16x32_bf16(af,  b2, acc2, 0, 0, 0);
    acc2 = __builtin_amdgcn_mfma_f32_16x16x32_bf16(alf, b2, acc2, 0, 0, 0);
    bf16x8 b3 = *(const bf16x8*)w3p;
    acc3 = __builtin_amdgcn_mfma_f32_16x16x32_bf16(af,  b3, acc3, 0, 0, 0);
    acc3 = __builtin_amdgcn_mfma_f32_16x16x32_bf16(alf, b3, acc3, 0, 0, 0);
  }

  if (w != 0) {
#pragma unroll
    for (int q = 0; q < 4; ++q) {
      red[w - 1][lane][0 * 4 + q] = acc0[q];
      red[w - 1][lane][1 * 4 + q] = acc1[q];
      red[w - 1][lane][2 * 4 + q] = acc2[q];
      red[w - 1][lane][3 * 4 + q] = acc3[q];
    }
  }
  __syncthreads();
  if (w == 0) {
    const int j = nt * 16 + r;
    const float b0 = bg[j], b1 = bg[1024 + j], b2 = bg[2048 + j], b3 = bg[3072 + j];
#pragma unroll
    for (int q = 0; q < 4; ++q) {
      const int bl = kg * 4 + q;
      float gi = acc0[q] + b0 + ctx_p[0][bl][0 * 16 + r] + ctx_p[1][bl][0 * 16 + r];
      float gf = acc1[q] + b1 + ctx_p[0][bl][1 * 16 + r] + ctx_p[1][bl][1 * 16 + r];
      float gg = acc2[q] + b2 + ctx_p[0][bl][2 * 16 + r] + ctx_p[1][bl][2 * 16 + r];
      float go = acc3[q] + b3 + ctx_p[0][bl][3 * 16 + r] + ctx_p[1][bl][3 * 16 + r];
#pragma unroll
      for (int p = 0; p < 3; ++p) {
        gi += red[p][lane][0 * 4 + q];
        gf += red[p][lane][1 * 4 + q];
        gg += red[p][lane][2 * 4 + q];
        go += red[p][lane][3 * 4 + q];
      }
      const int b = mq * 16 + bl;
      float si = 1.f / (1.f + expf(-gi));
      float sf = 1.f / (1.f + expf(-gf));
      float so = 1.f / (1.f + expf(-go));
      const size_t ci = (size_t)b * HH + j;
      float cc = sf * cbuf[ci] + si * tanhf(gg);
      float hh = so * tanhf(cc);
      cbuf[ci] = cc;
      short hi, lo; split2(hh, hi, lo);
      hHo[ci] = hi;
      hLo[ci] = lo;
    }
  }
}

// ---------------------------------------------------------------------------
// Generic LDS-tiled GEMM: out = A[M,K] @ W[N,K]^T. 128x128 tile, BK=32.
// OUTMODE: 0 = f32 row-major, 2 = bf16 ctx-remap
// ---------------------------------------------------------------------------
template<int OUTMODE>
__global__ __launch_bounds__(256) void tgemm_k(
    const short* __restrict__ A, const short* __restrict__ Wb,
    float* __restrict__ outf, short* __restrict__ outb,
    int M, int N, int K, int ldo)
{
  __shared__ short lA[128 * 40];
  __shared__ short lW[128 * 40];
  const int tid = threadIdx.x;
  const int w = tid >> 6, lane = tid & 63;
  const int r = lane & 15, kg = lane >> 4;
  const int m0 = blockIdx.x * 128;
  const int n0 = blockIdx.y * 128;
  const int srow = tid >> 2, scol = (tid & 3) * 8;

  f32x4 acc[2][8] = {};
  for (int k0 = 0; k0 < K; k0 += 32) {
    __syncthreads();
#pragma unroll
    for (int j = 0; j < 2; ++j) {
      const int row = j * 64 + srow;
      int ar = m0 + row; if (ar >= M) ar = M - 1;
      int wr = n0 + row; if (wr >= N) wr = N - 1;
      bf16x8 va = *(const bf16x8*)&A[(size_t)ar * K + k0 + scol];
      bf16x8 vw = *(const bf16x8*)&Wb[(size_t)wr * K + k0 + scol];
      *(bf16x8*)&lA[row * 40 + scol] = va;
      *(bf16x8*)&lW[row * 40 + scol] = vw;
    }
    __syncthreads();
    bf16x8 a0 = *(const bf16x8*)&lA[(w * 32 +  0 + r) * 40 + kg * 8];
    bf16x8 a1 = *(const bf16x8*)&lA[(w * 32 + 16 + r) * 40 + kg * 8];
#pragma unroll
    for (int nf = 0; nf < 8; ++nf) {
      bf16x8 wf = *(const bf16x8*)&lW[(nf * 16 + r) * 40 + kg * 8];
      acc[0][nf] = __builtin_amdgcn_mfma_f32_16x16x32_bf16(a0, wf, acc[0][nf], 0, 0, 0);
      acc[1][nf] = __builtin_amdgcn_mfma_f32_16x16x32_bf16(a1, wf, acc[1][nf], 0, 0, 0);
    }
  }
#pragma unroll
  for (int nf = 0; nf < 8; ++nf) {
    const int col = n0 + nf * 16 + r;
    if (col < N) {
#pragma unroll
      for (int mf = 0; mf < 2; ++mf)
#pragma unroll
        for (int q = 0; q < 4; ++q) {
          const int grow = m0 + w * 32 + mf * 16 + kg * 4 + q;
          if (grow < M) {
            if (OUTMODE == 0) {
              outf[(size_t)grow * ldo + col] = acc[mf][nf][q];
            } else {
              const int gate = col >> 10, ntc = (col >> 4) & 63, jj = col & 15;
              outb[((size_t)ntc * 3136 + grow) * 64 + gate * 16 + jj] =
                  (short)bf16_rn(acc[mf][nf][q]);
            }
          }
        }
    }
  }
}

// ---------------------------------------------------------------------------
// Batched fc GEMM, LDS-staged 128x128 tile. Grid (16, 94).
// ---------------------------------------------------------------------------
__global__ __launch_bounds__(256) void bgemm_k(
    const short* __restrict__ Ah, const short* __restrict__ Al,
    const short* __restrict__ Wb, const float* __restrict__ bias,
    float* __restrict__ outs)
{
  __shared__ short lAh[128 * 40];
  __shared__ short lAl[128 * 40];
  __shared__ short lW [128 * 40];
  const int tid = threadIdx.x;
  const int w = tid >> 6, lane = tid & 63;
  const int r = lane & 15, kg = lane >> 4;
  const int m0 = blockIdx.x * 128;
  const int n0 = blockIdx.y * 128;
  const int srow = tid >> 2, scol = (tid & 3) * 8;

  f32x4 acc[2][8] = {};
  for (int k0 = 0; k0 < HH; k0 += 32) {
    __syncthreads();
#pragma unroll
    for (int j = 0; j < 2; ++j) {
      const int row = j * 64 + srow;
      bf16x8 va = *(const bf16x8*)&Ah[(size_t)(m0 + row) * HH + k0 + scol];
      bf16x8 vl = *(const bf16x8*)&Al[(size_t)(m0 + row) * HH + k0 + scol];
      int wr = n0 + row; if (wr >= VV) wr = VV - 1;
      bf16x8 vw = *(const bf16x8*)&Wb[(size_t)wr * HH + k0 + scol];
      *(bf16x8*)&lAh[row * 40 + scol] = va;
      *(bf16x8*)&lAl[row * 40 + scol] = vl;
      *(bf16x8*)&lW [row * 40 + scol] = vw;
    }
    __syncthreads();
    bf16x8 ah0 = *(const bf16x8*)&lAh[(w * 32 +  0 + r) * 40 + kg * 8];
    bf16x8 ah1 = *(const bf16x8*)&lAh[(w * 32 + 16 + r) * 40 + kg * 8];
    bf16x8 al0 = *(const bf16x8*)&lAl[(w * 32 +  0 + r) * 40 + kg * 8];
    bf16x8 al1 = *(const bf16x8*)&lAl[(w * 32 + 16 + r) * 40 + kg * 8];
#pragma unroll
    for (int nf = 0; nf < 8; ++nf) {
      bf16x8 wf = *(const bf16x8*)&lW[(nf * 16 + r) * 40 + kg * 8];
      acc[0][nf] = __builtin_amdgcn_mfma_f32_16x16x32_bf16(ah0, wf, acc[0][nf], 0, 0, 0);
      acc[0][nf] = __builtin_amdgcn_mfma_f32_16x16x32_bf16(al0, wf, acc[0][nf], 0, 0, 0);
      acc[1][nf] = __builtin_amdgcn_mfma_f32_16x16x32_bf16(ah1, wf, acc[1][nf], 0, 0, 0);
      acc[1][nf] = __builtin_amdgcn_mfma_f32_16x16x32_bf16(al1, wf, acc[1][nf], 0, 0, 0);
    }
  }
#pragma unroll
  for (int nf = 0; nf < 8; ++nf) {
    const int colv = n0 + nf * 16 + r;
    if (colv < VV) {
      const float bv = bias[colv];
#pragma unroll
      for (int mf = 0; mf < 2; ++mf)
#pragma unroll
        for (int q = 0; q < 4; ++q) {
          const int grow = m0 + w * 32 + mf * 16 + kg * 4 + q;  // = t*64 + b
          const int tt = grow >> 6, b = grow & 63;
          outs[((size_t)b * TT + tt) * VV + colv] = acc[mf][nf][q] + bv;
        }
    }
  }
}

// ---------------------------------------------------------------------------
// MFMA GEMM used in one-time prep (h0, c0).
// ---------------------------------------------------------------------------
template<bool TWOPASS, bool SPLITOUT, int MT>
__global__ __launch_bounds__(256) void mgemm_k(
    const short* __restrict__ Ah, const short* __restrict__ Al, int lda,
    const short* __restrict__ Wb, int ldw,
    const float* __restrict__ bias,
    float* __restrict__ C, int ldc,
    short* __restrict__ Ch, short* __restrict__ Cl, int ldch,
    int N, int K)
{
  const int tid = threadIdx.x;
  const int w = tid >> 6, l = tid & 63;
  const int r = l & 15, kg = l >> 4;
  const int m0 = blockIdx.y * 64;
  const int nslice = (MT == 4) ? w : (w >> 1);
  const int mbase  = (MT == 4) ? 0 : ((w & 1) * 2);
  const int n0 = blockIdx.x * (MT * 16) + nslice * 16;
  const int nrow = n0 + r;
  const int nclmp = nrow < N ? nrow : N - 1;
  const short* wp  = Wb + (size_t)nclmp * ldw + kg * 8;
  const short* ap  = Ah + (size_t)(m0 + mbase * 16 + r) * lda + kg * 8;
  const short* alp = TWOPASS ? (Al + (size_t)(m0 + mbase * 16 + r) * lda + kg * 8)
                             : nullptr;
  f32x4 acc[MT] = {};
  for (int k0 = 0; k0 < K; k0 += 32) {
    bf16x8 bf = *(const bf16x8*)(wp + k0);
#pragma unroll
    for (int m = 0; m < MT; ++m) {
      bf16x8 af = *(const bf16x8*)(ap + (size_t)(16 * m) * lda + k0);
      acc[m] = __builtin_amdgcn_mfma_f32_16x16x32_bf16(af, bf, acc[m], 0, 0, 0);
      if (TWOPASS) {
        bf16x8 alf = *(const bf16x8*)(alp + (size_t)(16 * m) * lda + k0);
        acc[m] = __builtin_amdgcn_mfma_f32_16x16x32_bf16(alf, bf, acc[m], 0, 0, 0);
      }
    }
  }
  if (nrow < N) {
    float bv = bias ? bias[nrow] : 0.f;
#pragma unroll
    for (int m = 0; m < MT; ++m) {
#pragma unroll
      for (int q = 0; q < 4; ++q) {
        int mm = m0 + (mbase + m) * 16 + kg * 4 + q;
        float v = acc[m][q] + bv;
        if (SPLITOUT) {
          short hi, lo; split2(v, hi, lo);
          Ch[(size_t)mm * ldch + nrow] = hi;
          Cl[(size_t)mm * ldch + nrow] = lo;
        } else {
          C[(size_t)mm * ldc + nrow] = v;
        }
      }
    }
  }
}

__global__ __launch_bounds__(256) void transpose_split_k(
    const float* __restrict__ in, short* __restrict__ out, int R, int C)
{
  __shared__ float tile[32][33];
  int bc = blockIdx.x * 32, br = blockIdx.y * 32;
  int tx = threadIdx.x & 31, ty4 = (threadIdx.x >> 5) << 2;
#pragma unroll
  for (int i = 0; i < 4; ++i) {
    int r = br + ty4 + i, c = bc + tx;
    tile[ty4 + i][tx] = (r < R && c < C) ? in[(size_t)r * C + c] : 0.f;
  }
  __syncthreads();
#pragma unroll
  for (int i = 0; i < 4; ++i) {
    int oc = bc + ty4 + i, orr = br + tx;
    if (oc < C && orr < R) out[(size_t)oc * R + orr] = (short)bf16_rn(tile[tx][ty4 + i]);
  }
}

// ---------------------------------------------------------------------------
// Fused elementwise prep, 8-wide vectorized. Every segment boundary and every
// row stride touched is 8-aligned (checked: 512/640/2048/2688 splits).
// ---------------------------------------------------------------------------
#define S_FEATB   6422528ULL                       /* 64*49*2048      */
#define C1  (S_FEATB)
#define C2  (C1 + 12288000ULL)                     /* fc_W 12000*1024 */
#define C3  (C2 + 4194304ULL)                      /* W_hh 4096*1024  */
#define C4  (C3 + 2097152ULL)                      /* Wh0 1024*2048   */
#define C5  (C4 + 2097152ULL)                      /* Wc0 1024*2048   */
#define C6  (C5 + 2621440ULL)                      /* Wxg 4096*640    */
#define C7  (C6 + 8388608ULL)                      /* Wctx 4096*2048  */
#define C8  (C7 + 1310720ULL)                      /* xg 2048*640     */
#define C9  (C8 + 4096ULL)                         /* bg              */
#define C10 (C9 + 131072ULL)                       /* mean 64*2048    */

__global__ __launch_bounds__(256) void prep_k(
    const float* __restrict__ features, const float* __restrict__ fc_W,
    const float* __restrict__ W_hh, const float* __restrict__ Wh0,
    const float* __restrict__ Wc0, const float* __restrict__ W_ih,
    const int* __restrict__ captions, const float* __restrict__ emb,
    const float* __restrict__ cat,
    const float* __restrict__ b_ih, const float* __restrict__ b_hh,
    short* __restrict__ featb, short* __restrict__ fcWb,
    short* __restrict__ Whb, short* __restrict__ Wh0b,
    short* __restrict__ Wc0b, short* __restrict__ Wxg,
    short* __restrict__ Wctxb, short* __restrict__ xgH,
    short* __restrict__ xgL, float* __restrict__ bg,
    short* __restrict__ mfb)
{
  const size_t stride = (size_t)gridDim.x * 256;
  for (size_t ii = (size_t)blockIdx.x * 256 + threadIdx.x; ii < (C10 >> 3);
       ii += stride) {
    const size_t i = ii << 3;
    float f[8];
    if (i < C1) {
      *(float4*)&f[0] = *(const float4*)&features[i];
      *(float4*)&f[4] = *(const float4*)&features[i + 4];
      *(bf16x8*)&featb[i] = cvt8(f);
    } else if (i < C2) {
      const size_t j = i - C1;
      *(float4*)&f[0] = *(const float4*)&fc_W[j];
      *(float4*)&f[4] = *(const float4*)&fc_W[j + 4];
      *(bf16x8*)&fcWb[j] = cvt8(f);
    } else if (i < C3) {
      const size_t j = i - C2;
      *(float4*)&f[0] = *(const float4*)&W_hh[j];
      *(float4*)&f[4] = *(const float4*)&W_hh[j + 4];
      *(bf16x8*)&Whb[j] = cvt8(f);
    } else if (i < C4) {
      const size_t j = i - C3;
      *(float4*)&f[0] = *(const float4*)&Wh0[j];
      *(float4*)&f[4] = *(const float4*)&Wh0[j + 4];
      *(bf16x8*)&Wh0b[j] = cvt8(f);
    } else if (i < C5) {
      const size_t j = i - C4;
      *(float4*)&f[0] = *(const float4*)&Wc0[j];
      *(float4*)&f[4] = *(const float4*)&Wc0[j + 4];
      *(bf16x8*)&Wc0b[j] = cvt8(f);
    } else if (i < C6) {
      const size_t j = i - C5;
      const int n = (int)(j / XGLEN), k = (int)(j % XGLEN);
      const int ks = (k < EE) ? k : (EE + FF + (k - EE));
      const float* src = &W_ih[(size_t)n * XKLEN + ks];
      *(float4*)&f[0] = *(const float4*)&src[0];
      *(float4*)&f[4] = *(const float4*)&src[4];
      *(bf16x8*)&Wxg[j] = cvt8(f);
    } else if (i < C7) {
      const size_t j = i - C6;
      const int n = (int)(j / FF), k = (int)(j % FF);
      const float* src = &W_ih[(size_t)n * XKLEN + EE + k];
      *(float4*)&f[0] = *(const float4*)&src[0];
      *(float4*)&f[4] = *(const float4*)&src[4];
      *(bf16x8*)&Wctxb[j] = cvt8(f);
    } else if (i < C8) {
      const size_t j = i - C7;
      const int row = (int)(j / XGLEN), k = (int)(j % XGLEN);
      const int t = row >> 6, b = row & 63;
      const float* src;
      if (k < EE) {
        const int cap = captions[b * TT + t];
        src = &emb[(size_t)cap * EE + k];
      } else {
        src = &cat[(size_t)b * CDIM + (k - EE)];
      }
      *(float4*)&f[0] = *(const float4*)&src[0];
      *(float4*)&f[4] = *(const float4*)&src[4];
      bf16x8 hi8, lo8;
#pragma unroll
      for (int e = 0; e < 8; ++e) {
        short h, l2; split2(f[e], h, l2);
        hi8[e] = h; lo8[e] = l2;
      }
      *(bf16x8*)&xgH[j] = hi8;
      *(bf16x8*)&xgL[j] = lo8;
    } else if (i < C9) {
      const size_t j = i - C8;
      float4 a0 = *(const float4*)&b_ih[j];
      float4 a1 = *(const float4*)&b_ih[j + 4];
      float4 c0 = *(const float4*)&b_hh[j];
      float4 c1 = *(const float4*)&b_hh[j + 4];
      float4 o0 = make_float4(a0.x + c0.x, a0.y + c0.y, a0.z + c0.z, a0.w + c0.w);
      float4 o1 = make_float4(a1.x + c1.x, a1.y + c1.y, a1.z + c1.z, a1.w + c1.w);
      *(float4*)&bg[j] = o0;
      *(float4*)&bg[j + 4] = o1;
    } else {
      const size_t j = i - C9;
      const int b = (int)(j >> 11), f0 = (int)(j & 2047);
      float s[8] = {};
      for (int l = 0; l < LL; ++l) {
        const float* src = &features[((size_t)b * LL + l) * FF + f0];
        float4 u0 = *(const float4*)&src[0];
        float4 u1 = *(const float4*)&src[4];
        s[0] += u0.x; s[1] += u0.y; s[2] += u0.z; s[3] += u0.w;
        s[4] += u1.x; s[5] += u1.y; s[6] += u1.z; s[7] += u1.w;
      }
#pragma unroll
      for (int e = 0; e < 8; ++e) s[e] *= (1.f / 49.f);
      *(bf16x8*)&mfb[j] = cvt8(s);
    }
  }
}

extern "C" void kernel_launch(void* const* d_in, const int* in_sizes, int n_in,
                              void* d_out, int out_size, void* d_ws, size_t ws_size,
                              hipStream_t stream) {
  const int*   captions = (const int*)  d_in[0];
  const float* features = (const float*)d_in[1];
  const float* category = (const float*)d_in[2];
  const float* emb      = (const float*)d_in[3];
  const float* W_ih     = (const float*)d_in[4];
  const float* b_ih     = (const float*)d_in[5];
  const float* W_hh     = (const float*)d_in[6];
  const float* b_hh     = (const float*)d_in[7];
  const float* fc_W     = (const float*)d_in[8];
  const float* fc_b     = (const float*)d_in[9];
  const float* Wh0      = (const float*)d_in[10];
  const float* bh0      = (const float*)d_in[11];
  const float* Wc0      = (const float*)d_in[12];
  const float* bc0      = (const float*)d_in[13];
  const float* att_W    = (const float*)d_in[14];
  const float* att_U    = (const float*)d_in[15];
  const float* att_v    = (const float*)d_in[16];

  float* outs  = (float*)d_out;
  float* w_out = outs + (size_t)BB * TT * VV;

  char* p = (char*)d_ws;
  auto alloc = [&](size_t bytes) {
    char* q = p; p += (bytes + 255) & ~(size_t)255; return q;
  };
  short* attUt  = (short*)alloc((size_t)HH * HH * 2);
  short* attWt  = (short*)alloc((size_t)HH * FF * 2);
  short* featb  = (short*)alloc((size_t)BB * LL * FF * 2);   // prep only; reused as hall
  short* fcWb   = (short*)alloc((size_t)VV * HH * 2);
  short* Wctxb  = (short*)alloc((size_t)4096 * FF * 2);
  short* Whb    = (short*)alloc((size_t)4096 * HH * 2);
  short* Wxg    = (short*)alloc((size_t)4096 * XGLEN * 2);
  short* Wh0b   = (short*)alloc((size_t)HH * FF * 2);
  short* Wc0b   = (short*)alloc((size_t)HH * FF * 2);
  short* mfb    = (short*)alloc((size_t)BB * FF * 2);
  short* h0H    = (short*)alloc((size_t)BB * HH * 2);
  short* h0L    = (short*)alloc((size_t)BB * HH * 2);
  short* xgH    = (short*)alloc((size_t)2048 * XGLEN * 2);
  short* xgL    = (short*)alloc((size_t)2048 * XGLEN * 2);
  float* featp  = (float*)alloc((size_t)BB * LL * HH * 4);
  short* featCtx= (short*)alloc((size_t)64 * 3136 * 64 * 2);
  float* cbuf   = (float*)alloc((size_t)BB * HH * 4);
  float* partS  = (float*)alloc((size_t)64 * 3136 * 4);
  float* bg     = (float*)alloc(4096 * 4);
  // h history (= h(t) for t=0..31) aliases featb (dead after prep GEMMs).
  short* hallH = featb;
  short* hallL = featb + (size_t)TT * BB * HH;

  // ---- one-time prep ----
  prep_k<<<2048, 256, 0, stream>>>(
      features, fc_W, W_hh, Wh0, Wc0, W_ih, captions, emb, category,
      b_ih, b_hh,
      featb, fcWb, Whb, Wh0b, Wc0b, Wxg, Wctxb, xgH, xgL, bg, mfb);
  transpose_split_k<<<dim3(32, 32), 256, 0, stream>>>(att_U, attUt, HH, HH);
  transpose_split_k<<<dim3(32, 64), 256, 0, stream>>>(att_W, attWt, FF, HH);

  // h0 / c0
  mgemm_k<false, true, 2><<<dim3(32, 1), 256, 0, stream>>>(
      mfb, nullptr, FF, Wh0b, FF, bh0,
      nullptr, 0, h0H, h0L, HH, HH, FF);
  mgemm_k<false, false, 2><<<dim3(32, 1), 256, 0, stream>>>(
      mfb, nullptr, FF, Wc0b, FF, bc0,
      cbuf, HH, nullptr, nullptr, 0, HH, FF);
  // featp = features @ att_W   (fp32 out, [3136][1024])
  tgemm_k<0><<<dim3(25, 8), 256, 0, stream>>>(
      featb, attWt, featp, nullptr, BB * LL, HH, FF, HH);
  // featCtx = features @ W_ih_ctx^T  (bf16, remapped to [64 nt][3136][64])
  tgemm_k<2><<<dim3(25, 32), 256, 0, stream>>>(
      featb, Wctxb, nullptr, featCtx, BB * LL, 4096, FF, 0);

  // ---- timestep loop: 2 dispatches per step ----
  for (int t = 0; t < TT; ++t) {
    const short* hHi = (t == 0) ? h0H : hallH + (size_t)(t - 1) * BB * HH;
    const short* hLi = (t == 0) ? h0L : hallL + (size_t)(t - 1) * BB * HH;
    hupart_k<<<256, 256, 0, stream>>>(
        hHi, hLi, attUt, featp, att_v, partS);
    glstm3_k<<<256, 256, 0, stream>>>(
        xgH, xgL, hHi, hLi, Wxg, Whb, featCtx, partS, bg, cbuf,
        hallH + (size_t)t * BB * HH, hallL + (size_t)t * BB * HH, w_out, t);
  }

  // ---- deferred batched fc ----
  bgemm_k<<<dim3(16, 94), 256, 0, stream>>>(hallH, hallL, fcWb, fc_b, outs);
}

// Round 17
// 1947.963 us; speedup vs baseline: 1.1114x; 1.1114x over previous
//
#include <hip/hip_runtime.h>
#include <hip/hip_bf16.h>

#define BB 64
#define TT 32
#define VV 12000
#define EE 512
#define FF 2048
#define CDIM 128
#define HH 1024
#define LL 49
#define XKLEN 2688   /* E + F + C */
#define XGLEN 640    /* E + C : per-step gathered input */

typedef __attribute__((ext_vector_type(8))) short bf16x8;
typedef __attribute__((ext_vector_type(4))) float f32x4;

__device__ __forceinline__ unsigned short bf16_rn(float x) {
  unsigned u = __float_as_uint(x);
  u += 0x7FFFu + ((u >> 16) & 1u);
  return (unsigned short)(u >> 16);
}
__device__ __forceinline__ float bf16_tof(unsigned short h) {
  return __uint_as_float(((unsigned)h) << 16);
}
__device__ __forceinline__ void split2(float x, short& hi, short& lo) {
  unsigned short h = bf16_rn(x);
  float r = x - bf16_tof(h);
  hi = (short)h;
  lo = (short)bf16_rn(r);
}
__device__ __forceinline__ bf16x8 cvt8(const float* f) {
  bf16x8 o;
#pragma unroll
  for (int e = 0; e < 8; ++e) o[e] = (short)bf16_rn(f[e]);
  return o;
}

// ---------------------------------------------------------------------------
// D1: hU tile + partial scores. Grid 256 (XCD-swizzled: id=(bid&7)*32+bid>>3,
// nt=id>>2, mh=id&3). 16 b-rows per block. partS: [64 nt][64 b][49 l]
// featpB: [64 nt][3136 row][16 a] bf16 (dense per-block slab)
// ---------------------------------------------------------------------------
__global__ __launch_bounds__(256) void hupart_k(
    const short* __restrict__ hHi, const short* __restrict__ hLi,
    const short* __restrict__ attUt,   // [1024][1024] bf16 = att_U^T
    const short* __restrict__ featpB,  // [64][3136][16] bf16
    const float* __restrict__ att_v,
    float* __restrict__ partS)         // [64 nt][64 b][49 l]
{
  __shared__ float red[4][64][5];
  __shared__ float hu_s[16][17];
  __shared__ float av_s[16];
  const int tid = threadIdx.x;
  const int w = tid >> 6, lane = tid & 63;
  const int r = lane & 15, kg = lane >> 4;
  const int bid = blockIdx.x;
  const int id = (bid & 7) * 32 + (bid >> 3);
  const int nt = id >> 2, mh = id & 3;
  const int kb = w * 256;

  if (tid < 16) av_s[tid] = att_v[nt * 16 + tid];

  const short* wp  = attUt + (size_t)(nt * 16 + r) * HH + kb + kg * 8;
  const short* ap  = hHi + (size_t)(mh * 16 + r) * HH + kb + kg * 8;
  const short* alp = hLi + (size_t)(mh * 16 + r) * HH + kb + kg * 8;
  f32x4 acc = {};
#pragma unroll
  for (int k0 = 0; k0 < 256; k0 += 32) {
    bf16x8 bf = *(const bf16x8*)(wp + k0);
    bf16x8 af = *(const bf16x8*)(ap + k0);
    acc = __builtin_amdgcn_mfma_f32_16x16x32_bf16(af, bf, acc, 0, 0, 0);
    bf16x8 alf = *(const bf16x8*)(alp + k0);
    acc = __builtin_amdgcn_mfma_f32_16x16x32_bf16(alf, bf, acc, 0, 0, 0);
  }
#pragma unroll
  for (int q = 0; q < 4; ++q)
    red[w][lane][q] = acc[q];
  __syncthreads();

  {
    const int bl = tid >> 4, a = tid & 15;
    const int sl = (bl >> 2) * 16 + a;
    const int ii = bl & 3;
    hu_s[bl][a] = red[0][sl][ii] + red[1][sl][ii] + red[2][sl][ii] + red[3][sl][ii];
  }
  __syncthreads();

  for (int task = tid; task < 16 * LL; task += 256) {
    const int bl = task / LL, l = task - bl * LL;
    const int b = mh * 16 + bl;
    const short* fp = featpB + ((size_t)nt * 3136 + (size_t)b * LL + l) * 16;
    bf16x8 v0 = *(const bf16x8*)&fp[0];
    bf16x8 v1 = *(const bf16x8*)&fp[8];
    float s = 0.f;
#pragma unroll
    for (int a = 0; a < 8; ++a)
      s += tanhf(bf16_tof((unsigned short)v0[a]) + hu_s[bl][a]) * av_s[a];
#pragma unroll
    for (int a = 0; a < 8; ++a)
      s += tanhf(bf16_tof((unsigned short)v1[a]) + hu_s[bl][8 + a]) * av_s[8 + a];
    partS[(size_t)nt * 3136 + (size_t)mh * 784 + task] = s;
  }
}

// ---------------------------------------------------------------------------
// D2: softmax + ctx-weighted-sum + gates MFMA ([xg|h] segments) + LSTM.
// Grid 256 (XCD-swizzled). featCtx: [nt][3136][64]. h out to hall[t].
// ---------------------------------------------------------------------------
__global__ __launch_bounds__(256) void glstm3_k(
    const short* __restrict__ xgH, const short* __restrict__ xgL,  // [2048][640]
    const short* __restrict__ hHi, const short* __restrict__ hLi,  // [64][1024]
    const short* __restrict__ Wxg,      // [4096][640]
    const short* __restrict__ Whb,      // [4096][1024]
    const short* __restrict__ featCtx,  // [64][3136][64] bf16
    const float* __restrict__ partS,    // [64 nt][64 b][49 l]
    const float* __restrict__ bg,
    float* __restrict__ cbuf,
    short* __restrict__ hHo, short* __restrict__ hLo,
    float* __restrict__ w_out, int t)
{
  __shared__ float sw[16][52];
  __shared__ float ctx_p[2][16][72];
  __shared__ float red[3][64][17];
  const int tid = threadIdx.x;
  const int w = tid >> 6, lane = tid & 63;
  const int r = lane & 15, kg = lane >> 4;
  const int bid = blockIdx.x;
  const int id = (bid & 7) * 32 + (bid >> 3);
  const int nt = id >> 2, mq = id & 3;

  // Phase A: raw scores (coalesced nt-major reads)
  for (int idx = tid; idx < 16 * LL; idx += 256) {
    const float* ps = partS + (size_t)mq * 784 + idx;
    float s = 0.f;
#pragma unroll 8
    for (int a = 0; a < 64; ++a) s += ps[(size_t)a * 3136];
    sw[idx / LL][idx % LL] = s;
  }
  __syncthreads();
#pragma unroll
  for (int i = 0; i < 4; ++i) {
    const int bl = w * 4 + i;
    float v = (lane < LL) ? sw[bl][lane] : -1e30f;
    float m = v;
#pragma unroll
    for (int off = 32; off > 0; off >>= 1) m = fmaxf(m, __shfl_xor(m, off));
    float e = (lane < LL) ? expf(v - m) : 0.f;
    float s = e;
#pragma unroll
    for (int off = 32; off > 0; off >>= 1) s += __shfl_xor(s, off);
    float ww = e / s;
    if (lane < LL) {
      sw[bl][lane] = ww;
      if (nt == 0)
        w_out[((size_t)(mq * 16 + bl) * TT + t) * LL + lane] = ww;
    }
  }
  __syncthreads();

  // Phase B: ctx partials; 16B loads, 2-way l-split.
  {
    const int bl = tid >> 4, tsub = tid & 15;
    const int e8 = (tsub & 7) * 8, lpar = tsub >> 3;
    const size_t base =
        ((size_t)nt * 3136 + (size_t)(mq * 16 + bl) * LL) * 64 + e8;
    float s[8] = {};
    for (int l = lpar; l < LL; l += 2) {
      bf16x8 v = *(const bf16x8*)&featCtx[base + (size_t)l * 64];
      const float wl = sw[bl][l];
#pragma unroll
      for (int e = 0; e < 8; ++e)
        s[e] += wl * bf16_tof((unsigned short)v[e]);
    }
#pragma unroll
    for (int e = 0; e < 8; ++e)
      ctx_p[lpar][bl][e8 + e] = s[e];
  }

  // Phase C: gates MFMA over [xg(640) | h(1024)], K split 4 waves x 13 chunks
  const int brow = mq * 16 + r;
  const size_t xgrow = (size_t)t * 64 + brow;
  f32x4 acc0 = {}, acc1 = {}, acc2 = {}, acc3 = {};
#pragma unroll
  for (int c = 0; c < 13; ++c) {
    const int gk = (w * 13 + c) * 32;
    const short *a_h, *a_l, *w0p, *w1p, *w2p, *w3p;
    if (gk < XGLEN) {
      a_h = xgH + xgrow * XGLEN + gk + kg * 8;
      a_l = xgL + xgrow * XGLEN + gk + kg * 8;
      w0p = Wxg + (size_t)(0 * 1024 + nt * 16 + r) * XGLEN + gk + kg * 8;
      w1p = Wxg + (size_t)(1 * 1024 + nt * 16 + r) * XGLEN + gk + kg * 8;
      w2p = Wxg + (size_t)(2 * 1024 + nt * 16 + r) * XGLEN + gk + kg * 8;
      w3p = Wxg + (size_t)(3 * 1024 + nt * 16 + r) * XGLEN + gk + kg * 8;
    } else {
      const int hk = gk - XGLEN;
      a_h = hHi + (size_t)brow * HH + hk + kg * 8;
      a_l = hLi + (size_t)brow * HH + hk + kg * 8;
      w0p = Whb + (size_t)(0 * 1024 + nt * 16 + r) * HH + hk + kg * 8;
      w1p = Whb + (size_t)(1 * 1024 + nt * 16 + r) * HH + hk + kg * 8;
      w2p = Whb + (size_t)(2 * 1024 + nt * 16 + r) * HH + hk + kg * 8;
      w3p = Whb + (size_t)(3 * 1024 + nt * 16 + r) * HH + hk + kg * 8;
    }
    bf16x8 af  = *(const bf16x8*)a_h;
    bf16x8 alf = *(const bf16x8*)a_l;
    bf16x8 b0 = *(const bf16x8*)w0p;
    acc0 = __builtin_amdgcn_mfma_f32_16x16x32_bf16(af,  b0, acc0, 0, 0, 0);
    acc0 = __builtin_amdgcn_mfma_f32_16x16x32_bf16(alf, b0, acc0, 0, 0, 0);
    bf16x8 b1 = *(const bf16x8*)w1p;
    acc1 = __builtin_amdgcn_mfma_f32_16x16x32_bf16(af,  b1, acc1, 0, 0, 0);
    acc1 = __builtin_amdgcn_mfma_f32_16x16x32_bf16(alf, b1, acc1, 0, 0, 0);
    bf16x8 b2 = *(const bf16x8*)w2p;
    acc2 = __builtin_amdgcn_mfma_f32_16x16x32_bf16(af,  b2, acc2, 0, 0, 0);
    acc2 = __builtin_amdgcn_mfma_f32_16x16x32_bf16(alf, b2, acc2, 0, 0, 0);
    bf16x8 b3 = *(const bf16x8*)w3p;
    acc3 = __builtin_amdgcn_mfma_f32_16x16x32_bf16(af,  b3, acc3, 0, 0, 0);
    acc3 = __builtin_amdgcn_mfma_f32_16x16x32_bf16(alf, b3, acc3, 0, 0, 0);
  }

  if (w != 0) {
#pragma unroll
    for (int q = 0; q < 4; ++q) {
      red[w - 1][lane][0 * 4 + q] = acc0[q];
      red[w - 1][lane][1 * 4 + q] = acc1[q];
      red[w - 1][lane][2 * 4 + q] = acc2[q];
      red[w - 1][lane][3 * 4 + q] = acc3[q];
    }
  }
  __syncthreads();
  if (w == 0) {
    const int j = nt * 16 + r;
    const float b0 = bg[j], b1 = bg[1024 + j], b2 = bg[2048 + j], b3 = bg[3072 + j];
#pragma unroll
    for (int q = 0; q < 4; ++q) {
      const int bl = kg * 4 + q;
      float gi = acc0[q] + b0 + ctx_p[0][bl][0 * 16 + r] + ctx_p[1][bl][0 * 16 + r];
      float gf = acc1[q] + b1 + ctx_p[0][bl][1 * 16 + r] + ctx_p[1][bl][1 * 16 + r];
      float gg = acc2[q] + b2 + ctx_p[0][bl][2 * 16 + r] + ctx_p[1][bl][2 * 16 + r];
      float go = acc3[q] + b3 + ctx_p[0][bl][3 * 16 + r] + ctx_p[1][bl][3 * 16 + r];
#pragma unroll
      for (int p = 0; p < 3; ++p) {
        gi += red[p][lane][0 * 4 + q];
        gf += red[p][lane][1 * 4 + q];
        gg += red[p][lane][2 * 4 + q];
        go += red[p][lane][3 * 4 + q];
      }
      const int b = mq * 16 + bl;
      float si = 1.f / (1.f + expf(-gi));
      float sf = 1.f / (1.f + expf(-gf));
      float so = 1.f / (1.f + expf(-go));
      const size_t ci = (size_t)b * HH + j;
      float cc = sf * cbuf[ci] + si * tanhf(gg);
      float hh = so * tanhf(cc);
      cbuf[ci] = cc;
      short hi, lo; split2(hh, hi, lo);
      hHo[ci] = hi;
      hLo[ci] = lo;
    }
  }
}

// ---------------------------------------------------------------------------
// Generic LDS-tiled GEMM: out = A[M,K] @ W[N,K]^T. 128x128 tile, BK=32.
// OUTMODE: 0 = f32 row-major, 2 = bf16 ctx-remap, 3 = bf16 featp-remap
//   (3: col -> nt=col>>4, a=col&15; out[(nt*3136 + row)*16 + a])
// ---------------------------------------------------------------------------
template<int OUTMODE>
__global__ __launch_bounds__(256) void tgemm_k(
    const short* __restrict__ A, const short* __restrict__ Wb,
    float* __restrict__ outf, short* __restrict__ outb,
    int M, int N, int K, int ldo)
{
  __shared__ short lA[128 * 40];
  __shared__ short lW[128 * 40];
  const int tid = threadIdx.x;
  const int w = tid >> 6, lane = tid & 63;
  const int r = lane & 15, kg = lane >> 4;
  const int m0 = blockIdx.x * 128;
  const int n0 = blockIdx.y * 128;
  const int srow = tid >> 2, scol = (tid & 3) * 8;

  f32x4 acc[2][8] = {};
  for (int k0 = 0; k0 < K; k0 += 32) {
    __syncthreads();
#pragma unroll
    for (int j = 0; j < 2; ++j) {
      const int row = j * 64 + srow;
      int ar = m0 + row; if (ar >= M) ar = M - 1;
      int wr = n0 + row; if (wr >= N) wr = N - 1;
      bf16x8 va = *(const bf16x8*)&A[(size_t)ar * K + k0 + scol];
      bf16x8 vw = *(const bf16x8*)&Wb[(size_t)wr * K + k0 + scol];
      *(bf16x8*)&lA[row * 40 + scol] = va;
      *(bf16x8*)&lW[row * 40 + scol] = vw;
    }
    __syncthreads();
    bf16x8 a0 = *(const bf16x8*)&lA[(w * 32 +  0 + r) * 40 + kg * 8];
    bf16x8 a1 = *(const bf16x8*)&lA[(w * 32 + 16 + r) * 40 + kg * 8];
#pragma unroll
    for (int nf = 0; nf < 8; ++nf) {
      bf16x8 wf = *(const bf16x8*)&lW[(nf * 16 + r) * 40 + kg * 8];
      acc[0][nf] = __builtin_amdgcn_mfma_f32_16x16x32_bf16(a0, wf, acc[0][nf], 0, 0, 0);
      acc[1][nf] = __builtin_amdgcn_mfma_f32_16x16x32_bf16(a1, wf, acc[1][nf], 0, 0, 0);
    }
  }
#pragma unroll
  for (int nf = 0; nf < 8; ++nf) {
    const int col = n0 + nf * 16 + r;
    if (col < N) {
#pragma unroll
      for (int mf = 0; mf < 2; ++mf)
#pragma unroll
        for (int q = 0; q < 4; ++q) {
          const int grow = m0 + w * 32 + mf * 16 + kg * 4 + q;
          if (grow < M) {
            if (OUTMODE == 0) {
              outf[(size_t)grow * ldo + col] = acc[mf][nf][q];
            } else if (OUTMODE == 2) {
              const int gate = col >> 10, ntc = (col >> 4) & 63, jj = col & 15;
              outb[((size_t)ntc * 3136 + grow) * 64 + gate * 16 + jj] =
                  (short)bf16_rn(acc[mf][nf][q]);
            } else {
              const int ntc = col >> 4, aa = col & 15;
              outb[((size_t)ntc * 3136 + grow) * 16 + aa] =
                  (short)bf16_rn(acc[mf][nf][q]);
            }
          }
        }
    }
  }
}

// ---------------------------------------------------------------------------
// Batched fc GEMM, LDS-staged 128x128 tile. Grid (16, 94).
// ---------------------------------------------------------------------------
__global__ __launch_bounds__(256) void bgemm_k(
    const short* __restrict__ Ah, const short* __restrict__ Al,
    const short* __restrict__ Wb, const float* __restrict__ bias,
    float* __restrict__ outs)
{
  __shared__ short lAh[128 * 40];
  __shared__ short lAl[128 * 40];
  __shared__ short lW [128 * 40];
  const int tid = threadIdx.x;
  const int w = tid >> 6, lane = tid & 63;
  const int r = lane & 15, kg = lane >> 4;
  const int m0 = blockIdx.x * 128;
  const int n0 = blockIdx.y * 128;
  const int srow = tid >> 2, scol = (tid & 3) * 8;

  f32x4 acc[2][8] = {};
  for (int k0 = 0; k0 < HH; k0 += 32) {
    __syncthreads();
#pragma unroll
    for (int j = 0; j < 2; ++j) {
      const int row = j * 64 + srow;
      bf16x8 va = *(const bf16x8*)&Ah[(size_t)(m0 + row) * HH + k0 + scol];
      bf16x8 vl = *(const bf16x8*)&Al[(size_t)(m0 + row) * HH + k0 + scol];
      int wr = n0 + row; if (wr >= VV) wr = VV - 1;
      bf16x8 vw = *(const bf16x8*)&Wb[(size_t)wr * HH + k0 + scol];
      *(bf16x8*)&lAh[row * 40 + scol] = va;
      *(bf16x8*)&lAl[row * 40 + scol] = vl;
      *(bf16x8*)&lW [row * 40 + scol] = vw;
    }
    __syncthreads();
    bf16x8 ah0 = *(const bf16x8*)&lAh[(w * 32 +  0 + r) * 40 + kg * 8];
    bf16x8 ah1 = *(const bf16x8*)&lAh[(w * 32 + 16 + r) * 40 + kg * 8];
    bf16x8 al0 = *(const bf16x8*)&lAl[(w * 32 +  0 + r) * 40 + kg * 8];
    bf16x8 al1 = *(const bf16x8*)&lAl[(w * 32 + 16 + r) * 40 + kg * 8];
#pragma unroll
    for (int nf = 0; nf < 8; ++nf) {
      bf16x8 wf = *(const bf16x8*)&lW[(nf * 16 + r) * 40 + kg * 8];
      acc[0][nf] = __builtin_amdgcn_mfma_f32_16x16x32_bf16(ah0, wf, acc[0][nf], 0, 0, 0);
      acc[0][nf] = __builtin_amdgcn_mfma_f32_16x16x32_bf16(al0, wf, acc[0][nf], 0, 0, 0);
      acc[1][nf] = __builtin_amdgcn_mfma_f32_16x16x32_bf16(ah1, wf, acc[1][nf], 0, 0, 0);
      acc[1][nf] = __builtin_amdgcn_mfma_f32_16x16x32_bf16(al1, wf, acc[1][nf], 0, 0, 0);
    }
  }
#pragma unroll
  for (int nf = 0; nf < 8; ++nf) {
    const int colv = n0 + nf * 16 + r;
    if (colv < VV) {
      const float bv = bias[colv];
#pragma unroll
      for (int mf = 0; mf < 2; ++mf)
#pragma unroll
        for (int q = 0; q < 4; ++q) {
          const int grow = m0 + w * 32 + mf * 16 + kg * 4 + q;  // = t*64 + b
          const int tt = grow >> 6, b = grow & 63;
          outs[((size_t)b * TT + tt) * VV + colv] = acc[mf][nf][q] + bv;
        }
    }
  }
}

// ---------------------------------------------------------------------------
// MFMA GEMM used in one-time prep (h0, c0).
// ---------------------------------------------------------------------------
template<bool TWOPASS, bool SPLITOUT, int MT>
__global__ __launch_bounds__(256) void mgemm_k(
    const short* __restrict__ Ah, const short* __restrict__ Al, int lda,
    const short* __restrict__ Wb, int ldw,
    const float* __restrict__ bias,
    float* __restrict__ C, int ldc,
    short* __restrict__ Ch, short* __restrict__ Cl, int ldch,
    int N, int K)
{
  const int tid = threadIdx.x;
  const int w = tid >> 6, l = tid & 63;
  const int r = l & 15, kg = l >> 4;
  const int m0 = blockIdx.y * 64;
  const int nslice = (MT == 4) ? w : (w >> 1);
  const int mbase  = (MT == 4) ? 0 : ((w & 1) * 2);
  const int n0 = blockIdx.x * (MT * 16) + nslice * 16;
  const int nrow = n0 + r;
  const int nclmp = nrow < N ? nrow : N - 1;
  const short* wp  = Wb + (size_t)nclmp * ldw + kg * 8;
  const short* ap  = Ah + (size_t)(m0 + mbase * 16 + r) * lda + kg * 8;
  const short* alp = TWOPASS ? (Al + (size_t)(m0 + mbase * 16 + r) * lda + kg * 8)
                             : nullptr;
  f32x4 acc[MT] = {};
  for (int k0 = 0; k0 < K; k0 += 32) {
    bf16x8 bf = *(const bf16x8*)(wp + k0);
#pragma unroll
    for (int m = 0; m < MT; ++m) {
      bf16x8 af = *(const bf16x8*)(ap + (size_t)(16 * m) * lda + k0);
      acc[m] = __builtin_amdgcn_mfma_f32_16x16x32_bf16(af, bf, acc[m], 0, 0, 0);
      if (TWOPASS) {
        bf16x8 alf = *(const bf16x8*)(alp + (size_t)(16 * m) * lda + k0);
        acc[m] = __builtin_amdgcn_mfma_f32_16x16x32_bf16(alf, bf, acc[m], 0, 0, 0);
      }
    }
  }
  if (nrow < N) {
    float bv = bias ? bias[nrow] : 0.f;
#pragma unroll
    for (int m = 0; m < MT; ++m) {
#pragma unroll
      for (int q = 0; q < 4; ++q) {
        int mm = m0 + (mbase + m) * 16 + kg * 4 + q;
        float v = acc[m][q] + bv;
        if (SPLITOUT) {
          short hi, lo; split2(v, hi, lo);
          Ch[(size_t)mm * ldch + nrow] = hi;
          Cl[(size_t)mm * ldch + nrow] = lo;
        } else {
          C[(size_t)mm * ldc + nrow] = v;
        }
      }
    }
  }
}

__global__ __launch_bounds__(256) void transpose_split_k(
    const float* __restrict__ in, short* __restrict__ out, int R, int C)
{
  __shared__ float tile[32][33];
  int bc = blockIdx.x * 32, br = blockIdx.y * 32;
  int tx = threadIdx.x & 31, ty4 = (threadIdx.x >> 5) << 2;
#pragma unroll
  for (int i = 0; i < 4; ++i) {
    int r = br + ty4 + i, c = bc + tx;
    tile[ty4 + i][tx] = (r < R && c < C) ? in[(size_t)r * C + c] : 0.f;
  }
  __syncthreads();
#pragma unroll
  for (int i = 0; i < 4; ++i) {
    int oc = bc + ty4 + i, orr = br + tx;
    if (oc < C && orr < R) out[(size_t)oc * R + orr] = (short)bf16_rn(tile[tx][ty4 + i]);
  }
}

// ---------------------------------------------------------------------------
// Fused elementwise prep, 8-wide vectorized.
// ---------------------------------------------------------------------------
#define S_FEATB   6422528ULL                       /* 64*49*2048      */
#define C1  (S_FEATB)
#define C2  (C1 + 12288000ULL)                     /* fc_W 12000*1024 */
#define C3  (C2 + 4194304ULL)                      /* W_hh 4096*1024  */
#define C4  (C3 + 2097152ULL)                      /* Wh0 1024*2048   */
#define C5  (C4 + 2097152ULL)                      /* Wc0 1024*2048   */
#define C6  (C5 + 2621440ULL)                      /* Wxg 4096*640    */
#define C7  (C6 + 8388608ULL)                      /* Wctx 4096*2048  */
#define C8  (C7 + 1310720ULL)                      /* xg 2048*640     */
#define C9  (C8 + 4096ULL)                         /* bg              */
#define C10 (C9 + 131072ULL)                       /* mean 64*2048    */

__global__ __launch_bounds__(256) void prep_k(
    const float* __restrict__ features, const float* __restrict__ fc_W,
    const float* __restrict__ W_hh, const float* __restrict__ Wh0,
    const float* __restrict__ Wc0, const float* __restrict__ W_ih,
    const int* __restrict__ captions, const float* __restrict__ emb,
    const float* __restrict__ cat,
    const float* __restrict__ b_ih, const float* __restrict__ b_hh,
    short* __restrict__ featb, short* __restrict__ fcWb,
    short* __restrict__ Whb, short* __restrict__ Wh0b,
    short* __restrict__ Wc0b, short* __restrict__ Wxg,
    short* __restrict__ Wctxb, short* __restrict__ xgH,
    short* __restrict__ xgL, float* __restrict__ bg,
    short* __restrict__ mfb)
{
  const size_t stride = (size_t)gridDim.x * 256;
  for (size_t ii = (size_t)blockIdx.x * 256 + threadIdx.x; ii < (C10 >> 3);
       ii += stride) {
    const size_t i = ii << 3;
    float f[8];
    if (i < C1) {
      *(float4*)&f[0] = *(const float4*)&features[i];
      *(float4*)&f[4] = *(const float4*)&features[i + 4];
      *(bf16x8*)&featb[i] = cvt8(f);
    } else if (i < C2) {
      const size_t j = i - C1;
      *(float4*)&f[0] = *(const float4*)&fc_W[j];
      *(float4*)&f[4] = *(const float4*)&fc_W[j + 4];
      *(bf16x8*)&fcWb[j] = cvt8(f);
    } else if (i < C3) {
      const size_t j = i - C2;
      *(float4*)&f[0] = *(const float4*)&W_hh[j];
      *(float4*)&f[4] = *(const float4*)&W_hh[j + 4];
      *(bf16x8*)&Whb[j] = cvt8(f);
    } else if (i < C4) {
      const size_t j = i - C3;
      *(float4*)&f[0] = *(const float4*)&Wh0[j];
      *(float4*)&f[4] = *(const float4*)&Wh0[j + 4];
      *(bf16x8*)&Wh0b[j] = cvt8(f);
    } else if (i < C5) {
      const size_t j = i - C4;
      *(float4*)&f[0] = *(const float4*)&Wc0[j];
      *(float4*)&f[4] = *(const float4*)&Wc0[j + 4];
      *(bf16x8*)&Wc0b[j] = cvt8(f);
    } else if (i < C6) {
      const size_t j = i - C5;
      const int n = (int)(j / XGLEN), k = (int)(j % XGLEN);
      const int ks = (k < EE) ? k : (EE + FF + (k - EE));
      const float* src = &W_ih[(size_t)n * XKLEN + ks];
      *(float4*)&f[0] = *(const float4*)&src[0];
      *(float4*)&f[4] = *(const float4*)&src[4];
      *(bf16x8*)&Wxg[j] = cvt8(f);
    } else if (i < C7) {
      const size_t j = i - C6;
      const int n = (int)(j / FF), k = (int)(j % FF);
      const float* src = &W_ih[(size_t)n * XKLEN + EE + k];
      *(float4*)&f[0] = *(const float4*)&src[0];
      *(float4*)&f[4] = *(const float4*)&src[4];
      *(bf16x8*)&Wctxb[j] = cvt8(f);
    } else if (i < C8) {
      const size_t j = i - C7;
      const int row = (int)(j / XGLEN), k = (int)(j % XGLEN);
      const int t = row >> 6, b = row & 63;
      const float* src;
      if (k < EE) {
        const int cap = captions[b * TT + t];
        src = &emb[(size_t)cap * EE + k];
      } else {
        src = &cat[(size_t)b * CDIM + (k - EE)];
      }
      *(float4*)&f[0] = *(const float4*)&src[0];
      *(float4*)&f[4] = *(const float4*)&src[4];
      bf16x8 hi8, lo8;
#pragma unroll
      for (int e = 0; e < 8; ++e) {
        short h, l2; split2(f[e], h, l2);
        hi8[e] = h; lo8[e] = l2;
      }
      *(bf16x8*)&xgH[j] = hi8;
      *(bf16x8*)&xgL[j] = lo8;
    } else if (i < C9) {
      const size_t j = i - C8;
      float4 a0 = *(const float4*)&b_ih[j];
      float4 a1 = *(const float4*)&b_ih[j + 4];
      float4 c0 = *(const float4*)&b_hh[j];
      float4 c1 = *(const float4*)&b_hh[j + 4];
      float4 o0 = make_float4(a0.x + c0.x, a0.y + c0.y, a0.z + c0.z, a0.w + c0.w);
      float4 o1 = make_float4(a1.x + c1.x, a1.y + c1.y, a1.z + c1.z, a1.w + c1.w);
      *(float4*)&bg[j] = o0;
      *(float4*)&bg[j + 4] = o1;
    } else {
      const size_t j = i - C9;
      const int b = (int)(j >> 11), f0 = (int)(j & 2047);
      float s[8] = {};
      for (int l = 0; l < LL; ++l) {
        const float* src = &features[((size_t)b * LL + l) * FF + f0];
        float4 u0 = *(const float4*)&src[0];
        float4 u1 = *(const float4*)&src[4];
        s[0] += u0.x; s[1] += u0.y; s[2] += u0.z; s[3] += u0.w;
        s[4] += u1.x; s[5] += u1.y; s[6] += u1.z; s[7] += u1.w;
      }
#pragma unroll
      for (int e = 0; e < 8; ++e) s[e] *= (1.f / 49.f);
      *(bf16x8*)&mfb[j] = cvt8(s);
    }
  }
}

extern "C" void kernel_launch(void* const* d_in, const int* in_sizes, int n_in,
                              void* d_out, int out_size, void* d_ws, size_t ws_size,
                              hipStream_t stream) {
  const int*   captions = (const int*)  d_in[0];
  const float* features = (const float*)d_in[1];
  const float* category = (const float*)d_in[2];
  const float* emb      = (const float*)d_in[3];
  const float* W_ih     = (const float*)d_in[4];
  const float* b_ih     = (const float*)d_in[5];
  const float* W_hh     = (const float*)d_in[6];
  const float* b_hh     = (const float*)d_in[7];
  const float* fc_W     = (const float*)d_in[8];
  const float* fc_b     = (const float*)d_in[9];
  const float* Wh0      = (const float*)d_in[10];
  const float* bh0      = (const float*)d_in[11];
  const float* Wc0      = (const float*)d_in[12];
  const float* bc0      = (const float*)d_in[13];
  const float* att_W    = (const float*)d_in[14];
  const float* att_U    = (const float*)d_in[15];
  const float* att_v    = (const float*)d_in[16];

  float* outs  = (float*)d_out;
  float* w_out = outs + (size_t)BB * TT * VV;

  char* p = (char*)d_ws;
  auto alloc = [&](size_t bytes) {
    char* q = p; p += (bytes + 255) & ~(size_t)255; return q;
  };
  short* attUt  = (short*)alloc((size_t)HH * HH * 2);
  short* attWt  = (short*)alloc((size_t)HH * FF * 2);
  short* featb  = (short*)alloc((size_t)BB * LL * FF * 2);   // prep only; reused as hall
  short* fcWb   = (short*)alloc((size_t)VV * HH * 2);
  short* Wctxb  = (short*)alloc((size_t)4096 * FF * 2);
  short* Whb    = (short*)alloc((size_t)4096 * HH * 2);
  short* Wxg    = (short*)alloc((size_t)4096 * XGLEN * 2);
  short* Wh0b   = (short*)alloc((size_t)HH * FF * 2);
  short* Wc0b   = (short*)alloc((size_t)HH * FF * 2);
  short* mfb    = (short*)alloc((size_t)BB * FF * 2);
  short* h0H    = (short*)alloc((size_t)BB * HH * 2);
  short* h0L    = (short*)alloc((size_t)BB * HH * 2);
  short* xgH    = (short*)alloc((size_t)2048 * XGLEN * 2);
  short* xgL    = (short*)alloc((size_t)2048 * XGLEN * 2);
  short* featpB = (short*)alloc((size_t)64 * 3136 * 16 * 2); // [nt][3136][16] bf16
  short* featCtx= (short*)alloc((size_t)64 * 3136 * 64 * 2);
  float* cbuf   = (float*)alloc((size_t)BB * HH * 4);
  float* partS  = (float*)alloc((size_t)64 * 3136 * 4);
  float* bg     = (float*)alloc(4096 * 4);
  // h history (= h(t) for t=0..31) aliases featb (dead after prep GEMMs).
  short* hallH = featb;
  short* hallL = featb + (size_t)TT * BB * HH;

  // ---- one-time prep ----
  prep_k<<<2048, 256, 0, stream>>>(
      features, fc_W, W_hh, Wh0, Wc0, W_ih, captions, emb, category,
      b_ih, b_hh,
      featb, fcWb, Whb, Wh0b, Wc0b, Wxg, Wctxb, xgH, xgL, bg, mfb);
  transpose_split_k<<<dim3(32, 32), 256, 0, stream>>>(att_U, attUt, HH, HH);
  transpose_split_k<<<dim3(32, 64), 256, 0, stream>>>(att_W, attWt, FF, HH);

  // h0 / c0
  mgemm_k<false, true, 2><<<dim3(32, 1), 256, 0, stream>>>(
      mfb, nullptr, FF, Wh0b, FF, bh0,
      nullptr, 0, h0H, h0L, HH, HH, FF);
  mgemm_k<false, false, 2><<<dim3(32, 1), 256, 0, stream>>>(
      mfb, nullptr, FF, Wc0b, FF, bc0,
      cbuf, HH, nullptr, nullptr, 0, HH, FF);
  // featpB = features @ att_W  (bf16, remapped to [64 nt][3136][16])
  tgemm_k<3><<<dim3(25, 8), 256, 0, stream>>>(
      featb, attWt, nullptr, featpB, BB * LL, HH, FF, 0);
  // featCtx = features @ W_ih_ctx^T  (bf16, remapped to [64 nt][3136][64])
  tgemm_k<2><<<dim3(25, 32), 256, 0, stream>>>(
      featb, Wctxb, nullptr, featCtx, BB * LL, 4096, FF, 0);

  // ---- timestep loop: 2 dispatches per step ----
  for (int t = 0; t < TT; ++t) {
    const short* hHi = (t == 0) ? h0H : hallH + (size_t)(t - 1) * BB * HH;
    const short* hLi = (t == 0) ? h0L : hallL + (size_t)(t - 1) * BB * HH;
    hupart_k<<<256, 256, 0, stream>>>(
        hHi, hLi, attUt, featpB, att_v, partS);
    glstm3_k<<<256, 256, 0, stream>>>(
        xgH, xgL, hHi, hLi, Wxg, Whb, featCtx, partS, bg, cbuf,
        hallH + (size_t)t * BB * HH, hallL + (size_t)t * BB * HH, w_out, t);
  }

  // ---- deferred batched fc ----
  bgemm_k<<<dim3(16, 94), 256, 0, stream>>>(hallH, hallL, fcWb, fc_b, outs);
}

// Round 18
// 1844.458 us; speedup vs baseline: 1.1738x; 1.0561x over previous
//
#include <hip/hip_runtime.h>
#include <hip/hip_bf16.h>

#define BB 64
#define TT 32
#define VV 12000
#define EE 512
#define FF 2048
#define CDIM 128
#define HH 1024
#define LL 49
#define XKLEN 2688   /* E + F + C */
#define XGLEN 640    /* E + C : per-step gathered input */

typedef __attribute__((ext_vector_type(8))) short bf16x8;
typedef __attribute__((ext_vector_type(4))) float f32x4;

__device__ __forceinline__ unsigned short bf16_rn(float x) {
  unsigned u = __float_as_uint(x);
  u += 0x7FFFu + ((u >> 16) & 1u);
  return (unsigned short)(u >> 16);
}
__device__ __forceinline__ float bf16_tof(unsigned short h) {
  return __uint_as_float(((unsigned)h) << 16);
}
__device__ __forceinline__ void split2(float x, short& hi, short& lo) {
  unsigned short h = bf16_rn(x);
  float r = x - bf16_tof(h);
  hi = (short)h;
  lo = (short)bf16_rn(r);
}
__device__ __forceinline__ bf16x8 cvt8(const float* f) {
  bf16x8 o;
#pragma unroll
  for (int e = 0; e < 8; ++e) o[e] = (short)bf16_rn(f[e]);
  return o;
}

// ---------------------------------------------------------------------------
// D1: hU tile + partial scores. Grid 256 (XCD-swizzled). hi-only MFMA
// (attention-score path tolerates bf16-level hU). partS: [64 nt][64 b][49 l]
// featpB: [64 nt][3136 row][16 a] bf16
// ---------------------------------------------------------------------------
__global__ __launch_bounds__(256) void hupart_k(
    const short* __restrict__ hHi,
    const short* __restrict__ attUt,   // [1024][1024] bf16 = att_U^T
    const short* __restrict__ featpB,  // [64][3136][16] bf16
    const float* __restrict__ att_v,
    float* __restrict__ partS)         // [64 nt][64 b][49 l]
{
  __shared__ float red[4][64][5];
  __shared__ float hu_s[16][17];
  __shared__ float av_s[16];
  const int tid = threadIdx.x;
  const int w = tid >> 6, lane = tid & 63;
  const int r = lane & 15, kg = lane >> 4;
  const int bid = blockIdx.x;
  const int id = (bid & 7) * 32 + (bid >> 3);
  const int nt = id >> 2, mh = id & 3;
  const int kb = w * 256;

  if (tid < 16) av_s[tid] = att_v[nt * 16 + tid];

  const short* wp = attUt + (size_t)(nt * 16 + r) * HH + kb + kg * 8;
  const short* ap = hHi + (size_t)(mh * 16 + r) * HH + kb + kg * 8;
  f32x4 acc = {};
#pragma unroll
  for (int k0 = 0; k0 < 256; k0 += 32) {
    bf16x8 bf = *(const bf16x8*)(wp + k0);
    bf16x8 af = *(const bf16x8*)(ap + k0);
    acc = __builtin_amdgcn_mfma_f32_16x16x32_bf16(af, bf, acc, 0, 0, 0);
  }
#pragma unroll
  for (int q = 0; q < 4; ++q)
    red[w][lane][q] = acc[q];
  __syncthreads();

  {
    const int bl = tid >> 4, a = tid & 15;
    const int sl = (bl >> 2) * 16 + a;
    const int ii = bl & 3;
    hu_s[bl][a] = red[0][sl][ii] + red[1][sl][ii] + red[2][sl][ii] + red[3][sl][ii];
  }
  __syncthreads();

  for (int task = tid; task < 16 * LL; task += 256) {
    const int bl = task / LL, l = task - bl * LL;
    const int b = mh * 16 + bl;
    const short* fp = featpB + ((size_t)nt * 3136 + (size_t)b * LL + l) * 16;
    bf16x8 v0 = *(const bf16x8*)&fp[0];
    bf16x8 v1 = *(const bf16x8*)&fp[8];
    float s = 0.f;
#pragma unroll
    for (int a = 0; a < 8; ++a)
      s += tanhf(bf16_tof((unsigned short)v0[a]) + hu_s[bl][a]) * av_s[a];
#pragma unroll
    for (int a = 0; a < 8; ++a)
      s += tanhf(bf16_tof((unsigned short)v1[a]) + hu_s[bl][8 + a]) * av_s[8 + a];
    partS[(size_t)nt * 3136 + (size_t)mh * 784 + task] = s;
  }
}

// ---------------------------------------------------------------------------
// D2: softmax + ctx-weighted-sum + gates MFMA ([xg|h] segments) + LSTM.
// Grid 256 (XCD-swizzled). featCtx: [nt][3136][64]. h out to hall[t].
// ---------------------------------------------------------------------------
__global__ __launch_bounds__(256) void glstm3_k(
    const short* __restrict__ xgH, const short* __restrict__ xgL,  // [2048][640]
    const short* __restrict__ hHi, const short* __restrict__ hLi,  // [64][1024]
    const short* __restrict__ Wxg,      // [4096][640]
    const short* __restrict__ Whb,      // [4096][1024]
    const short* __restrict__ featCtx,  // [64][3136][64] bf16
    const float* __restrict__ partS,    // [64 nt][64 b][49 l]
    const float* __restrict__ bg,
    float* __restrict__ cbuf,
    short* __restrict__ hHo, short* __restrict__ hLo,
    float* __restrict__ w_out, int t)
{
  __shared__ float sw[16][52];
  __shared__ float ctx_p[2][16][72];
  __shared__ float red[3][64][17];
  const int tid = threadIdx.x;
  const int w = tid >> 6, lane = tid & 63;
  const int r = lane & 15, kg = lane >> 4;
  const int bid = blockIdx.x;
  const int id = (bid & 7) * 32 + (bid >> 3);
  const int nt = id >> 2, mq = id & 3;

  // Phase A: raw scores (coalesced nt-major reads)
  for (int idx = tid; idx < 16 * LL; idx += 256) {
    const float* ps = partS + (size_t)mq * 784 + idx;
    float s = 0.f;
#pragma unroll 8
    for (int a = 0; a < 64; ++a) s += ps[(size_t)a * 3136];
    sw[idx / LL][idx % LL] = s;
  }
  __syncthreads();
#pragma unroll
  for (int i = 0; i < 4; ++i) {
    const int bl = w * 4 + i;
    float v = (lane < LL) ? sw[bl][lane] : -1e30f;
    float m = v;
#pragma unroll
    for (int off = 32; off > 0; off >>= 1) m = fmaxf(m, __shfl_xor(m, off));
    float e = (lane < LL) ? expf(v - m) : 0.f;
    float s = e;
#pragma unroll
    for (int off = 32; off > 0; off >>= 1) s += __shfl_xor(s, off);
    float ww = e / s;
    if (lane < LL) {
      sw[bl][lane] = ww;
      if (nt == 0)
        w_out[((size_t)(mq * 16 + bl) * TT + t) * LL + lane] = ww;
    }
  }
  __syncthreads();

  // Phase B: ctx partials; 16B loads, 2-way l-split.
  {
    const int bl = tid >> 4, tsub = tid & 15;
    const int e8 = (tsub & 7) * 8, lpar = tsub >> 3;
    const size_t base =
        ((size_t)nt * 3136 + (size_t)(mq * 16 + bl) * LL) * 64 + e8;
    float s[8] = {};
    for (int l = lpar; l < LL; l += 2) {
      bf16x8 v = *(const bf16x8*)&featCtx[base + (size_t)l * 64];
      const float wl = sw[bl][l];
#pragma unroll
      for (int e = 0; e < 8; ++e)
        s[e] += wl * bf16_tof((unsigned short)v[e]);
    }
#pragma unroll
    for (int e = 0; e < 8; ++e)
      ctx_p[lpar][bl][e8 + e] = s[e];
  }

  // Phase C: gates MFMA over [xg(640) | h(1024)], K split 4 waves x 13 chunks
  const int brow = mq * 16 + r;
  const size_t xgrow = (size_t)t * 64 + brow;
  f32x4 acc0 = {}, acc1 = {}, acc2 = {}, acc3 = {};
#pragma unroll
  for (int c = 0; c < 13; ++c) {
    const int gk = (w * 13 + c) * 32;
    const short *a_h, *a_l, *w0p, *w1p, *w2p, *w3p;
    if (gk < XGLEN) {
      a_h = xgH + xgrow * XGLEN + gk + kg * 8;
      a_l = xgL + xgrow * XGLEN + gk + kg * 8;
      w0p = Wxg + (size_t)(0 * 1024 + nt * 16 + r) * XGLEN + gk + kg * 8;
      w1p = Wxg + (size_t)(1 * 1024 + nt * 16 + r) * XGLEN + gk + kg * 8;
      w2p = Wxg + (size_t)(2 * 1024 + nt * 16 + r) * XGLEN + gk + kg * 8;
      w3p = Wxg + (size_t)(3 * 1024 + nt * 16 + r) * XGLEN + gk + kg * 8;
    } else {
      const int hk = gk - XGLEN;
      a_h = hHi + (size_t)brow * HH + hk + kg * 8;
      a_l = hLi + (size_t)brow * HH + hk + kg * 8;
      w0p = Whb + (size_t)(0 * 1024 + nt * 16 + r) * HH + hk + kg * 8;
      w1p = Whb + (size_t)(1 * 1024 + nt * 16 + r) * HH + hk + kg * 8;
      w2p = Whb + (size_t)(2 * 1024 + nt * 16 + r) * HH + hk + kg * 8;
      w3p = Whb + (size_t)(3 * 1024 + nt * 16 + r) * HH + hk + kg * 8;
    }
    bf16x8 af  = *(const bf16x8*)a_h;
    bf16x8 alf = *(const bf16x8*)a_l;
    bf16x8 b0 = *(const bf16x8*)w0p;
    acc0 = __builtin_amdgcn_mfma_f32_16x16x32_bf16(af,  b0, acc0, 0, 0, 0);
    acc0 = __builtin_amdgcn_mfma_f32_16x16x32_bf16(alf, b0, acc0, 0, 0, 0);
    bf16x8 b1 = *(const bf16x8*)w1p;
    acc1 = __builtin_amdgcn_mfma_f32_16x16x32_bf16(af,  b1, acc1, 0, 0, 0);
    acc1 = __builtin_amdgcn_mfma_f32_16x16x32_bf16(alf, b1, acc1, 0, 0, 0);
    bf16x8 b2 = *(const bf16x8*)w2p;
    acc2 = __builtin_amdgcn_mfma_f32_16x16x32_bf16(af,  b2, acc2, 0, 0, 0);
    acc2 = __builtin_amdgcn_mfma_f32_16x16x32_bf16(alf, b2, acc2, 0, 0, 0);
    bf16x8 b3 = *(const bf16x8*)w3p;
    acc3 = __builtin_amdgcn_mfma_f32_16x16x32_bf16(af,  b3, acc3, 0, 0, 0);
    acc3 = __builtin_amdgcn_mfma_f32_16x16x32_bf16(alf, b3, acc3, 0, 0, 0);
  }

  if (w != 0) {
#pragma unroll
    for (int q = 0; q < 4; ++q) {
      red[w - 1][lane][0 * 4 + q] = acc0[q];
      red[w - 1][lane][1 * 4 + q] = acc1[q];
      red[w - 1][lane][2 * 4 + q] = acc2[q];
      red[w - 1][lane][3 * 4 + q] = acc3[q];
    }
  }
  __syncthreads();
  if (w == 0) {
    const int j = nt * 16 + r;
    const float b0 = bg[j], b1 = bg[1024 + j], b2 = bg[2048 + j], b3 = bg[3072 + j];
#pragma unroll
    for (int q = 0; q < 4; ++q) {
      const int bl = kg * 4 + q;
      float gi = acc0[q] + b0 + ctx_p[0][bl][0 * 16 + r] + ctx_p[1][bl][0 * 16 + r];
      float gf = acc1[q] + b1 + ctx_p[0][bl][1 * 16 + r] + ctx_p[1][bl][1 * 16 + r];
      float gg = acc2[q] + b2 + ctx_p[0][bl][2 * 16 + r] + ctx_p[1][bl][2 * 16 + r];
      float go = acc3[q] + b3 + ctx_p[0][bl][3 * 16 + r] + ctx_p[1][bl][3 * 16 + r];
#pragma unroll
      for (int p = 0; p < 3; ++p) {
        gi += red[p][lane][0 * 4 + q];
        gf += red[p][lane][1 * 4 + q];
        gg += red[p][lane][2 * 4 + q];
        go += red[p][lane][3 * 4 + q];
      }
      const int b = mq * 16 + bl;
      float si = 1.f / (1.f + expf(-gi));
      float sf = 1.f / (1.f + expf(-gf));
      float so = 1.f / (1.f + expf(-go));
      const size_t ci = (size_t)b * HH + j;
      float cc = sf * cbuf[ci] + si * tanhf(gg);
      float hh = so * tanhf(cc);
      cbuf[ci] = cc;
      short hi, lo; split2(hh, hi, lo);
      hHo[ci] = hi;
      hLo[ci] = lo;
    }
  }
}

// ---------------------------------------------------------------------------
// Combined prep GEMM: A=featb[3136][2048]; blockIdx.y<8 -> featpB (attWt,
// N=1024, remap [nt][3136][16]); else -> featCtx (Wctxb, N=4096, remap
// [nt][3136][64]). Grid (25, 40), 128x128 tile.
// ---------------------------------------------------------------------------
__global__ __launch_bounds__(256) void tgemm2_k(
    const short* __restrict__ A,
    const short* __restrict__ attWt,   // [1024][2048]
    const short* __restrict__ Wctxb,   // [4096][2048]
    short* __restrict__ featpB, short* __restrict__ featCtx)
{
  __shared__ short lA[128 * 40];
  __shared__ short lW[128 * 40];
  const int tid = threadIdx.x;
  const int w = tid >> 6, lane = tid & 63;
  const int r = lane & 15, kg = lane >> 4;
  const int M = BB * LL, K = FF;
  const bool ctx = (blockIdx.y >= 8);
  const short* Wb = ctx ? Wctxb : attWt;
  const int n0 = (ctx ? (blockIdx.y - 8) : blockIdx.y) * 128;
  const int m0 = blockIdx.x * 128;
  const int srow = tid >> 2, scol = (tid & 3) * 8;

  f32x4 acc[2][8] = {};
  for (int k0 = 0; k0 < K; k0 += 32) {
    __syncthreads();
#pragma unroll
    for (int j = 0; j < 2; ++j) {
      const int row = j * 64 + srow;
      int ar = m0 + row; if (ar >= M) ar = M - 1;
      bf16x8 va = *(const bf16x8*)&A[(size_t)ar * K + k0 + scol];
      bf16x8 vw = *(const bf16x8*)&Wb[(size_t)(n0 + row) * K + k0 + scol];
      *(bf16x8*)&lA[row * 40 + scol] = va;
      *(bf16x8*)&lW[row * 40 + scol] = vw;
    }
    __syncthreads();
    bf16x8 a0 = *(const bf16x8*)&lA[(w * 32 +  0 + r) * 40 + kg * 8];
    bf16x8 a1 = *(const bf16x8*)&lA[(w * 32 + 16 + r) * 40 + kg * 8];
#pragma unroll
    for (int nf = 0; nf < 8; ++nf) {
      bf16x8 wf = *(const bf16x8*)&lW[(nf * 16 + r) * 40 + kg * 8];
      acc[0][nf] = __builtin_amdgcn_mfma_f32_16x16x32_bf16(a0, wf, acc[0][nf], 0, 0, 0);
      acc[1][nf] = __builtin_amdgcn_mfma_f32_16x16x32_bf16(a1, wf, acc[1][nf], 0, 0, 0);
    }
  }
#pragma unroll
  for (int nf = 0; nf < 8; ++nf) {
    const int col = n0 + nf * 16 + r;
#pragma unroll
    for (int mf = 0; mf < 2; ++mf)
#pragma unroll
      for (int q = 0; q < 4; ++q) {
        const int grow = m0 + w * 32 + mf * 16 + kg * 4 + q;
        if (grow < M) {
          const short v = (short)bf16_rn(acc[mf][nf][q]);
          if (!ctx) {
            const int ntc = col >> 4, aa = col & 15;
            featpB[((size_t)ntc * 3136 + grow) * 16 + aa] = v;
          } else {
            const int gate = col >> 10, ntc = (col >> 4) & 63, jj = col & 15;
            featCtx[((size_t)ntc * 3136 + grow) * 64 + gate * 16 + jj] = v;
          }
        }
      }
  }
}

// ---------------------------------------------------------------------------
// Batched fc GEMM, LDS-staged 128x128 tile. Grid (16, 94).
// ---------------------------------------------------------------------------
__global__ __launch_bounds__(256) void bgemm_k(
    const short* __restrict__ Ah, const short* __restrict__ Al,
    const short* __restrict__ Wb, const float* __restrict__ bias,
    float* __restrict__ outs)
{
  __shared__ short lAh[128 * 40];
  __shared__ short lAl[128 * 40];
  __shared__ short lW [128 * 40];
  const int tid = threadIdx.x;
  const int w = tid >> 6, lane = tid & 63;
  const int r = lane & 15, kg = lane >> 4;
  const int m0 = blockIdx.x * 128;
  const int n0 = blockIdx.y * 128;
  const int srow = tid >> 2, scol = (tid & 3) * 8;

  f32x4 acc[2][8] = {};
  for (int k0 = 0; k0 < HH; k0 += 32) {
    __syncthreads();
#pragma unroll
    for (int j = 0; j < 2; ++j) {
      const int row = j * 64 + srow;
      bf16x8 va = *(const bf16x8*)&Ah[(size_t)(m0 + row) * HH + k0 + scol];
      bf16x8 vl = *(const bf16x8*)&Al[(size_t)(m0 + row) * HH + k0 + scol];
      int wr = n0 + row; if (wr >= VV) wr = VV - 1;
      bf16x8 vw = *(const bf16x8*)&Wb[(size_t)wr * HH + k0 + scol];
      *(bf16x8*)&lAh[row * 40 + scol] = va;
      *(bf16x8*)&lAl[row * 40 + scol] = vl;
      *(bf16x8*)&lW [row * 40 + scol] = vw;
    }
    __syncthreads();
    bf16x8 ah0 = *(const bf16x8*)&lAh[(w * 32 +  0 + r) * 40 + kg * 8];
    bf16x8 ah1 = *(const bf16x8*)&lAh[(w * 32 + 16 + r) * 40 + kg * 8];
    bf16x8 al0 = *(const bf16x8*)&lAl[(w * 32 +  0 + r) * 40 + kg * 8];
    bf16x8 al1 = *(const bf16x8*)&lAl[(w * 32 + 16 + r) * 40 + kg * 8];
#pragma unroll
    for (int nf = 0; nf < 8; ++nf) {
      bf16x8 wf = *(const bf16x8*)&lW[(nf * 16 + r) * 40 + kg * 8];
      acc[0][nf] = __builtin_amdgcn_mfma_f32_16x16x32_bf16(ah0, wf, acc[0][nf], 0, 0, 0);
      acc[0][nf] = __builtin_amdgcn_mfma_f32_16x16x32_bf16(al0, wf, acc[0][nf], 0, 0, 0);
      acc[1][nf] = __builtin_amdgcn_mfma_f32_16x16x32_bf16(ah1, wf, acc[1][nf], 0, 0, 0);
      acc[1][nf] = __builtin_amdgcn_mfma_f32_16x16x32_bf16(al1, wf, acc[1][nf], 0, 0, 0);
    }
  }
#pragma unroll
  for (int nf = 0; nf < 8; ++nf) {
    const int colv = n0 + nf * 16 + r;
    if (colv < VV) {
      const float bv = bias[colv];
#pragma unroll
      for (int mf = 0; mf < 2; ++mf)
#pragma unroll
        for (int q = 0; q < 4; ++q) {
          const int grow = m0 + w * 32 + mf * 16 + kg * 4 + q;  // = t*64 + b
          const int tt = grow >> 6, b = grow & 63;
          outs[((size_t)b * TT + tt) * VV + colv] = acc[mf][nf][q] + bv;
        }
    }
  }
}

// ---------------------------------------------------------------------------
// Fused h0/c0: grid 64; bid<32 -> h0 (split out), else c0 (f32 out).
// mfb[64][2048] @ W^T (N=1024, K=2048), mgemm MT=2 structure.
// ---------------------------------------------------------------------------
__global__ __launch_bounds__(256) void h0c0_k(
    const short* __restrict__ mfb,
    const short* __restrict__ Wh0b, const float* __restrict__ bh0,
    const short* __restrict__ Wc0b, const float* __restrict__ bc0,
    short* __restrict__ h0H, short* __restrict__ h0L,
    float* __restrict__ cbuf)
{
  const int tid = threadIdx.x;
  const int w = tid >> 6, l = tid & 63;
  const int r = l & 15, kg = l >> 4;
  const bool cpath = blockIdx.x >= 32;
  const int nb = blockIdx.x & 31;
  const short* Wb = cpath ? Wc0b : Wh0b;
  const float* bias = cpath ? bc0 : bh0;
  const int nslice = w >> 1, mbase = (w & 1) * 2;
  const int n0 = nb * 32 + nslice * 16;
  const int nrow = n0 + r;
  const short* wp = Wb + (size_t)nrow * FF + kg * 8;
  const short* ap = mfb + (size_t)(mbase * 16 + r) * FF + kg * 8;
  f32x4 acc[2] = {};
  for (int k0 = 0; k0 < FF; k0 += 32) {
    bf16x8 bf = *(const bf16x8*)(wp + k0);
#pragma unroll
    for (int m = 0; m < 2; ++m) {
      bf16x8 af = *(const bf16x8*)(ap + (size_t)(16 * m) * FF + k0);
      acc[m] = __builtin_amdgcn_mfma_f32_16x16x32_bf16(af, bf, acc[m], 0, 0, 0);
    }
  }
  const float bv = bias[nrow];
#pragma unroll
  for (int m = 0; m < 2; ++m)
#pragma unroll
    for (int q = 0; q < 4; ++q) {
      const int mm = (mbase + m) * 16 + kg * 4 + q;
      const float v = acc[m][q] + bv;
      if (cpath) {
        cbuf[(size_t)mm * HH + nrow] = v;
      } else {
        short hi, lo; split2(v, hi, lo);
        h0H[(size_t)mm * HH + nrow] = hi;
        h0L[(size_t)mm * HH + nrow] = lo;
      }
    }
}

// ---------------------------------------------------------------------------
// Combined transpose+cast: grid (32, 96): y<32 -> att_U (R=1024),
// else att_W (R=2048, br offset). out[C][R] = bf16(in^T).
// ---------------------------------------------------------------------------
__global__ __launch_bounds__(256) void transpose2_k(
    const float* __restrict__ attU, short* __restrict__ attUt,
    const float* __restrict__ attW, short* __restrict__ attWt)
{
  __shared__ float tile[32][33];
  const bool isW = blockIdx.y >= 32;
  const float* in = isW ? attW : attU;
  short* out = isW ? attWt : attUt;
  const int R = isW ? FF : HH;
  const int br = (isW ? (blockIdx.y - 32) : blockIdx.y) * 32;
  const int bc = blockIdx.x * 32;
  int tx = threadIdx.x & 31, ty4 = (threadIdx.x >> 5) << 2;
#pragma unroll
  for (int i = 0; i < 4; ++i)
    tile[ty4 + i][tx] = in[(size_t)(br + ty4 + i) * HH + bc + tx];
  __syncthreads();
#pragma unroll
  for (int i = 0; i < 4; ++i)
    out[(size_t)(bc + ty4 + i) * R + br + tx] = (short)bf16_rn(tile[tx][ty4 + i]);
}

// ---------------------------------------------------------------------------
// Fused elementwise prep, 8-wide vectorized.
// ---------------------------------------------------------------------------
#define S_FEATB   6422528ULL                       /* 64*49*2048      */
#define C1  (S_FEATB)
#define C2  (C1 + 12288000ULL)                     /* fc_W 12000*1024 */
#define C3  (C2 + 4194304ULL)                      /* W_hh 4096*1024  */
#define C4  (C3 + 2097152ULL)                      /* Wh0 1024*2048   */
#define C5  (C4 + 2097152ULL)                      /* Wc0 1024*2048   */
#define C6  (C5 + 2621440ULL)                      /* Wxg 4096*640    */
#define C7  (C6 + 8388608ULL)                      /* Wctx 4096*2048  */
#define C8  (C7 + 1310720ULL)                      /* xg 2048*640     */
#define C9  (C8 + 4096ULL)                         /* bg              */
#define C10 (C9 + 131072ULL)                       /* mean 64*2048    */

__global__ __launch_bounds__(256) void prep_k(
    const float* __restrict__ features, const float* __restrict__ fc_W,
    const float* __restrict__ W_hh, const float* __restrict__ Wh0,
    const float* __restrict__ Wc0, const float* __restrict__ W_ih,
    const int* __restrict__ captions, const float* __restrict__ emb,
    const float* __restrict__ cat,
    const float* __restrict__ b_ih, const float* __restrict__ b_hh,
    short* __restrict__ featb, short* __restrict__ fcWb,
    short* __restrict__ Whb, short* __restrict__ Wh0b,
    short* __restrict__ Wc0b, short* __restrict__ Wxg,
    short* __restrict__ Wctxb, short* __restrict__ xgH,
    short* __restrict__ xgL, float* __restrict__ bg,
    short* __restrict__ mfb)
{
  const size_t stride = (size_t)gridDim.x * 256;
  for (size_t ii = (size_t)blockIdx.x * 256 + threadIdx.x; ii < (C10 >> 3);
       ii += stride) {
    const size_t i = ii << 3;
    float f[8];
    if (i < C1) {
      *(float4*)&f[0] = *(const float4*)&features[i];
      *(float4*)&f[4] = *(const float4*)&features[i + 4];
      *(bf16x8*)&featb[i] = cvt8(f);
    } else if (i < C2) {
      const size_t j = i - C1;
      *(float4*)&f[0] = *(const float4*)&fc_W[j];
      *(float4*)&f[4] = *(const float4*)&fc_W[j + 4];
      *(bf16x8*)&fcWb[j] = cvt8(f);
    } else if (i < C3) {
      const size_t j = i - C2;
      *(float4*)&f[0] = *(const float4*)&W_hh[j];
      *(float4*)&f[4] = *(const float4*)&W_hh[j + 4];
      *(bf16x8*)&Whb[j] = cvt8(f);
    } else if (i < C4) {
      const size_t j = i - C3;
      *(float4*)&f[0] = *(const float4*)&Wh0[j];
      *(float4*)&f[4] = *(const float4*)&Wh0[j + 4];
      *(bf16x8*)&Wh0b[j] = cvt8(f);
    } else if (i < C5) {
      const size_t j = i - C4;
      *(float4*)&f[0] = *(const float4*)&Wc0[j];
      *(float4*)&f[4] = *(const float4*)&Wc0[j + 4];
      *(bf16x8*)&Wc0b[j] = cvt8(f);
    } else if (i < C6) {
      const size_t j = i - C5;
      const int n = (int)(j / XGLEN), k = (int)(j % XGLEN);
      const int ks = (k < EE) ? k : (EE + FF + (k - EE));
      const float* src = &W_ih[(size_t)n * XKLEN + ks];
      *(float4*)&f[0] = *(const float4*)&src[0];
      *(float4*)&f[4] = *(const float4*)&src[4];
      *(bf16x8*)&Wxg[j] = cvt8(f);
    } else if (i < C7) {
      const size_t j = i - C6;
      const int n = (int)(j / FF), k = (int)(j % FF);
      const float* src = &W_ih[(size_t)n * XKLEN + EE + k];
      *(float4*)&f[0] = *(const float4*)&src[0];
      *(float4*)&f[4] = *(const float4*)&src[4];
      *(bf16x8*)&Wctxb[j] = cvt8(f);
    } else if (i < C8) {
      const size_t j = i - C7;
      const int row = (int)(j / XGLEN), k = (int)(j % XGLEN);
      const int t = row >> 6, b = row & 63;
      const float* src;
      if (k < EE) {
        const int cap = captions[b * TT + t];
        src = &emb[(size_t)cap * EE + k];
      } else {
        src = &cat[(size_t)b * CDIM + (k - EE)];
      }
      *(float4*)&f[0] = *(const float4*)&src[0];
      *(float4*)&f[4] = *(const float4*)&src[4];
      bf16x8 hi8, lo8;
#pragma unroll
      for (int e = 0; e < 8; ++e) {
        short h, l2; split2(f[e], h, l2);
        hi8[e] = h; lo8[e] = l2;
      }
      *(bf16x8*)&xgH[j] = hi8;
      *(bf16x8*)&xgL[j] = lo8;
    } else if (i < C9) {
      const size_t j = i - C8;
      float4 a0 = *(const float4*)&b_ih[j];
      float4 a1 = *(const float4*)&b_ih[j + 4];
      float4 c0 = *(const float4*)&b_hh[j];
      float4 c1 = *(const float4*)&b_hh[j + 4];
      float4 o0 = make_float4(a0.x + c0.x, a0.y + c0.y, a0.z + c0.z, a0.w + c0.w);
      float4 o1 = make_float4(a1.x + c1.x, a1.y + c1.y, a1.z + c1.z, a1.w + c1.w);
      *(float4*)&bg[j] = o0;
      *(float4*)&bg[j + 4] = o1;
    } else {
      const size_t j = i - C9;
      const int b = (int)(j >> 11), f0 = (int)(j & 2047);
      float s[8] = {};
      for (int l = 0; l < LL; ++l) {
        const float* src = &features[((size_t)b * LL + l) * FF + f0];
        float4 u0 = *(const float4*)&src[0];
        float4 u1 = *(const float4*)&src[4];
        s[0] += u0.x; s[1] += u0.y; s[2] += u0.z; s[3] += u0.w;
        s[4] += u1.x; s[5] += u1.y; s[6] += u1.z; s[7] += u1.w;
      }
#pragma unroll
      for (int e = 0; e < 8; ++e) s[e] *= (1.f / 49.f);
      *(bf16x8*)&mfb[j] = cvt8(s);
    }
  }
}

extern "C" void kernel_launch(void* const* d_in, const int* in_sizes, int n_in,
                              void* d_out, int out_size, void* d_ws, size_t ws_size,
                              hipStream_t stream) {
  const int*   captions = (const int*)  d_in[0];
  const float* features = (const float*)d_in[1];
  const float* category = (const float*)d_in[2];
  const float* emb      = (const float*)d_in[3];
  const float* W_ih     = (const float*)d_in[4];
  const float* b_ih     = (const float*)d_in[5];
  const float* W_hh     = (const float*)d_in[6];
  const float* b_hh     = (const float*)d_in[7];
  const float* fc_W     = (const float*)d_in[8];
  const float* fc_b     = (const float*)d_in[9];
  const float* Wh0      = (const float*)d_in[10];
  const float* bh0      = (const float*)d_in[11];
  const float* Wc0      = (const float*)d_in[12];
  const float* bc0      = (const float*)d_in[13];
  const float* att_W    = (const float*)d_in[14];
  const float* att_U    = (const float*)d_in[15];
  const float* att_v    = (const float*)d_in[16];

  float* outs  = (float*)d_out;
  float* w_out = outs + (size_t)BB * TT * VV;

  char* p = (char*)d_ws;
  auto alloc = [&](size_t bytes) {
    char* q = p; p += (bytes + 255) & ~(size_t)255; return q;
  };
  short* attUt  = (short*)alloc((size_t)HH * HH * 2);
  short* attWt  = (short*)alloc((size_t)HH * FF * 2);
  short* featb  = (short*)alloc((size_t)BB * LL * FF * 2);   // prep only; reused as hall
  short* fcWb   = (short*)alloc((size_t)VV * HH * 2);
  short* Wctxb  = (short*)alloc((size_t)4096 * FF * 2);
  short* Whb    = (short*)alloc((size_t)4096 * HH * 2);
  short* Wxg    = (short*)alloc((size_t)4096 * XGLEN * 2);
  short* Wh0b   = (short*)alloc((size_t)HH * FF * 2);
  short* Wc0b   = (short*)alloc((size_t)HH * FF * 2);
  short* mfb    = (short*)alloc((size_t)BB * FF * 2);
  short* h0H    = (short*)alloc((size_t)BB * HH * 2);
  short* h0L    = (short*)alloc((size_t)BB * HH * 2);
  short* xgH    = (short*)alloc((size_t)2048 * XGLEN * 2);
  short* xgL    = (short*)alloc((size_t)2048 * XGLEN * 2);
  short* featpB = (short*)alloc((size_t)64 * 3136 * 16 * 2); // [nt][3136][16] bf16
  short* featCtx= (short*)alloc((size_t)64 * 3136 * 64 * 2);
  float* cbuf   = (float*)alloc((size_t)BB * HH * 4);
  float* partS  = (float*)alloc((size_t)64 * 3136 * 4);
  float* bg     = (float*)alloc(4096 * 4);
  // h history (= h(t) for t=0..31) aliases featb (dead after prep GEMMs).
  short* hallH = featb;
  short* hallL = featb + (size_t)TT * BB * HH;

  // ---- one-time prep: 4 dispatches ----
  prep_k<<<2048, 256, 0, stream>>>(
      features, fc_W, W_hh, Wh0, Wc0, W_ih, captions, emb, category,
      b_ih, b_hh,
      featb, fcWb, Whb, Wh0b, Wc0b, Wxg, Wctxb, xgH, xgL, bg, mfb);
  transpose2_k<<<dim3(32, 96), 256, 0, stream>>>(att_U, attUt, att_W, attWt);
  h0c0_k<<<64, 256, 0, stream>>>(mfb, Wh0b, bh0, Wc0b, bc0, h0H, h0L, cbuf);
  tgemm2_k<<<dim3(25, 40), 256, 0, stream>>>(featb, attWt, Wctxb, featpB, featCtx);

  // ---- timestep loop: 2 dispatches per step ----
  for (int t = 0; t < TT; ++t) {
    const short* hHi = (t == 0) ? h0H : hallH + (size_t)(t - 1) * BB * HH;
    const short* hLi = (t == 0) ? h0L : hallL + (size_t)(t - 1) * BB * HH;
    hupart_k<<<256, 256, 0, stream>>>(
        hHi, attUt, featpB, att_v, partS);
    glstm3_k<<<256, 256, 0, stream>>>(
        xgH, xgL, hHi, hLi, Wxg, Whb, featCtx, partS, bg, cbuf,
        hallH + (size_t)t * BB * HH, hallL + (size_t)t * BB * HH, w_out, t);
  }

  // ---- deferred batched fc ----
  bgemm_k<<<dim3(16, 94), 256, 0, stream>>>(hallH, hallL, fcWb, fc_b, outs);
}

// Round 19
// 1755.113 us; speedup vs baseline: 1.2335x; 1.0509x over previous
//
#include <hip/hip_runtime.h>
#include <hip/hip_bf16.h>

#define BB 64
#define TT 32
#define VV 12000
#define EE 512
#define FF 2048
#define CDIM 128
#define HH 1024
#define LL 49
#define XKLEN 2688   /* E + F + C */
#define XGLEN 640    /* E + C : per-step gathered input */

typedef __attribute__((ext_vector_type(8))) short bf16x8;
typedef __attribute__((ext_vector_type(4))) float f32x4;

__device__ __forceinline__ unsigned short bf16_rn(float x) {
  unsigned u = __float_as_uint(x);
  u += 0x7FFFu + ((u >> 16) & 1u);
  return (unsigned short)(u >> 16);
}
__device__ __forceinline__ float bf16_tof(unsigned short h) {
  return __uint_as_float(((unsigned)h) << 16);
}
__device__ __forceinline__ void split2(float x, short& hi, short& lo) {
  unsigned short h = bf16_rn(x);
  float r = x - bf16_tof(h);
  hi = (short)h;
  lo = (short)bf16_rn(r);
}
__device__ __forceinline__ bf16x8 cvt8(const float* f) {
  bf16x8 o;
#pragma unroll
  for (int e = 0; e < 8; ++e) o[e] = (short)bf16_rn(f[e]);
  return o;
}

// ---------------------------------------------------------------------------
// D1: hU tile + partial scores. Grid 256 (XCD-swizzled). hi-only MFMA.
// partS: [64 nt][64 b][49 l]; featpB: [64 nt][3136 row][16 a] bf16
// ---------------------------------------------------------------------------
__global__ __launch_bounds__(256) void hupart_k(
    const short* __restrict__ hHi,
    const short* __restrict__ attUt,   // [1024][1024] bf16 = att_U^T
    const short* __restrict__ featpB,  // [64][3136][16] bf16
    const float* __restrict__ att_v,
    float* __restrict__ partS)         // [64 nt][64 b][49 l]
{
  __shared__ float red[4][64][5];
  __shared__ float hu_s[16][17];
  __shared__ float av_s[16];
  const int tid = threadIdx.x;
  const int w = tid >> 6, lane = tid & 63;
  const int r = lane & 15, kg = lane >> 4;
  const int bid = blockIdx.x;
  const int id = (bid & 7) * 32 + (bid >> 3);
  const int nt = id >> 2, mh = id & 3;
  const int kb = w * 256;

  if (tid < 16) av_s[tid] = att_v[nt * 16 + tid];

  const short* wp = attUt + (size_t)(nt * 16 + r) * HH + kb + kg * 8;
  const short* ap = hHi + (size_t)(mh * 16 + r) * HH + kb + kg * 8;
  f32x4 acc = {};
#pragma unroll
  for (int k0 = 0; k0 < 256; k0 += 32) {
    bf16x8 bf = *(const bf16x8*)(wp + k0);
    bf16x8 af = *(const bf16x8*)(ap + k0);
    acc = __builtin_amdgcn_mfma_f32_16x16x32_bf16(af, bf, acc, 0, 0, 0);
  }
#pragma unroll
  for (int q = 0; q < 4; ++q)
    red[w][lane][q] = acc[q];
  __syncthreads();

  {
    const int bl = tid >> 4, a = tid & 15;
    const int sl = (bl >> 2) * 16 + a;
    const int ii = bl & 3;
    hu_s[bl][a] = red[0][sl][ii] + red[1][sl][ii] + red[2][sl][ii] + red[3][sl][ii];
  }
  __syncthreads();

  for (int task = tid; task < 16 * LL; task += 256) {
    const int bl = task / LL, l = task - bl * LL;
    const int b = mh * 16 + bl;
    const short* fp = featpB + ((size_t)nt * 3136 + (size_t)b * LL + l) * 16;
    bf16x8 v0 = *(const bf16x8*)&fp[0];
    bf16x8 v1 = *(const bf16x8*)&fp[8];
    float s = 0.f;
#pragma unroll
    for (int a = 0; a < 8; ++a)
      s += tanhf(bf16_tof((unsigned short)v0[a]) + hu_s[bl][a]) * av_s[a];
#pragma unroll
    for (int a = 0; a < 8; ++a)
      s += tanhf(bf16_tof((unsigned short)v1[a]) + hu_s[bl][8 + a]) * av_s[8 + a];
    partS[(size_t)nt * 3136 + (size_t)mh * 784 + task] = s;
  }
}

// ---------------------------------------------------------------------------
// D2: softmax + ctx-weighted-sum + gates MFMA (h-only, K=1024) + LSTM.
// xg contribution precomputed in gxg[2048][4096] f32 (includes bg).
// Grid 256 (XCD-swizzled). featCtx: [nt][3136][64]. h out to hall[t].
// ---------------------------------------------------------------------------
__global__ __launch_bounds__(256) void glstm3_k(
    const short* __restrict__ hHi, const short* __restrict__ hLi,  // [64][1024]
    const short* __restrict__ Whb,      // [4096][1024]
    const short* __restrict__ featCtx,  // [64][3136][64] bf16
    const float* __restrict__ partS,    // [64 nt][64 b][49 l]
    const float* __restrict__ gxg,      // [2048][4096] f32 = xg@Wxg^T + bg
    float* __restrict__ cbuf,
    short* __restrict__ hHo, short* __restrict__ hLo,
    float* __restrict__ w_out, int t)
{
  __shared__ float sw[16][52];
  __shared__ float ctx_p[2][16][72];
  __shared__ float red[3][64][17];
  const int tid = threadIdx.x;
  const int w = tid >> 6, lane = tid & 63;
  const int r = lane & 15, kg = lane >> 4;
  const int bid = blockIdx.x;
  const int id = (bid & 7) * 32 + (bid >> 3);
  const int nt = id >> 2, mq = id & 3;

  // Phase A: raw scores (coalesced nt-major reads)
  for (int idx = tid; idx < 16 * LL; idx += 256) {
    const float* ps = partS + (size_t)mq * 784 + idx;
    float s = 0.f;
#pragma unroll 8
    for (int a = 0; a < 64; ++a) s += ps[(size_t)a * 3136];
    sw[idx / LL][idx % LL] = s;
  }
  __syncthreads();
#pragma unroll
  for (int i = 0; i < 4; ++i) {
    const int bl = w * 4 + i;
    float v = (lane < LL) ? sw[bl][lane] : -1e30f;
    float m = v;
#pragma unroll
    for (int off = 32; off > 0; off >>= 1) m = fmaxf(m, __shfl_xor(m, off));
    float e = (lane < LL) ? expf(v - m) : 0.f;
    float s = e;
#pragma unroll
    for (int off = 32; off > 0; off >>= 1) s += __shfl_xor(s, off);
    float ww = e / s;
    if (lane < LL) {
      sw[bl][lane] = ww;
      if (nt == 0)
        w_out[((size_t)(mq * 16 + bl) * TT + t) * LL + lane] = ww;
    }
  }
  __syncthreads();

  // Phase B: ctx partials; 16B loads, 2-way l-split.
  {
    const int bl = tid >> 4, tsub = tid & 15;
    const int e8 = (tsub & 7) * 8, lpar = tsub >> 3;
    const size_t base =
        ((size_t)nt * 3136 + (size_t)(mq * 16 + bl) * LL) * 64 + e8;
    float s[8] = {};
    for (int l = lpar; l < LL; l += 2) {
      bf16x8 v = *(const bf16x8*)&featCtx[base + (size_t)l * 64];
      const float wl = sw[bl][l];
#pragma unroll
      for (int e = 0; e < 8; ++e)
        s[e] += wl * bf16_tof((unsigned short)v[e]);
    }
#pragma unroll
    for (int e = 0; e < 8; ++e)
      ctx_p[lpar][bl][e8 + e] = s[e];
  }

  // Phase C: gates MFMA over h only (K=1024), split 4 waves x 8 chunks
  const int brow = mq * 16 + r;
  f32x4 acc0 = {}, acc1 = {}, acc2 = {}, acc3 = {};
#pragma unroll
  for (int c = 0; c < 8; ++c) {
    const int hk = (w * 8 + c) * 32;
    const short* a_h = hHi + (size_t)brow * HH + hk + kg * 8;
    const short* a_l = hLi + (size_t)brow * HH + hk + kg * 8;
    const short* w0p = Whb + (size_t)(0 * 1024 + nt * 16 + r) * HH + hk + kg * 8;
    const short* w1p = Whb + (size_t)(1 * 1024 + nt * 16 + r) * HH + hk + kg * 8;
    const short* w2p = Whb + (size_t)(2 * 1024 + nt * 16 + r) * HH + hk + kg * 8;
    const short* w3p = Whb + (size_t)(3 * 1024 + nt * 16 + r) * HH + hk + kg * 8;
    bf16x8 af  = *(const bf16x8*)a_h;
    bf16x8 alf = *(const bf16x8*)a_l;
    bf16x8 b0 = *(const bf16x8*)w0p;
    acc0 = __builtin_amdgcn_mfma_f32_16x16x32_bf16(af,  b0, acc0, 0, 0, 0);
    acc0 = __builtin_amdgcn_mfma_f32_16x16x32_bf16(alf, b0, acc0, 0, 0, 0);
    bf16x8 b1 = *(const bf16x8*)w1p;
    acc1 = __builtin_amdgcn_mfma_f32_16x16x32_bf16(af,  b1, acc1, 0, 0, 0);
    acc1 = __builtin_amdgcn_mfma_f32_16x16x32_bf16(alf, b1, acc1, 0, 0, 0);
    bf16x8 b2 = *(const bf16x8*)w2p;
    acc2 = __builtin_amdgcn_mfma_f32_16x16x32_bf16(af,  b2, acc2, 0, 0, 0);
    acc2 = __builtin_amdgcn_mfma_f32_16x16x32_bf16(alf, b2, acc2, 0, 0, 0);
    bf16x8 b3 = *(const bf16x8*)w3p;
    acc3 = __builtin_amdgcn_mfma_f32_16x16x32_bf16(af,  b3, acc3, 0, 0, 0);
    acc3 = __builtin_amdgcn_mfma_f32_16x16x32_bf16(alf, b3, acc3, 0, 0, 0);
  }

  if (w != 0) {
#pragma unroll
    for (int q = 0; q < 4; ++q) {
      red[w - 1][lane][0 * 4 + q] = acc0[q];
      red[w - 1][lane][1 * 4 + q] = acc1[q];
      red[w - 1][lane][2 * 4 + q] = acc2[q];
      red[w - 1][lane][3 * 4 + q] = acc3[q];
    }
  }
  __syncthreads();
  if (w == 0) {
    const int j = nt * 16 + r;
#pragma unroll
    for (int q = 0; q < 4; ++q) {
      const int bl = kg * 4 + q;
      const int b = mq * 16 + bl;
      const float* gx = gxg + ((size_t)t * 64 + b) * 4096;
      float gi = acc0[q] + gx[0 * 1024 + j]
               + ctx_p[0][bl][0 * 16 + r] + ctx_p[1][bl][0 * 16 + r];
      float gf = acc1[q] + gx[1 * 1024 + j]
               + ctx_p[0][bl][1 * 16 + r] + ctx_p[1][bl][1 * 16 + r];
      float gg = acc2[q] + gx[2 * 1024 + j]
               + ctx_p[0][bl][2 * 16 + r] + ctx_p[1][bl][2 * 16 + r];
      float go = acc3[q] + gx[3 * 1024 + j]
               + ctx_p[0][bl][3 * 16 + r] + ctx_p[1][bl][3 * 16 + r];
#pragma unroll
      for (int p = 0; p < 3; ++p) {
        gi += red[p][lane][0 * 4 + q];
        gf += red[p][lane][1 * 4 + q];
        gg += red[p][lane][2 * 4 + q];
        go += red[p][lane][3 * 4 + q];
      }
      float si = 1.f / (1.f + expf(-gi));
      float sf = 1.f / (1.f + expf(-gf));
      float so = 1.f / (1.f + expf(-go));
      const size_t ci = (size_t)b * HH + j;
      float cc = sf * cbuf[ci] + si * tanhf(gg);
      float hh = so * tanhf(cc);
      cbuf[ci] = cc;
      short hi, lo; split2(hh, hi, lo);
      hHo[ci] = hi;
      hLo[ci] = lo;
    }
  }
}

// ---------------------------------------------------------------------------
// Combined prep GEMM: A=featb[3136][2048]; blockIdx.y<8 -> featpB (attWt,
// remap [nt][3136][16]); else -> featCtx (Wctxb, remap [nt][3136][64]).
// Grid (25, 40), 128x128 tile.
// ---------------------------------------------------------------------------
__global__ __launch_bounds__(256) void tgemm2_k(
    const short* __restrict__ A,
    const short* __restrict__ attWt,   // [1024][2048]
    const short* __restrict__ Wctxb,   // [4096][2048]
    short* __restrict__ featpB, short* __restrict__ featCtx)
{
  __shared__ short lA[128 * 40];
  __shared__ short lW[128 * 40];
  const int tid = threadIdx.x;
  const int w = tid >> 6, lane = tid & 63;
  const int r = lane & 15, kg = lane >> 4;
  const int M = BB * LL, K = FF;
  const bool ctx = (blockIdx.y >= 8);
  const short* Wb = ctx ? Wctxb : attWt;
  const int n0 = (ctx ? (blockIdx.y - 8) : blockIdx.y) * 128;
  const int m0 = blockIdx.x * 128;
  const int srow = tid >> 2, scol = (tid & 3) * 8;

  f32x4 acc[2][8] = {};
  for (int k0 = 0; k0 < K; k0 += 32) {
    __syncthreads();
#pragma unroll
    for (int j = 0; j < 2; ++j) {
      const int row = j * 64 + srow;
      int ar = m0 + row; if (ar >= M) ar = M - 1;
      bf16x8 va = *(const bf16x8*)&A[(size_t)ar * K + k0 + scol];
      bf16x8 vw = *(const bf16x8*)&Wb[(size_t)(n0 + row) * K + k0 + scol];
      *(bf16x8*)&lA[row * 40 + scol] = va;
      *(bf16x8*)&lW[row * 40 + scol] = vw;
    }
    __syncthreads();
    bf16x8 a0 = *(const bf16x8*)&lA[(w * 32 +  0 + r) * 40 + kg * 8];
    bf16x8 a1 = *(const bf16x8*)&lA[(w * 32 + 16 + r) * 40 + kg * 8];
#pragma unroll
    for (int nf = 0; nf < 8; ++nf) {
      bf16x8 wf = *(const bf16x8*)&lW[(nf * 16 + r) * 40 + kg * 8];
      acc[0][nf] = __builtin_amdgcn_mfma_f32_16x16x32_bf16(a0, wf, acc[0][nf], 0, 0, 0);
      acc[1][nf] = __builtin_amdgcn_mfma_f32_16x16x32_bf16(a1, wf, acc[1][nf], 0, 0, 0);
    }
  }
#pragma unroll
  for (int nf = 0; nf < 8; ++nf) {
    const int col = n0 + nf * 16 + r;
#pragma unroll
    for (int mf = 0; mf < 2; ++mf)
#pragma unroll
      for (int q = 0; q < 4; ++q) {
        const int grow = m0 + w * 32 + mf * 16 + kg * 4 + q;
        if (grow < M) {
          const short v = (short)bf16_rn(acc[mf][nf][q]);
          if (!ctx) {
            const int ntc = col >> 4, aa = col & 15;
            featpB[((size_t)ntc * 3136 + grow) * 16 + aa] = v;
          } else {
            const int gate = col >> 10, ntc = (col >> 4) & 63, jj = col & 15;
            featCtx[((size_t)ntc * 3136 + grow) * 64 + gate * 16 + jj] = v;
          }
        }
      }
  }
}

// ---------------------------------------------------------------------------
// Prep GEMM: gxg[2048][4096] = [xgH+xgL][2048][640] @ Wxg[4096][640]^T + bg.
// hi/lo two-pass, f32 out. Grid (16, 32), 128x128 tile, K=640.
// ---------------------------------------------------------------------------
__global__ __launch_bounds__(256) void tgemm3_k(
    const short* __restrict__ Ah, const short* __restrict__ Al,
    const short* __restrict__ Wb, const float* __restrict__ bias,
    float* __restrict__ outs)
{
  __shared__ short lAh[128 * 40];
  __shared__ short lAl[128 * 40];
  __shared__ short lW [128 * 40];
  const int tid = threadIdx.x;
  const int w = tid >> 6, lane = tid & 63;
  const int r = lane & 15, kg = lane >> 4;
  const int m0 = blockIdx.x * 128;
  const int n0 = blockIdx.y * 128;
  const int srow = tid >> 2, scol = (tid & 3) * 8;

  f32x4 acc[2][8] = {};
  for (int k0 = 0; k0 < XGLEN; k0 += 32) {
    __syncthreads();
#pragma unroll
    for (int j = 0; j < 2; ++j) {
      const int row = j * 64 + srow;
      bf16x8 va = *(const bf16x8*)&Ah[(size_t)(m0 + row) * XGLEN + k0 + scol];
      bf16x8 vl = *(const bf16x8*)&Al[(size_t)(m0 + row) * XGLEN + k0 + scol];
      bf16x8 vw = *(const bf16x8*)&Wb[(size_t)(n0 + row) * XGLEN + k0 + scol];
      *(bf16x8*)&lAh[row * 40 + scol] = va;
      *(bf16x8*)&lAl[row * 40 + scol] = vl;
      *(bf16x8*)&lW [row * 40 + scol] = vw;
    }
    __syncthreads();
    bf16x8 ah0 = *(const bf16x8*)&lAh[(w * 32 +  0 + r) * 40 + kg * 8];
    bf16x8 ah1 = *(const bf16x8*)&lAh[(w * 32 + 16 + r) * 40 + kg * 8];
    bf16x8 al0 = *(const bf16x8*)&lAl[(w * 32 +  0 + r) * 40 + kg * 8];
    bf16x8 al1 = *(const bf16x8*)&lAl[(w * 32 + 16 + r) * 40 + kg * 8];
#pragma unroll
    for (int nf = 0; nf < 8; ++nf) {
      bf16x8 wf = *(const bf16x8*)&lW[(nf * 16 + r) * 40 + kg * 8];
      acc[0][nf] = __builtin_amdgcn_mfma_f32_16x16x32_bf16(ah0, wf, acc[0][nf], 0, 0, 0);
      acc[0][nf] = __builtin_amdgcn_mfma_f32_16x16x32_bf16(al0, wf, acc[0][nf], 0, 0, 0);
      acc[1][nf] = __builtin_amdgcn_mfma_f32_16x16x32_bf16(ah1, wf, acc[1][nf], 0, 0, 0);
      acc[1][nf] = __builtin_amdgcn_mfma_f32_16x16x32_bf16(al1, wf, acc[1][nf], 0, 0, 0);
    }
  }
#pragma unroll
  for (int nf = 0; nf < 8; ++nf) {
    const int colv = n0 + nf * 16 + r;
    const float bv = bias[colv];
#pragma unroll
    for (int mf = 0; mf < 2; ++mf)
#pragma unroll
      for (int q = 0; q < 4; ++q) {
        const int grow = m0 + w * 32 + mf * 16 + kg * 4 + q;
        outs[(size_t)grow * 4096 + colv] = acc[mf][nf][q] + bv;
      }
  }
}

// ---------------------------------------------------------------------------
// Batched fc GEMM, LDS-staged 128x128 tile. Grid (16, 94).
// ---------------------------------------------------------------------------
__global__ __launch_bounds__(256) void bgemm_k(
    const short* __restrict__ Ah, const short* __restrict__ Al,
    const short* __restrict__ Wb, const float* __restrict__ bias,
    float* __restrict__ outs)
{
  __shared__ short lAh[128 * 40];
  __shared__ short lAl[128 * 40];
  __shared__ short lW [128 * 40];
  const int tid = threadIdx.x;
  const int w = tid >> 6, lane = tid & 63;
  const int r = lane & 15, kg = lane >> 4;
  const int m0 = blockIdx.x * 128;
  const int n0 = blockIdx.y * 128;
  const int srow = tid >> 2, scol = (tid & 3) * 8;

  f32x4 acc[2][8] = {};
  for (int k0 = 0; k0 < HH; k0 += 32) {
    __syncthreads();
#pragma unroll
    for (int j = 0; j < 2; ++j) {
      const int row = j * 64 + srow;
      bf16x8 va = *(const bf16x8*)&Ah[(size_t)(m0 + row) * HH + k0 + scol];
      bf16x8 vl = *(const bf16x8*)&Al[(size_t)(m0 + row) * HH + k0 + scol];
      int wr = n0 + row; if (wr >= VV) wr = VV - 1;
      bf16x8 vw = *(const bf16x8*)&Wb[(size_t)wr * HH + k0 + scol];
      *(bf16x8*)&lAh[row * 40 + scol] = va;
      *(bf16x8*)&lAl[row * 40 + scol] = vl;
      *(bf16x8*)&lW [row * 40 + scol] = vw;
    }
    __syncthreads();
    bf16x8 ah0 = *(const bf16x8*)&lAh[(w * 32 +  0 + r) * 40 + kg * 8];
    bf16x8 ah1 = *(const bf16x8*)&lAh[(w * 32 + 16 + r) * 40 + kg * 8];
    bf16x8 al0 = *(const bf16x8*)&lAl[(w * 32 +  0 + r) * 40 + kg * 8];
    bf16x8 al1 = *(const bf16x8*)&lAl[(w * 32 + 16 + r) * 40 + kg * 8];
#pragma unroll
    for (int nf = 0; nf < 8; ++nf) {
      bf16x8 wf = *(const bf16x8*)&lW[(nf * 16 + r) * 40 + kg * 8];
      acc[0][nf] = __builtin_amdgcn_mfma_f32_16x16x32_bf16(ah0, wf, acc[0][nf], 0, 0, 0);
      acc[0][nf] = __builtin_amdgcn_mfma_f32_16x16x32_bf16(al0, wf, acc[0][nf], 0, 0, 0);
      acc[1][nf] = __builtin_amdgcn_mfma_f32_16x16x32_bf16(ah1, wf, acc[1][nf], 0, 0, 0);
      acc[1][nf] = __builtin_amdgcn_mfma_f32_16x16x32_bf16(al1, wf, acc[1][nf], 0, 0, 0);
    }
  }
#pragma unroll
  for (int nf = 0; nf < 8; ++nf) {
    const int colv = n0 + nf * 16 + r;
    if (colv < VV) {
      const float bv = bias[colv];
#pragma unroll
      for (int mf = 0; mf < 2; ++mf)
#pragma unroll
        for (int q = 0; q < 4; ++q) {
          const int grow = m0 + w * 32 + mf * 16 + kg * 4 + q;  // = t*64 + b
          const int tt = grow >> 6, b = grow & 63;
          outs[((size_t)b * TT + tt) * VV + colv] = acc[mf][nf][q] + bv;
        }
    }
  }
}

// ---------------------------------------------------------------------------
// Fused h0/c0: grid 64; bid<32 -> h0 (split out), else c0 (f32 out).
// ---------------------------------------------------------------------------
__global__ __launch_bounds__(256) void h0c0_k(
    const short* __restrict__ mfb,
    const short* __restrict__ Wh0b, const float* __restrict__ bh0,
    const short* __restrict__ Wc0b, const float* __restrict__ bc0,
    short* __restrict__ h0H, short* __restrict__ h0L,
    float* __restrict__ cbuf)
{
  const int tid = threadIdx.x;
  const int w = tid >> 6, l = tid & 63;
  const int r = l & 15, kg = l >> 4;
  const bool cpath = blockIdx.x >= 32;
  const int nb = blockIdx.x & 31;
  const short* Wb = cpath ? Wc0b : Wh0b;
  const float* bias = cpath ? bc0 : bh0;
  const int nslice = w >> 1, mbase = (w & 1) * 2;
  const int n0 = nb * 32 + nslice * 16;
  const int nrow = n0 + r;
  const short* wp = Wb + (size_t)nrow * FF + kg * 8;
  const short* ap = mfb + (size_t)(mbase * 16 + r) * FF + kg * 8;
  f32x4 acc[2] = {};
  for (int k0 = 0; k0 < FF; k0 += 32) {
    bf16x8 bf = *(const bf16x8*)(wp + k0);
#pragma unroll
    for (int m = 0; m < 2; ++m) {
      bf16x8 af = *(const bf16x8*)(ap + (size_t)(16 * m) * FF + k0);
      acc[m] = __builtin_amdgcn_mfma_f32_16x16x32_bf16(af, bf, acc[m], 0, 0, 0);
    }
  }
  const float bv = bias[nrow];
#pragma unroll
  for (int m = 0; m < 2; ++m)
#pragma unroll
    for (int q = 0; q < 4; ++q) {
      const int mm = (mbase + m) * 16 + kg * 4 + q;
      const float v = acc[m][q] + bv;
      if (cpath) {
        cbuf[(size_t)mm * HH + nrow] = v;
      } else {
        short hi, lo; split2(v, hi, lo);
        h0H[(size_t)mm * HH + nrow] = hi;
        h0L[(size_t)mm * HH + nrow] = lo;
      }
    }
}

// ---------------------------------------------------------------------------
// Combined transpose+cast: grid (32, 96): y<32 -> att_U, else att_W.
// ---------------------------------------------------------------------------
__global__ __launch_bounds__(256) void transpose2_k(
    const float* __restrict__ attU, short* __restrict__ attUt,
    const float* __restrict__ attW, short* __restrict__ attWt)
{
  __shared__ float tile[32][33];
  const bool isW = blockIdx.y >= 32;
  const float* in = isW ? attW : attU;
  short* out = isW ? attWt : attUt;
  const int R = isW ? FF : HH;
  const int br = (isW ? (blockIdx.y - 32) : blockIdx.y) * 32;
  const int bc = blockIdx.x * 32;
  int tx = threadIdx.x & 31, ty4 = (threadIdx.x >> 5) << 2;
#pragma unroll
  for (int i = 0; i < 4; ++i)
    tile[ty4 + i][tx] = in[(size_t)(br + ty4 + i) * HH + bc + tx];
  __syncthreads();
#pragma unroll
  for (int i = 0; i < 4; ++i)
    out[(size_t)(bc + ty4 + i) * R + br + tx] = (short)bf16_rn(tile[tx][ty4 + i]);
}

// ---------------------------------------------------------------------------
// Fused elementwise prep, 8-wide vectorized.
// ---------------------------------------------------------------------------
#define S_FEATB   6422528ULL                       /* 64*49*2048      */
#define C1  (S_FEATB)
#define C2  (C1 + 12288000ULL)                     /* fc_W 12000*1024 */
#define C3  (C2 + 4194304ULL)                      /* W_hh 4096*1024  */
#define C4  (C3 + 2097152ULL)                      /* Wh0 1024*2048   */
#define C5  (C4 + 2097152ULL)                      /* Wc0 1024*2048   */
#define C6  (C5 + 2621440ULL)                      /* Wxg 4096*640    */
#define C7  (C6 + 8388608ULL)                      /* Wctx 4096*2048  */
#define C8  (C7 + 1310720ULL)                      /* xg 2048*640     */
#define C9  (C8 + 4096ULL)                         /* bg              */
#define C10 (C9 + 131072ULL)                       /* mean 64*2048    */

__global__ __launch_bounds__(256) void prep_k(
    const float* __restrict__ features, const float* __restrict__ fc_W,
    const float* __restrict__ W_hh, const float* __restrict__ Wh0,
    const float* __restrict__ Wc0, const float* __restrict__ W_ih,
    const int* __restrict__ captions, const float* __restrict__ emb,
    const float* __restrict__ cat,
    const float* __restrict__ b_ih, const float* __restrict__ b_hh,
    short* __restrict__ featb, short* __restrict__ fcWb,
    short* __restrict__ Whb, short* __restrict__ Wh0b,
    short* __restrict__ Wc0b, short* __restrict__ Wxg,
    short* __restrict__ Wctxb, short* __restrict__ xgH,
    short* __restrict__ xgL, float* __restrict__ bg,
    short* __restrict__ mfb)
{
  const size_t stride = (size_t)gridDim.x * 256;
  for (size_t ii = (size_t)blockIdx.x * 256 + threadIdx.x; ii < (C10 >> 3);
       ii += stride) {
    const size_t i = ii << 3;
    float f[8];
    if (i < C1) {
      *(float4*)&f[0] = *(const float4*)&features[i];
      *(float4*)&f[4] = *(const float4*)&features[i + 4];
      *(bf16x8*)&featb[i] = cvt8(f);
    } else if (i < C2) {
      const size_t j = i - C1;
      *(float4*)&f[0] = *(const float4*)&fc_W[j];
      *(float4*)&f[4] = *(const float4*)&fc_W[j + 4];
      *(bf16x8*)&fcWb[j] = cvt8(f);
    } else if (i < C3) {
      const size_t j = i - C2;
      *(float4*)&f[0] = *(const float4*)&W_hh[j];
      *(float4*)&f[4] = *(const float4*)&W_hh[j + 4];
      *(bf16x8*)&Whb[j] = cvt8(f);
    } else if (i < C4) {
      const size_t j = i - C3;
      *(float4*)&f[0] = *(const float4*)&Wh0[j];
      *(float4*)&f[4] = *(const float4*)&Wh0[j + 4];
      *(bf16x8*)&Wh0b[j] = cvt8(f);
    } else if (i < C5) {
      const size_t j = i - C4;
      *(float4*)&f[0] = *(const float4*)&Wc0[j];
      *(float4*)&f[4] = *(const float4*)&Wc0[j + 4];
      *(bf16x8*)&Wc0b[j] = cvt8(f);
    } else if (i < C6) {
      const size_t j = i - C5;
      const int n = (int)(j / XGLEN), k = (int)(j % XGLEN);
      const int ks = (k < EE) ? k : (EE + FF + (k - EE));
      const float* src = &W_ih[(size_t)n * XKLEN + ks];
      *(float4*)&f[0] = *(const float4*)&src[0];
      *(float4*)&f[4] = *(const float4*)&src[4];
      *(bf16x8*)&Wxg[j] = cvt8(f);
    } else if (i < C7) {
      const size_t j = i - C6;
      const int n = (int)(j / FF), k = (int)(j % FF);
      const float* src = &W_ih[(size_t)n * XKLEN + EE + k];
      *(float4*)&f[0] = *(const float4*)&src[0];
      *(float4*)&f[4] = *(const float4*)&src[4];
      *(bf16x8*)&Wctxb[j] = cvt8(f);
    } else if (i < C8) {
      const size_t j = i - C7;
      const int row = (int)(j / XGLEN), k = (int)(j % XGLEN);
      const int t = row >> 6, b = row & 63;
      const float* src;
      if (k < EE) {
        const int cap = captions[b * TT + t];
        src = &emb[(size_t)cap * EE + k];
      } else {
        src = &cat[(size_t)b * CDIM + (k - EE)];
      }
      *(float4*)&f[0] = *(const float4*)&src[0];
      *(float4*)&f[4] = *(const float4*)&src[4];
      bf16x8 hi8, lo8;
#pragma unroll
      for (int e = 0; e < 8; ++e) {
        short h, l2; split2(f[e], h, l2);
        hi8[e] = h; lo8[e] = l2;
      }
      *(bf16x8*)&xgH[j] = hi8;
      *(bf16x8*)&xgL[j] = lo8;
    } else if (i < C9) {
      const size_t j = i - C8;
      float4 a0 = *(const float4*)&b_ih[j];
      float4 a1 = *(const float4*)&b_ih[j + 4];
      float4 c0 = *(const float4*)&b_hh[j];
      float4 c1 = *(const float4*)&b_hh[j + 4];
      float4 o0 = make_float4(a0.x + c0.x, a0.y + c0.y, a0.z + c0.z, a0.w + c0.w);
      float4 o1 = make_float4(a1.x + c1.x, a1.y + c1.y, a1.z + c1.z, a1.w + c1.w);
      *(float4*)&bg[j] = o0;
      *(float4*)&bg[j + 4] = o1;
    } else {
      const size_t j = i - C9;
      const int b = (int)(j >> 11), f0 = (int)(j & 2047);
      float s[8] = {};
      for (int l = 0; l < LL; ++l) {
        const float* src = &features[((size_t)b * LL + l) * FF + f0];
        float4 u0 = *(const float4*)&src[0];
        float4 u1 = *(const float4*)&src[4];
        s[0] += u0.x; s[1] += u0.y; s[2] += u0.z; s[3] += u0.w;
        s[4] += u1.x; s[5] += u1.y; s[6] += u1.z; s[7] += u1.w;
      }
#pragma unroll
      for (int e = 0; e < 8; ++e) s[e] *= (1.f / 49.f);
      *(bf16x8*)&mfb[j] = cvt8(s);
    }
  }
}

extern "C" void kernel_launch(void* const* d_in, const int* in_sizes, int n_in,
                              void* d_out, int out_size, void* d_ws, size_t ws_size,
                              hipStream_t stream) {
  const int*   captions = (const int*)  d_in[0];
  const float* features = (const float*)d_in[1];
  const float* category = (const float*)d_in[2];
  const float* emb      = (const float*)d_in[3];
  const float* W_ih     = (const float*)d_in[4];
  const float* b_ih     = (const float*)d_in[5];
  const float* W_hh     = (const float*)d_in[6];
  const float* b_hh     = (const float*)d_in[7];
  const float* fc_W     = (const float*)d_in[8];
  const float* fc_b     = (const float*)d_in[9];
  const float* Wh0      = (const float*)d_in[10];
  const float* bh0      = (const float*)d_in[11];
  const float* Wc0      = (const float*)d_in[12];
  const float* bc0      = (const float*)d_in[13];
  const float* att_W    = (const float*)d_in[14];
  const float* att_U    = (const float*)d_in[15];
  const float* att_v    = (const float*)d_in[16];

  float* outs  = (float*)d_out;
  float* w_out = outs + (size_t)BB * TT * VV;

  char* p = (char*)d_ws;
  auto alloc = [&](size_t bytes) {
    char* q = p; p += (bytes + 255) & ~(size_t)255; return q;
  };
  short* attUt  = (short*)alloc((size_t)HH * HH * 2);
  short* attWt  = (short*)alloc((size_t)HH * FF * 2);
  short* featb  = (short*)alloc((size_t)BB * LL * FF * 2);   // prep only; reused as hall
  short* fcWb   = (short*)alloc((size_t)VV * HH * 2);
  short* Wctxb  = (short*)alloc((size_t)4096 * FF * 2);
  short* Whb    = (short*)alloc((size_t)4096 * HH * 2);
  short* Wxg    = (short*)alloc((size_t)4096 * XGLEN * 2);
  short* Wh0b   = (short*)alloc((size_t)HH * FF * 2);
  short* Wc0b   = (short*)alloc((size_t)HH * FF * 2);
  short* mfb    = (short*)alloc((size_t)BB * FF * 2);
  short* h0H    = (short*)alloc((size_t)BB * HH * 2);
  short* h0L    = (short*)alloc((size_t)BB * HH * 2);
  short* xgH    = (short*)alloc((size_t)2048 * XGLEN * 2);
  short* xgL    = (short*)alloc((size_t)2048 * XGLEN * 2);
  short* featpB = (short*)alloc((size_t)64 * 3136 * 16 * 2); // [nt][3136][16] bf16
  short* featCtx= (short*)alloc((size_t)64 * 3136 * 64 * 2);
  float* gxg    = (float*)alloc((size_t)2048 * 4096 * 4);    // xg@Wxg^T + bg
  float* cbuf   = (float*)alloc((size_t)BB * HH * 4);
  float* partS  = (float*)alloc((size_t)64 * 3136 * 4);
  float* bg     = (float*)alloc(4096 * 4);
  // h history (= h(t) for t=0..31) aliases featb (dead after prep GEMMs).
  short* hallH = featb;
  short* hallL = featb + (size_t)TT * BB * HH;

  // ---- one-time prep: 5 dispatches ----
  prep_k<<<2048, 256, 0, stream>>>(
      features, fc_W, W_hh, Wh0, Wc0, W_ih, captions, emb, category,
      b_ih, b_hh,
      featb, fcWb, Whb, Wh0b, Wc0b, Wxg, Wctxb, xgH, xgL, bg, mfb);
  transpose2_k<<<dim3(32, 96), 256, 0, stream>>>(att_U, attUt, att_W, attWt);
  h0c0_k<<<64, 256, 0, stream>>>(mfb, Wh0b, bh0, Wc0b, bc0, h0H, h0L, cbuf);
  tgemm2_k<<<dim3(25, 40), 256, 0, stream>>>(featb, attWt, Wctxb, featpB, featCtx);
  tgemm3_k<<<dim3(16, 32), 256, 0, stream>>>(xgH, xgL, Wxg, bg, gxg);

  // ---- timestep loop: 2 dispatches per step ----
  for (int t = 0; t < TT; ++t) {
    const short* hHi = (t == 0) ? h0H : hallH + (size_t)(t - 1) * BB * HH;
    const short* hLi = (t == 0) ? h0L : hallL + (size_t)(t - 1) * BB * HH;
    hupart_k<<<256, 256, 0, stream>>>(
        hHi, attUt, featpB, att_v, partS);
    glstm3_k<<<256, 256, 0, stream>>>(
        hHi, hLi, Whb, featCtx, partS, gxg, cbuf,
        hallH + (size_t)t * BB * HH, hallL + (size_t)t * BB * HH, w_out, t);
  }

  // ---- deferred batched fc ----
  bgemm_k<<<dim3(16, 94), 256, 0, stream>>>(hallH, hallL, fcWb, fc_b, outs);
}

// Round 20
// 1743.938 us; speedup vs baseline: 1.2414x; 1.0064x over previous
//
#include <hip/hip_runtime.h>
#include <hip/hip_bf16.h>

#define BB 64
#define TT 32
#define VV 12000
#define EE 512
#define FF 2048
#define CDIM 128
#define HH 1024
#define LL 49
#define XKLEN 2688   /* E + F + C */
#define XGLEN 640    /* E + C : per-step gathered input */

typedef __attribute__((ext_vector_type(8))) short bf16x8;
typedef __attribute__((ext_vector_type(4))) float f32x4;

__device__ __forceinline__ unsigned short bf16_rn(float x) {
  unsigned u = __float_as_uint(x);
  u += 0x7FFFu + ((u >> 16) & 1u);
  return (unsigned short)(u >> 16);
}
__device__ __forceinline__ float bf16_tof(unsigned short h) {
  return __uint_as_float(((unsigned)h) << 16);
}
__device__ __forceinline__ void split2(float x, short& hi, short& lo) {
  unsigned short h = bf16_rn(x);
  float r = x - bf16_tof(h);
  hi = (short)h;
  lo = (short)bf16_rn(r);
}
__device__ __forceinline__ bf16x8 cvt8(const float* f) {
  bf16x8 o;
#pragma unroll
  for (int e = 0; e < 8; ++e) o[e] = (short)bf16_rn(f[e]);
  return o;
}
// async global->LDS, 16B per lane; ldsptr must be wave-uniform (dest =
// base + lane*16), gptr is per-lane.
__device__ __forceinline__ void gload16(const void* g, void* l) {
  __builtin_amdgcn_global_load_lds(
      (const __attribute__((address_space(1))) void*)g,
      (__attribute__((address_space(3))) void*)l, 16, 0, 0);
}

// ---------------------------------------------------------------------------
// D1: hU tile + partial scores. Grid 256 (XCD-swizzled). hi-only MFMA.
// partS: [64 nt][64 b][49 l]; featpB: [64 nt][3136 row][16 a] bf16
// ---------------------------------------------------------------------------
__global__ __launch_bounds__(256) void hupart_k(
    const short* __restrict__ hHi,
    const short* __restrict__ attUt,   // [1024][1024] bf16 = att_U^T
    const short* __restrict__ featpB,  // [64][3136][16] bf16
    const float* __restrict__ att_v,
    float* __restrict__ partS)         // [64 nt][64 b][49 l]
{
  __shared__ float red[4][64][5];
  __shared__ float hu_s[16][17];
  __shared__ float av_s[16];
  const int tid = threadIdx.x;
  const int w = tid >> 6, lane = tid & 63;
  const int r = lane & 15, kg = lane >> 4;
  const int bid = blockIdx.x;
  const int id = (bid & 7) * 32 + (bid >> 3);
  const int nt = id >> 2, mh = id & 3;
  const int kb = w * 256;

  if (tid < 16) av_s[tid] = att_v[nt * 16 + tid];

  const short* wp = attUt + (size_t)(nt * 16 + r) * HH + kb + kg * 8;
  const short* ap = hHi + (size_t)(mh * 16 + r) * HH + kb + kg * 8;
  f32x4 acc = {};
#pragma unroll
  for (int k0 = 0; k0 < 256; k0 += 32) {
    bf16x8 bf = *(const bf16x8*)(wp + k0);
    bf16x8 af = *(const bf16x8*)(ap + k0);
    acc = __builtin_amdgcn_mfma_f32_16x16x32_bf16(af, bf, acc, 0, 0, 0);
  }
#pragma unroll
  for (int q = 0; q < 4; ++q)
    red[w][lane][q] = acc[q];
  __syncthreads();

  {
    const int bl = tid >> 4, a = tid & 15;
    const int sl = (bl >> 2) * 16 + a;
    const int ii = bl & 3;
    hu_s[bl][a] = red[0][sl][ii] + red[1][sl][ii] + red[2][sl][ii] + red[3][sl][ii];
  }
  __syncthreads();

  for (int task = tid; task < 16 * LL; task += 256) {
    const int bl = task / LL, l = task - bl * LL;
    const int b = mh * 16 + bl;
    const short* fp = featpB + ((size_t)nt * 3136 + (size_t)b * LL + l) * 16;
    bf16x8 v0 = *(const bf16x8*)&fp[0];
    bf16x8 v1 = *(const bf16x8*)&fp[8];
    float s = 0.f;
#pragma unroll
    for (int a = 0; a < 8; ++a)
      s += tanhf(bf16_tof((unsigned short)v0[a]) + hu_s[bl][a]) * av_s[a];
#pragma unroll
    for (int a = 0; a < 8; ++a)
      s += tanhf(bf16_tof((unsigned short)v1[a]) + hu_s[bl][8 + a]) * av_s[8 + a];
    partS[(size_t)nt * 3136 + (size_t)mh * 784 + task] = s;
  }
}

// ---------------------------------------------------------------------------
// D2: softmax + ctx-weighted-sum + gates MFMA (h-only, K=1024) + LSTM.
// xg contribution precomputed in gxg[2048][4096] f32 (includes bg).
// Grid 256 (XCD-swizzled). featCtx: [nt][3136][64]. h out to hall[t].
// ---------------------------------------------------------------------------
__global__ __launch_bounds__(256) void glstm3_k(
    const short* __restrict__ hHi, const short* __restrict__ hLi,  // [64][1024]
    const short* __restrict__ Whb,      // [4096][1024]
    const short* __restrict__ featCtx,  // [64][3136][64] bf16
    const float* __restrict__ partS,    // [64 nt][64 b][49 l]
    const float* __restrict__ gxg,      // [2048][4096] f32 = xg@Wxg^T + bg
    float* __restrict__ cbuf,
    short* __restrict__ hHo, short* __restrict__ hLo,
    float* __restrict__ w_out, int t)
{
  __shared__ float sw[16][52];
  __shared__ float ctx_p[2][16][72];
  __shared__ float red[3][64][17];
  const int tid = threadIdx.x;
  const int w = tid >> 6, lane = tid & 63;
  const int r = lane & 15, kg = lane >> 4;
  const int bid = blockIdx.x;
  const int id = (bid & 7) * 32 + (bid >> 3);
  const int nt = id >> 2, mq = id & 3;

  // Phase A: raw scores (coalesced nt-major reads)
  for (int idx = tid; idx < 16 * LL; idx += 256) {
    const float* ps = partS + (size_t)mq * 784 + idx;
    float s = 0.f;
#pragma unroll 8
    for (int a = 0; a < 64; ++a) s += ps[(size_t)a * 3136];
    sw[idx / LL][idx % LL] = s;
  }
  __syncthreads();
#pragma unroll
  for (int i = 0; i < 4; ++i) {
    const int bl = w * 4 + i;
    float v = (lane < LL) ? sw[bl][lane] : -1e30f;
    float m = v;
#pragma unroll
    for (int off = 32; off > 0; off >>= 1) m = fmaxf(m, __shfl_xor(m, off));
    float e = (lane < LL) ? expf(v - m) : 0.f;
    float s = e;
#pragma unroll
    for (int off = 32; off > 0; off >>= 1) s += __shfl_xor(s, off);
    float ww = e / s;
    if (lane < LL) {
      sw[bl][lane] = ww;
      if (nt == 0)
        w_out[((size_t)(mq * 16 + bl) * TT + t) * LL + lane] = ww;
    }
  }
  __syncthreads();

  // Phase B: ctx partials; 16B loads, 2-way l-split.
  {
    const int bl = tid >> 4, tsub = tid & 15;
    const int e8 = (tsub & 7) * 8, lpar = tsub >> 3;
    const size_t base =
        ((size_t)nt * 3136 + (size_t)(mq * 16 + bl) * LL) * 64 + e8;
    float s[8] = {};
    for (int l = lpar; l < LL; l += 2) {
      bf16x8 v = *(const bf16x8*)&featCtx[base + (size_t)l * 64];
      const float wl = sw[bl][l];
#pragma unroll
      for (int e = 0; e < 8; ++e)
        s[e] += wl * bf16_tof((unsigned short)v[e]);
    }
#pragma unroll
    for (int e = 0; e < 8; ++e)
      ctx_p[lpar][bl][e8 + e] = s[e];
  }

  // Phase C: gates MFMA over h only (K=1024), split 4 waves x 8 chunks
  const int brow = mq * 16 + r;
  f32x4 acc0 = {}, acc1 = {}, acc2 = {}, acc3 = {};
#pragma unroll
  for (int c = 0; c < 8; ++c) {
    const int hk = (w * 8 + c) * 32;
    const short* a_h = hHi + (size_t)brow * HH + hk + kg * 8;
    const short* a_l = hLi + (size_t)brow * HH + hk + kg * 8;
    const short* w0p = Whb + (size_t)(0 * 1024 + nt * 16 + r) * HH + hk + kg * 8;
    const short* w1p = Whb + (size_t)(1 * 1024 + nt * 16 + r) * HH + hk + kg * 8;
    const short* w2p = Whb + (size_t)(2 * 1024 + nt * 16 + r) * HH + hk + kg * 8;
    const short* w3p = Whb + (size_t)(3 * 1024 + nt * 16 + r) * HH + hk + kg * 8;
    bf16x8 af  = *(const bf16x8*)a_h;
    bf16x8 alf = *(const bf16x8*)a_l;
    bf16x8 b0 = *(const bf16x8*)w0p;
    acc0 = __builtin_amdgcn_mfma_f32_16x16x32_bf16(af,  b0, acc0, 0, 0, 0);
    acc0 = __builtin_amdgcn_mfma_f32_16x16x32_bf16(alf, b0, acc0, 0, 0, 0);
    bf16x8 b1 = *(const bf16x8*)w1p;
    acc1 = __builtin_amdgcn_mfma_f32_16x16x32_bf16(af,  b1, acc1, 0, 0, 0);
    acc1 = __builtin_amdgcn_mfma_f32_16x16x32_bf16(alf, b1, acc1, 0, 0, 0);
    bf16x8 b2 = *(const bf16x8*)w2p;
    acc2 = __builtin_amdgcn_mfma_f32_16x16x32_bf16(af,  b2, acc2, 0, 0, 0);
    acc2 = __builtin_amdgcn_mfma_f32_16x16x32_bf16(alf, b2, acc2, 0, 0, 0);
    bf16x8 b3 = *(const bf16x8*)w3p;
    acc3 = __builtin_amdgcn_mfma_f32_16x16x32_bf16(af,  b3, acc3, 0, 0, 0);
    acc3 = __builtin_amdgcn_mfma_f32_16x16x32_bf16(alf, b3, acc3, 0, 0, 0);
  }

  if (w != 0) {
#pragma unroll
    for (int q = 0; q < 4; ++q) {
      red[w - 1][lane][0 * 4 + q] = acc0[q];
      red[w - 1][lane][1 * 4 + q] = acc1[q];
      red[w - 1][lane][2 * 4 + q] = acc2[q];
      red[w - 1][lane][3 * 4 + q] = acc3[q];
    }
  }
  __syncthreads();
  if (w == 0) {
    const int j = nt * 16 + r;
#pragma unroll
    for (int q = 0; q < 4; ++q) {
      const int bl = kg * 4 + q;
      const int b = mq * 16 + bl;
      const float* gx = gxg + ((size_t)t * 64 + b) * 4096;
      float gi = acc0[q] + gx[0 * 1024 + j]
               + ctx_p[0][bl][0 * 16 + r] + ctx_p[1][bl][0 * 16 + r];
      float gf = acc1[q] + gx[1 * 1024 + j]
               + ctx_p[0][bl][1 * 16 + r] + ctx_p[1][bl][1 * 16 + r];
      float gg = acc2[q] + gx[2 * 1024 + j]
               + ctx_p[0][bl][2 * 16 + r] + ctx_p[1][bl][2 * 16 + r];
      float go = acc3[q] + gx[3 * 1024 + j]
               + ctx_p[0][bl][3 * 16 + r] + ctx_p[1][bl][3 * 16 + r];
#pragma unroll
      for (int p = 0; p < 3; ++p) {
        gi += red[p][lane][0 * 4 + q];
        gf += red[p][lane][1 * 4 + q];
        gg += red[p][lane][2 * 4 + q];
        go += red[p][lane][3 * 4 + q];
      }
      float si = 1.f / (1.f + expf(-gi));
      float sf = 1.f / (1.f + expf(-gf));
      float so = 1.f / (1.f + expf(-go));
      const size_t ci = (size_t)b * HH + j;
      float cc = sf * cbuf[ci] + si * tanhf(gg);
      float hh = so * tanhf(cc);
      cbuf[ci] = cc;
      short hi, lo; split2(hh, hi, lo);
      hHo[ci] = hi;
      hLo[ci] = lo;
    }
  }
}

// ---------------------------------------------------------------------------
// Combined prep GEMM (global_load_lds staging, linear LDS [128][32]):
// A=featb[3136][2048]; blockIdx.y<8 -> featpB (attWt, remap [nt][3136][16]);
// else -> featCtx (Wctxb, remap [nt][3136][64]). Grid (25, 40).
// ---------------------------------------------------------------------------
__global__ __launch_bounds__(256) void tgemm2_k(
    const short* __restrict__ A,
    const short* __restrict__ attWt,   // [1024][2048]
    const short* __restrict__ Wctxb,   // [4096][2048]
    short* __restrict__ featpB, short* __restrict__ featCtx)
{
  __shared__ short lA[128 * 32];
  __shared__ short lW[128 * 32];
  const int tid = threadIdx.x;
  const int w = tid >> 6, lane = tid & 63;
  const int r = lane & 15, kg = lane >> 4;
  const int M = BB * LL, K = FF;
  const bool ctx = (blockIdx.y >= 8);
  const short* Wb = ctx ? Wctxb : attWt;
  const int n0 = (ctx ? (blockIdx.y - 8) : blockIdx.y) * 128;
  const int m0 = blockIdx.x * 128;
  const int srow = tid >> 2, scol = (tid & 3) * 8;

  f32x4 acc[2][8] = {};
  for (int k0 = 0; k0 < K; k0 += 32) {
    __syncthreads();
#pragma unroll
    for (int j = 0; j < 2; ++j) {
      const int row = j * 64 + srow;
      int ar = m0 + row; if (ar >= M) ar = M - 1;
      const size_t lbase = (size_t)j * 4096 + (size_t)w * 1024;  // bytes
      gload16(&A[(size_t)ar * K + k0 + scol], (char*)lA + lbase);
      gload16(&Wb[(size_t)(n0 + row) * K + k0 + scol], (char*)lW + lbase);
    }
    __syncthreads();
    bf16x8 a0 = *(const bf16x8*)&lA[(w * 32 +  0 + r) * 32 + kg * 8];
    bf16x8 a1 = *(const bf16x8*)&lA[(w * 32 + 16 + r) * 32 + kg * 8];
#pragma unroll
    for (int nf = 0; nf < 8; ++nf) {
      bf16x8 wf = *(const bf16x8*)&lW[(nf * 16 + r) * 32 + kg * 8];
      acc[0][nf] = __builtin_amdgcn_mfma_f32_16x16x32_bf16(a0, wf, acc[0][nf], 0, 0, 0);
      acc[1][nf] = __builtin_amdgcn_mfma_f32_16x16x32_bf16(a1, wf, acc[1][nf], 0, 0, 0);
    }
  }
#pragma unroll
  for (int nf = 0; nf < 8; ++nf) {
    const int col = n0 + nf * 16 + r;
#pragma unroll
    for (int mf = 0; mf < 2; ++mf)
#pragma unroll
      for (int q = 0; q < 4; ++q) {
        const int grow = m0 + w * 32 + mf * 16 + kg * 4 + q;
        if (grow < M) {
          const short v = (short)bf16_rn(acc[mf][nf][q]);
          if (!ctx) {
            const int ntc = col >> 4, aa = col & 15;
            featpB[((size_t)ntc * 3136 + grow) * 16 + aa] = v;
          } else {
            const int gate = col >> 10, ntc = (col >> 4) & 63, jj = col & 15;
            featCtx[((size_t)ntc * 3136 + grow) * 64 + gate * 16 + jj] = v;
          }
        }
      }
  }
}

// ---------------------------------------------------------------------------
// Prep GEMM (global_load_lds): gxg[2048][4096] = [xg hi+lo]@Wxg^T + bg.
// Grid (16, 32), K=640.
// ---------------------------------------------------------------------------
__global__ __launch_bounds__(256) void tgemm3_k(
    const short* __restrict__ Ah, const short* __restrict__ Al,
    const short* __restrict__ Wb, const float* __restrict__ bias,
    float* __restrict__ outs)
{
  __shared__ short lAh[128 * 32];
  __shared__ short lAl[128 * 32];
  __shared__ short lW [128 * 32];
  const int tid = threadIdx.x;
  const int w = tid >> 6, lane = tid & 63;
  const int r = lane & 15, kg = lane >> 4;
  const int m0 = blockIdx.x * 128;
  const int n0 = blockIdx.y * 128;
  const int srow = tid >> 2, scol = (tid & 3) * 8;

  f32x4 acc[2][8] = {};
  for (int k0 = 0; k0 < XGLEN; k0 += 32) {
    __syncthreads();
#pragma unroll
    for (int j = 0; j < 2; ++j) {
      const int row = j * 64 + srow;
      const size_t lbase = (size_t)j * 4096 + (size_t)w * 1024;
      gload16(&Ah[(size_t)(m0 + row) * XGLEN + k0 + scol], (char*)lAh + lbase);
      gload16(&Al[(size_t)(m0 + row) * XGLEN + k0 + scol], (char*)lAl + lbase);
      gload16(&Wb[(size_t)(n0 + row) * XGLEN + k0 + scol], (char*)lW + lbase);
    }
    __syncthreads();
    bf16x8 ah0 = *(const bf16x8*)&lAh[(w * 32 +  0 + r) * 32 + kg * 8];
    bf16x8 ah1 = *(const bf16x8*)&lAh[(w * 32 + 16 + r) * 32 + kg * 8];
    bf16x8 al0 = *(const bf16x8*)&lAl[(w * 32 +  0 + r) * 32 + kg * 8];
    bf16x8 al1 = *(const bf16x8*)&lAl[(w * 32 + 16 + r) * 32 + kg * 8];
#pragma unroll
    for (int nf = 0; nf < 8; ++nf) {
      bf16x8 wf = *(const bf16x8*)&lW[(nf * 16 + r) * 32 + kg * 8];
      acc[0][nf] = __builtin_amdgcn_mfma_f32_16x16x32_bf16(ah0, wf, acc[0][nf], 0, 0, 0);
      acc[0][nf] = __builtin_amdgcn_mfma_f32_16x16x32_bf16(al0, wf, acc[0][nf], 0, 0, 0);
      acc[1][nf] = __builtin_amdgcn_mfma_f32_16x16x32_bf16(ah1, wf, acc[1][nf], 0, 0, 0);
      acc[1][nf] = __builtin_amdgcn_mfma_f32_16x16x32_bf16(al1, wf, acc[1][nf], 0, 0, 0);
    }
  }
#pragma unroll
  for (int nf = 0; nf < 8; ++nf) {
    const int colv = n0 + nf * 16 + r;
    const float bv = bias[colv];
#pragma unroll
    for (int mf = 0; mf < 2; ++mf)
#pragma unroll
      for (int q = 0; q < 4; ++q) {
        const int grow = m0 + w * 32 + mf * 16 + kg * 4 + q;
        outs[(size_t)grow * 4096 + colv] = acc[mf][nf][q] + bv;
      }
  }
}

// ---------------------------------------------------------------------------
// Batched fc GEMM (global_load_lds staging, linear LDS). Grid (16, 94).
// ---------------------------------------------------------------------------
__global__ __launch_bounds__(256) void bgemm_k(
    const short* __restrict__ Ah, const short* __restrict__ Al,
    const short* __restrict__ Wb, const float* __restrict__ bias,
    float* __restrict__ outs)
{
  __shared__ short lAh[128 * 32];
  __shared__ short lAl[128 * 32];
  __shared__ short lW [128 * 32];
  const int tid = threadIdx.x;
  const int w = tid >> 6, lane = tid & 63;
  const int r = lane & 15, kg = lane >> 4;
  const int m0 = blockIdx.x * 128;
  const int n0 = blockIdx.y * 128;
  const int srow = tid >> 2, scol = (tid & 3) * 8;

  f32x4 acc[2][8] = {};
  for (int k0 = 0; k0 < HH; k0 += 32) {
    __syncthreads();
#pragma unroll
    for (int j = 0; j < 2; ++j) {
      const int row = j * 64 + srow;
      int wr = n0 + row; if (wr >= VV) wr = VV - 1;
      const size_t lbase = (size_t)j * 4096 + (size_t)w * 1024;
      gload16(&Ah[(size_t)(m0 + row) * HH + k0 + scol], (char*)lAh + lbase);
      gload16(&Al[(size_t)(m0 + row) * HH + k0 + scol], (char*)lAl + lbase);
      gload16(&Wb[(size_t)wr * HH + k0 + scol], (char*)lW + lbase);
    }
    __syncthreads();
    bf16x8 ah0 = *(const bf16x8*)&lAh[(w * 32 +  0 + r) * 32 + kg * 8];
    bf16x8 ah1 = *(const bf16x8*)&lAh[(w * 32 + 16 + r) * 32 + kg * 8];
    bf16x8 al0 = *(const bf16x8*)&lAl[(w * 32 +  0 + r) * 32 + kg * 8];
    bf16x8 al1 = *(const bf16x8*)&lAl[(w * 32 + 16 + r) * 32 + kg * 8];
#pragma unroll
    for (int nf = 0; nf < 8; ++nf) {
      bf16x8 wf = *(const bf16x8*)&lW[(nf * 16 + r) * 32 + kg * 8];
      acc[0][nf] = __builtin_amdgcn_mfma_f32_16x16x32_bf16(ah0, wf, acc[0][nf], 0, 0, 0);
      acc[0][nf] = __builtin_amdgcn_mfma_f32_16x16x32_bf16(al0, wf, acc[0][nf], 0, 0, 0);
      acc[1][nf] = __builtin_amdgcn_mfma_f32_16x16x32_bf16(ah1, wf, acc[1][nf], 0, 0, 0);
      acc[1][nf] = __builtin_amdgcn_mfma_f32_16x16x32_bf16(al1, wf, acc[1][nf], 0, 0, 0);
    }
  }
#pragma unroll
  for (int nf = 0; nf < 8; ++nf) {
    const int colv = n0 + nf * 16 + r;
    if (colv < VV) {
      const float bv = bias[colv];
#pragma unroll
      for (int mf = 0; mf < 2; ++mf)
#pragma unroll
        for (int q = 0; q < 4; ++q) {
          const int grow = m0 + w * 32 + mf * 16 + kg * 4 + q;  // = t*64 + b
          const int tt = grow >> 6, b = grow & 63;
          outs[((size_t)b * TT + tt) * VV + colv] = acc[mf][nf][q] + bv;
        }
    }
  }
}

// ---------------------------------------------------------------------------
// Fused h0/c0: grid 64; bid<32 -> h0 (split out), else c0 (f32 out).
// ---------------------------------------------------------------------------
__global__ __launch_bounds__(256) void h0c0_k(
    const short* __restrict__ mfb,
    const short* __restrict__ Wh0b, const float* __restrict__ bh0,
    const short* __restrict__ Wc0b, const float* __restrict__ bc0,
    short* __restrict__ h0H, short* __restrict__ h0L,
    float* __restrict__ cbuf)
{
  const int tid = threadIdx.x;
  const int w = tid >> 6, l = tid & 63;
  const int r = l & 15, kg = l >> 4;
  const bool cpath = blockIdx.x >= 32;
  const int nb = blockIdx.x & 31;
  const short* Wb = cpath ? Wc0b : Wh0b;
  const float* bias = cpath ? bc0 : bh0;
  const int nslice = w >> 1, mbase = (w & 1) * 2;
  const int n0 = nb * 32 + nslice * 16;
  const int nrow = n0 + r;
  const short* wp = Wb + (size_t)nrow * FF + kg * 8;
  const short* ap = mfb + (size_t)(mbase * 16 + r) * FF + kg * 8;
  f32x4 acc[2] = {};
  for (int k0 = 0; k0 < FF; k0 += 32) {
    bf16x8 bf = *(const bf16x8*)(wp + k0);
#pragma unroll
    for (int m = 0; m < 2; ++m) {
      bf16x8 af = *(const bf16x8*)(ap + (size_t)(16 * m) * FF + k0);
      acc[m] = __builtin_amdgcn_mfma_f32_16x16x32_bf16(af, bf, acc[m], 0, 0, 0);
    }
  }
  const float bv = bias[nrow];
#pragma unroll
  for (int m = 0; m < 2; ++m)
#pragma unroll
    for (int q = 0; q < 4; ++q) {
      const int mm = (mbase + m) * 16 + kg * 4 + q;
      const float v = acc[m][q] + bv;
      if (cpath) {
        cbuf[(size_t)mm * HH + nrow] = v;
      } else {
        short hi, lo; split2(v, hi, lo);
        h0H[(size_t)mm * HH + nrow] = hi;
        h0L[(size_t)mm * HH + nrow] = lo;
      }
    }
}

// ---------------------------------------------------------------------------
// Combined transpose+cast: grid (32, 96): y<32 -> att_U, else att_W.
// ---------------------------------------------------------------------------
__global__ __launch_bounds__(256) void transpose2_k(
    const float* __restrict__ attU, short* __restrict__ attUt,
    const float* __restrict__ attW, short* __restrict__ attWt)
{
  __shared__ float tile[32][33];
  const bool isW = blockIdx.y >= 32;
  const float* in = isW ? attW : attU;
  short* out = isW ? attWt : attUt;
  const int R = isW ? FF : HH;
  const int br = (isW ? (blockIdx.y - 32) : blockIdx.y) * 32;
  const int bc = blockIdx.x * 32;
  int tx = threadIdx.x & 31, ty4 = (threadIdx.x >> 5) << 2;
#pragma unroll
  for (int i = 0; i < 4; ++i)
    tile[ty4 + i][tx] = in[(size_t)(br + ty4 + i) * HH + bc + tx];
  __syncthreads();
#pragma unroll
  for (int i = 0; i < 4; ++i)
    out[(size_t)(bc + ty4 + i) * R + br + tx] = (short)bf16_rn(tile[tx][ty4 + i]);
}

// ---------------------------------------------------------------------------
// Fused elementwise prep, 8-wide vectorized.
// ---------------------------------------------------------------------------
#define S_FEATB   6422528ULL                       /* 64*49*2048      */
#define C1  (S_FEATB)
#define C2  (C1 + 12288000ULL)                     /* fc_W 12000*1024 */
#define C3  (C2 + 4194304ULL)                      /* W_hh 4096*1024  */
#define C4  (C3 + 2097152ULL)                      /* Wh0 1024*2048   */
#define C5  (C4 + 2097152ULL)                      /* Wc0 1024*2048   */
#define C6  (C5 + 2621440ULL)                      /* Wxg 4096*640    */
#define C7  (C6 + 8388608ULL)                      /* Wctx 4096*2048  */
#define C8  (C7 + 1310720ULL)                      /* xg 2048*640     */
#define C9  (C8 + 4096ULL)                         /* bg              */
#define C10 (C9 + 131072ULL)                       /* mean 64*2048    */

__global__ __launch_bounds__(256) void prep_k(
    const float* __restrict__ features, const float* __restrict__ fc_W,
    const float* __restrict__ W_hh, const float* __restrict__ Wh0,
    const float* __restrict__ Wc0, const float* __restrict__ W_ih,
    const int* __restrict__ captions, const float* __restrict__ emb,
    const float* __restrict__ cat,
    const float* __restrict__ b_ih, const float* __restrict__ b_hh,
    short* __restrict__ featb, short* __restrict__ fcWb,
    short* __restrict__ Whb, short* __restrict__ Wh0b,
    short* __restrict__ Wc0b, short* __restrict__ Wxg,
    short* __restrict__ Wctxb, short* __restrict__ xgH,
    short* __restrict__ xgL, float* __restrict__ bg,
    short* __restrict__ mfb)
{
  const size_t stride = (size_t)gridDim.x * 256;
  for (size_t ii = (size_t)blockIdx.x * 256 + threadIdx.x; ii < (C10 >> 3);
       ii += stride) {
    const size_t i = ii << 3;
    float f[8];
    if (i < C1) {
      *(float4*)&f[0] = *(const float4*)&features[i];
      *(float4*)&f[4] = *(const float4*)&features[i + 4];
      *(bf16x8*)&featb[i] = cvt8(f);
    } else if (i < C2) {
      const size_t j = i - C1;
      *(float4*)&f[0] = *(const float4*)&fc_W[j];
      *(float4*)&f[4] = *(const float4*)&fc_W[j + 4];
      *(bf16x8*)&fcWb[j] = cvt8(f);
    } else if (i < C3) {
      const size_t j = i - C2;
      *(float4*)&f[0] = *(const float4*)&W_hh[j];
      *(float4*)&f[4] = *(const float4*)&W_hh[j + 4];
      *(bf16x8*)&Whb[j] = cvt8(f);
    } else if (i < C4) {
      const size_t j = i - C3;
      *(float4*)&f[0] = *(const float4*)&Wh0[j];
      *(float4*)&f[4] = *(const float4*)&Wh0[j + 4];
      *(bf16x8*)&Wh0b[j] = cvt8(f);
    } else if (i < C5) {
      const size_t j = i - C4;
      *(float4*)&f[0] = *(const float4*)&Wc0[j];
      *(float4*)&f[4] = *(const float4*)&Wc0[j + 4];
      *(bf16x8*)&Wc0b[j] = cvt8(f);
    } else if (i < C6) {
      const size_t j = i - C5;
      const int n = (int)(j / XGLEN), k = (int)(j % XGLEN);
      const int ks = (k < EE) ? k : (EE + FF + (k - EE));
      const float* src = &W_ih[(size_t)n * XKLEN + ks];
      *(float4*)&f[0] = *(const float4*)&src[0];
      *(float4*)&f[4] = *(const float4*)&src[4];
      *(bf16x8*)&Wxg[j] = cvt8(f);
    } else if (i < C7) {
      const size_t j = i - C6;
      const int n = (int)(j / FF), k = (int)(j % FF);
      const float* src = &W_ih[(size_t)n * XKLEN + EE + k];
      *(float4*)&f[0] = *(const float4*)&src[0];
      *(float4*)&f[4] = *(const float4*)&src[4];
      *(bf16x8*)&Wctxb[j] = cvt8(f);
    } else if (i < C8) {
      const size_t j = i - C7;
      const int row = (int)(j / XGLEN), k = (int)(j % XGLEN);
      const int t = row >> 6, b = row & 63;
      const float* src;
      if (k < EE) {
        const int cap = captions[b * TT + t];
        src = &emb[(size_t)cap * EE + k];
      } else {
        src = &cat[(size_t)b * CDIM + (k - EE)];
      }
      *(float4*)&f[0] = *(const float4*)&src[0];
      *(float4*)&f[4] = *(const float4*)&src[4];
      bf16x8 hi8, lo8;
#pragma unroll
      for (int e = 0; e < 8; ++e) {
        short h, l2; split2(f[e], h, l2);
        hi8[e] = h; lo8[e] = l2;
      }
      *(bf16x8*)&xgH[j] = hi8;
      *(bf16x8*)&xgL[j] = lo8;
    } else if (i < C9) {
      const size_t j = i - C8;
      float4 a0 = *(const float4*)&b_ih[j];
      float4 a1 = *(const float4*)&b_ih[j + 4];
      float4 c0 = *(const float4*)&b_hh[j];
      float4 c1 = *(const float4*)&b_hh[j + 4];
      float4 o0 = make_float4(a0.x + c0.x, a0.y + c0.y, a0.z + c0.z, a0.w + c0.w);
      float4 o1 = make_float4(a1.x + c1.x, a1.y + c1.y, a1.z + c1.z, a1.w + c1.w);
      *(float4*)&bg[j] = o0;
      *(float4*)&bg[j + 4] = o1;
    } else {
      const size_t j = i - C9;
      const int b = (int)(j >> 11), f0 = (int)(j & 2047);
      float s[8] = {};
      for (int l = 0; l < LL; ++l) {
        const float* src = &features[((size_t)b * LL + l) * FF + f0];
        float4 u0 = *(const float4*)&src[0];
        float4 u1 = *(const float4*)&src[4];
        s[0] += u0.x; s[1] += u0.y; s[2] += u0.z; s[3] += u0.w;
        s[4] += u1.x; s[5] += u1.y; s[6] += u1.z; s[7] += u1.w;
      }
#pragma unroll
      for (int e = 0; e < 8; ++e) s[e] *= (1.f / 49.f);
      *(bf16x8*)&mfb[j] = cvt8(s);
    }
  }
}

extern "C" void kernel_launch(void* const* d_in, const int* in_sizes, int n_in,
                              void* d_out, int out_size, void* d_ws, size_t ws_size,
                              hipStream_t stream) {
  const int*   captions = (const int*)  d_in[0];
  const float* features = (const float*)d_in[1];
  const float* category = (const float*)d_in[2];
  const float* emb      = (const float*)d_in[3];
  const float* W_ih     = (const float*)d_in[4];
  const float* b_ih     = (const float*)d_in[5];
  const float* W_hh     = (const float*)d_in[6];
  const float* b_hh     = (const float*)d_in[7];
  const float* fc_W     = (const float*)d_in[8];
  const float* fc_b     = (const float*)d_in[9];
  const float* Wh0      = (const float*)d_in[10];
  const float* bh0      = (const float*)d_in[11];
  const float* Wc0      = (const float*)d_in[12];
  const float* bc0      = (const float*)d_in[13];
  const float* att_W    = (const float*)d_in[14];
  const float* att_U    = (const float*)d_in[15];
  const float* att_v    = (const float*)d_in[16];

  float* outs  = (float*)d_out;
  float* w_out = outs + (size_t)BB * TT * VV;

  char* p = (char*)d_ws;
  auto alloc = [&](size_t bytes) {
    char* q = p; p += (bytes + 255) & ~(size_t)255; return q;
  };
  short* attUt  = (short*)alloc((size_t)HH * HH * 2);
  short* attWt  = (short*)alloc((size_t)HH * FF * 2);
  short* featb  = (short*)alloc((size_t)BB * LL * FF * 2);   // prep only; reused as hall
  short* fcWb   = (short*)alloc((size_t)VV * HH * 2);
  short* Wctxb  = (short*)alloc((size_t)4096 * FF * 2);
  short* Whb    = (short*)alloc((size_t)4096 * HH * 2);
  short* Wxg    = (short*)alloc((size_t)4096 * XGLEN * 2);
  short* Wh0b   = (short*)alloc((size_t)HH * FF * 2);
  short* Wc0b   = (short*)alloc((size_t)HH * FF * 2);
  short* mfb    = (short*)alloc((size_t)BB * FF * 2);
  short* h0H    = (short*)alloc((size_t)BB * HH * 2);
  short* h0L    = (short*)alloc((size_t)BB * HH * 2);
  short* xgH    = (short*)alloc((size_t)2048 * XGLEN * 2);
  short* xgL    = (short*)alloc((size_t)2048 * XGLEN * 2);
  short* featpB = (short*)alloc((size_t)64 * 3136 * 16 * 2); // [nt][3136][16] bf16
  short* featCtx= (short*)alloc((size_t)64 * 3136 * 64 * 2);
  float* gxg    = (float*)alloc((size_t)2048 * 4096 * 4);    // xg@Wxg^T + bg
  float* cbuf   = (float*)alloc((size_t)BB * HH * 4);
  float* partS  = (float*)alloc((size_t)64 * 3136 * 4);
  float* bg     = (float*)alloc(4096 * 4);
  // h history (= h(t) for t=0..31) aliases featb (dead after prep GEMMs).
  short* hallH = featb;
  short* hallL = featb + (size_t)TT * BB * HH;

  // ---- one-time prep: 5 dispatches ----
  prep_k<<<2048, 256, 0, stream>>>(
      features, fc_W, W_hh, Wh0, Wc0, W_ih, captions, emb, category,
      b_ih, b_hh,
      featb, fcWb, Whb, Wh0b, Wc0b, Wxg, Wctxb, xgH, xgL, bg, mfb);
  transpose2_k<<<dim3(32, 96), 256, 0, stream>>>(att_U, attUt, att_W, attWt);
  h0c0_k<<<64, 256, 0, stream>>>(mfb, Wh0b, bh0, Wc0b, bc0, h0H, h0L, cbuf);
  tgemm2_k<<<dim3(25, 40), 256, 0, stream>>>(featb, attWt, Wctxb, featpB, featCtx);
  tgemm3_k<<<dim3(16, 32), 256, 0, stream>>>(xgH, xgL, Wxg, bg, gxg);

  // ---- timestep loop: 2 dispatches per step ----
  for (int t = 0; t < TT; ++t) {
    const short* hHi = (t == 0) ? h0H : hallH + (size_t)(t - 1) * BB * HH;
    const short* hLi = (t == 0) ? h0L : hallL + (size_t)(t - 1) * BB * HH;
    hupart_k<<<256, 256, 0, stream>>>(
        hHi, attUt, featpB, att_v, partS);
    glstm3_k<<<256, 256, 0, stream>>>(
        hHi, hLi, Whb, featCtx, partS, gxg, cbuf,
        hallH + (size_t)t * BB * HH, hallL + (size_t)t * BB * HH, w_out, t);
  }

  // ---- deferred batched fc ----
  bgemm_k<<<dim3(16, 94), 256, 0, stream>>>(hallH, hallL, fcWb, fc_b, outs);
}

// Round 21
// 1582.225 us; speedup vs baseline: 1.3683x; 1.1022x over previous
//
#include <hip/hip_runtime.h>
#include <hip/hip_bf16.h>

#define BB 64
#define TT 32
#define VV 12000
#define EE 512
#define FF 2048
#define CDIM 128
#define HH 1024
#define LL 49
#define XKLEN 2688   /* E + F + C */
#define XGLEN 640    /* E + C : per-step gathered input */

typedef __attribute__((ext_vector_type(8))) short bf16x8;
typedef __attribute__((ext_vector_type(4))) float f32x4;

__device__ __forceinline__ unsigned short bf16_rn(float x) {
  unsigned u = __float_as_uint(x);
  u += 0x7FFFu + ((u >> 16) & 1u);
  return (unsigned short)(u >> 16);
}
__device__ __forceinline__ float bf16_tof(unsigned short h) {
  return __uint_as_float(((unsigned)h) << 16);
}
__device__ __forceinline__ void split2(float x, short& hi, short& lo) {
  unsigned short h = bf16_rn(x);
  float r = x - bf16_tof(h);
  hi = (short)h;
  lo = (short)bf16_rn(r);
}
__device__ __forceinline__ bf16x8 cvt8(const float* f) {
  bf16x8 o;
#pragma unroll
  for (int e = 0; e < 8; ++e) o[e] = (short)bf16_rn(f[e]);
  return o;
}
__device__ __forceinline__ void gload16(const void* g, void* l) {
  __builtin_amdgcn_global_load_lds(
      (const __attribute__((address_space(1))) void*)g,
      (__attribute__((address_space(3))) void*)l, 16, 0, 0);
}

// ---------------------------------------------------------------------------
// STEP1 (512 blocks): both halves depend only on h(t-1).
//  blocks 0..255  : hU tile + partial scores -> partS [64 nt][64 b][49 l]
//  blocks 256..511: gates MFMA h@Whb^T (hi/lo) + LDS reduce -> ghh[64][4096]
// ---------------------------------------------------------------------------
__global__ __launch_bounds__(256) void step1_k(
    const short* __restrict__ hHi, const short* __restrict__ hLi,
    const short* __restrict__ attUt,   // [1024][1024] bf16
    const short* __restrict__ featpB,  // [64][3136][16] bf16
    const float* __restrict__ att_v,
    const short* __restrict__ Whb,     // [4096][1024] bf16
    float* __restrict__ partS,         // [64][64][49]
    float* __restrict__ ghh)           // [64][4096] f32
{
  __shared__ float red4[4][64][5];
  __shared__ float hu_s[16][17];
  __shared__ float av_s[16];
  __shared__ float red3[3][64][17];
  const int tid = threadIdx.x;
  const int w = tid >> 6, lane = tid & 63;
  const int r = lane & 15, kg = lane >> 4;

  if (blockIdx.x < 256) {
    // ---- hupart half ----
    const int bid = blockIdx.x;
    const int id = (bid & 7) * 32 + (bid >> 3);
    const int nt = id >> 2, mh = id & 3;
    const int kb = w * 256;

    if (tid < 16) av_s[tid] = att_v[nt * 16 + tid];

    const short* wp = attUt + (size_t)(nt * 16 + r) * HH + kb + kg * 8;
    const short* ap = hHi + (size_t)(mh * 16 + r) * HH + kb + kg * 8;
    f32x4 acc = {};
#pragma unroll
    for (int k0 = 0; k0 < 256; k0 += 32) {
      bf16x8 bf = *(const bf16x8*)(wp + k0);
      bf16x8 af = *(const bf16x8*)(ap + k0);
      acc = __builtin_amdgcn_mfma_f32_16x16x32_bf16(af, bf, acc, 0, 0, 0);
    }
#pragma unroll
    for (int q = 0; q < 4; ++q)
      red4[w][lane][q] = acc[q];
    __syncthreads();

    {
      const int bl = tid >> 4, a = tid & 15;
      const int sl = (bl >> 2) * 16 + a;
      const int ii = bl & 3;
      hu_s[bl][a] = red4[0][sl][ii] + red4[1][sl][ii]
                  + red4[2][sl][ii] + red4[3][sl][ii];
    }
    __syncthreads();

    for (int task = tid; task < 16 * LL; task += 256) {
      const int bl = task / LL, l = task - bl * LL;
      const int b = mh * 16 + bl;
      const short* fp = featpB + ((size_t)nt * 3136 + (size_t)b * LL + l) * 16;
      bf16x8 v0 = *(const bf16x8*)&fp[0];
      bf16x8 v1 = *(const bf16x8*)&fp[8];
      float s = 0.f;
#pragma unroll
      for (int a = 0; a < 8; ++a)
        s += tanhf(bf16_tof((unsigned short)v0[a]) + hu_s[bl][a]) * av_s[a];
#pragma unroll
      for (int a = 0; a < 8; ++a)
        s += tanhf(bf16_tof((unsigned short)v1[a]) + hu_s[bl][8 + a]) * av_s[8 + a];
      partS[(size_t)nt * 3136 + (size_t)mh * 784 + task] = s;
    }
  } else {
    // ---- gates half: ghh = h @ Whb^T (K=1024, split 4 waves x 8 chunks) ----
    const int bid = blockIdx.x - 256;
    const int id = (bid & 7) * 32 + (bid >> 3);
    const int nt = id >> 2, mq = id & 3;
    const int brow = mq * 16 + r;
    f32x4 acc0 = {}, acc1 = {}, acc2 = {}, acc3 = {};
#pragma unroll
    for (int c = 0; c < 8; ++c) {
      const int hk = (w * 8 + c) * 32;
      const short* a_h = hHi + (size_t)brow * HH + hk + kg * 8;
      const short* a_l = hLi + (size_t)brow * HH + hk + kg * 8;
      const short* w0p = Whb + (size_t)(0 * 1024 + nt * 16 + r) * HH + hk + kg * 8;
      const short* w1p = Whb + (size_t)(1 * 1024 + nt * 16 + r) * HH + hk + kg * 8;
      const short* w2p = Whb + (size_t)(2 * 1024 + nt * 16 + r) * HH + hk + kg * 8;
      const short* w3p = Whb + (size_t)(3 * 1024 + nt * 16 + r) * HH + hk + kg * 8;
      bf16x8 af  = *(const bf16x8*)a_h;
      bf16x8 alf = *(const bf16x8*)a_l;
      bf16x8 b0 = *(const bf16x8*)w0p;
      acc0 = __builtin_amdgcn_mfma_f32_16x16x32_bf16(af,  b0, acc0, 0, 0, 0);
      acc0 = __builtin_amdgcn_mfma_f32_16x16x32_bf16(alf, b0, acc0, 0, 0, 0);
      bf16x8 b1 = *(const bf16x8*)w1p;
      acc1 = __builtin_amdgcn_mfma_f32_16x16x32_bf16(af,  b1, acc1, 0, 0, 0);
      acc1 = __builtin_amdgcn_mfma_f32_16x16x32_bf16(alf, b1, acc1, 0, 0, 0);
      bf16x8 b2 = *(const bf16x8*)w2p;
      acc2 = __builtin_amdgcn_mfma_f32_16x16x32_bf16(af,  b2, acc2, 0, 0, 0);
      acc2 = __builtin_amdgcn_mfma_f32_16x16x32_bf16(alf, b2, acc2, 0, 0, 0);
      bf16x8 b3 = *(const bf16x8*)w3p;
      acc3 = __builtin_amdgcn_mfma_f32_16x16x32_bf16(af,  b3, acc3, 0, 0, 0);
      acc3 = __builtin_amdgcn_mfma_f32_16x16x32_bf16(alf, b3, acc3, 0, 0, 0);
    }
    if (w != 0) {
#pragma unroll
      for (int q = 0; q < 4; ++q) {
        red3[w - 1][lane][0 * 4 + q] = acc0[q];
        red3[w - 1][lane][1 * 4 + q] = acc1[q];
        red3[w - 1][lane][2 * 4 + q] = acc2[q];
        red3[w - 1][lane][3 * 4 + q] = acc3[q];
      }
    }
    __syncthreads();
    if (w == 0) {
      const int j = nt * 16 + r;
#pragma unroll
      for (int q = 0; q < 4; ++q) {
        const int b = mq * 16 + kg * 4 + q;
        float g0 = acc0[q], g1 = acc1[q], g2 = acc2[q], g3 = acc3[q];
#pragma unroll
        for (int p = 0; p < 3; ++p) {
          g0 += red3[p][lane][0 * 4 + q];
          g1 += red3[p][lane][1 * 4 + q];
          g2 += red3[p][lane][2 * 4 + q];
          g3 += red3[p][lane][3 * 4 + q];
        }
        float* gh = ghh + (size_t)b * 4096;
        gh[0 * 1024 + j] = g0;
        gh[1 * 1024 + j] = g1;
        gh[2 * 1024 + j] = g2;
        gh[3 * 1024 + j] = g3;
      }
    }
  }
}

// ---------------------------------------------------------------------------
// STEP2 (256 blocks): score-sum + softmax + ctx weighted-sum + LSTM epilogue
// (all 256 threads: 16 b x 16 j). Reads partS, ghh, gxg; writes h, cbuf.
// ---------------------------------------------------------------------------
__global__ __launch_bounds__(256) void step2_k(
    const short* __restrict__ featCtx,  // [64][3136][64] bf16
    const float* __restrict__ partS,    // [64 nt][64 b][49 l]
    const float* __restrict__ ghh,      // [64][4096]
    const float* __restrict__ gxg,      // [2048][4096] = xg@Wxg^T + bg
    float* __restrict__ cbuf,
    short* __restrict__ hHo, short* __restrict__ hLo,
    float* __restrict__ w_out, int t)
{
  __shared__ float sw[16][52];
  __shared__ float ctx_p[2][16][72];
  const int tid = threadIdx.x;
  const int w = tid >> 6, lane = tid & 63;
  const int bid = blockIdx.x;
  const int id = (bid & 7) * 32 + (bid >> 3);
  const int nt = id >> 2, mq = id & 3;

  // Phase A: raw scores (coalesced nt-major reads)
  for (int idx = tid; idx < 16 * LL; idx += 256) {
    const float* ps = partS + (size_t)mq * 784 + idx;
    float s = 0.f;
#pragma unroll 8
    for (int a = 0; a < 64; ++a) s += ps[(size_t)a * 3136];
    sw[idx / LL][idx % LL] = s;
  }
  __syncthreads();
#pragma unroll
  for (int i = 0; i < 4; ++i) {
    const int bl = w * 4 + i;
    float v = (lane < LL) ? sw[bl][lane] : -1e30f;
    float m = v;
#pragma unroll
    for (int off = 32; off > 0; off >>= 1) m = fmaxf(m, __shfl_xor(m, off));
    float e = (lane < LL) ? expf(v - m) : 0.f;
    float s = e;
#pragma unroll
    for (int off = 32; off > 0; off >>= 1) s += __shfl_xor(s, off);
    float ww = e / s;
    if (lane < LL) {
      sw[bl][lane] = ww;
      if (nt == 0)
        w_out[((size_t)(mq * 16 + bl) * TT + t) * LL + lane] = ww;
    }
  }
  __syncthreads();

  // Phase B: ctx partials; 16B loads, 2-way l-split.
  {
    const int bl = tid >> 4, tsub = tid & 15;
    const int e8 = (tsub & 7) * 8, lpar = tsub >> 3;
    const size_t base =
        ((size_t)nt * 3136 + (size_t)(mq * 16 + bl) * LL) * 64 + e8;
    float s[8] = {};
    for (int l = lpar; l < LL; l += 2) {
      bf16x8 v = *(const bf16x8*)&featCtx[base + (size_t)l * 64];
      const float wl = sw[bl][l];
#pragma unroll
      for (int e = 0; e < 8; ++e)
        s[e] += wl * bf16_tof((unsigned short)v[e]);
    }
#pragma unroll
    for (int e = 0; e < 8; ++e)
      ctx_p[lpar][bl][e8 + e] = s[e];
  }
  __syncthreads();

  // Epilogue: all 256 threads; thread = (bl, jr)
  {
    const int bl = tid >> 4, jr = tid & 15;
    const int b = mq * 16 + bl;
    const int j = nt * 16 + jr;
    const float* gh = ghh + (size_t)b * 4096;
    const float* gx = gxg + ((size_t)t * 64 + b) * 4096;
    float gi = gh[0 * 1024 + j] + gx[0 * 1024 + j]
             + ctx_p[0][bl][0 * 16 + jr] + ctx_p[1][bl][0 * 16 + jr];
    float gf = gh[1 * 1024 + j] + gx[1 * 1024 + j]
             + ctx_p[0][bl][1 * 16 + jr] + ctx_p[1][bl][1 * 16 + jr];
    float gg = gh[2 * 1024 + j] + gx[2 * 1024 + j]
             + ctx_p[0][bl][2 * 16 + jr] + ctx_p[1][bl][2 * 16 + jr];
    float go = gh[3 * 1024 + j] + gx[3 * 1024 + j]
             + ctx_p[0][bl][3 * 16 + jr] + ctx_p[1][bl][3 * 16 + jr];
    float si = 1.f / (1.f + expf(-gi));
    float sf = 1.f / (1.f + expf(-gf));
    float so = 1.f / (1.f + expf(-go));
    const size_t ci = (size_t)b * HH + j;
    float cc = sf * cbuf[ci] + si * tanhf(gg);
    float hh = so * tanhf(cc);
    cbuf[ci] = cc;
    short hi, lo; split2(hh, hi, lo);
    hHo[ci] = hi;
    hLo[ci] = lo;
  }
}

// ---------------------------------------------------------------------------
// Combined prep GEMM (global_load_lds staging, linear LDS [128][32]).
// Grid (25, 40).
// ---------------------------------------------------------------------------
__global__ __launch_bounds__(256) void tgemm2_k(
    const short* __restrict__ A,
    const short* __restrict__ attWt,   // [1024][2048]
    const short* __restrict__ Wctxb,   // [4096][2048]
    short* __restrict__ featpB, short* __restrict__ featCtx)
{
  __shared__ short lA[128 * 32];
  __shared__ short lW[128 * 32];
  const int tid = threadIdx.x;
  const int w = tid >> 6, lane = tid & 63;
  const int r = lane & 15, kg = lane >> 4;
  const int M = BB * LL, K = FF;
  const bool ctx = (blockIdx.y >= 8);
  const short* Wb = ctx ? Wctxb : attWt;
  const int n0 = (ctx ? (blockIdx.y - 8) : blockIdx.y) * 128;
  const int m0 = blockIdx.x * 128;
  const int srow = tid >> 2, scol = (tid & 3) * 8;

  f32x4 acc[2][8] = {};
  for (int k0 = 0; k0 < K; k0 += 32) {
    __syncthreads();
#pragma unroll
    for (int j = 0; j < 2; ++j) {
      const int row = j * 64 + srow;
      int ar = m0 + row; if (ar >= M) ar = M - 1;
      const size_t lbase = (size_t)j * 4096 + (size_t)w * 1024;  // bytes
      gload16(&A[(size_t)ar * K + k0 + scol], (char*)lA + lbase);
      gload16(&Wb[(size_t)(n0 + row) * K + k0 + scol], (char*)lW + lbase);
    }
    __syncthreads();
    bf16x8 a0 = *(const bf16x8*)&lA[(w * 32 +  0 + r) * 32 + kg * 8];
    bf16x8 a1 = *(const bf16x8*)&lA[(w * 32 + 16 + r) * 32 + kg * 8];
#pragma unroll
    for (int nf = 0; nf < 8; ++nf) {
      bf16x8 wf = *(const bf16x8*)&lW[(nf * 16 + r) * 32 + kg * 8];
      acc[0][nf] = __builtin_amdgcn_mfma_f32_16x16x32_bf16(a0, wf, acc[0][nf], 0, 0, 0);
      acc[1][nf] = __builtin_amdgcn_mfma_f32_16x16x32_bf16(a1, wf, acc[1][nf], 0, 0, 0);
    }
  }
#pragma unroll
  for (int nf = 0; nf < 8; ++nf) {
    const int col = n0 + nf * 16 + r;
#pragma unroll
    for (int mf = 0; mf < 2; ++mf)
#pragma unroll
      for (int q = 0; q < 4; ++q) {
        const int grow = m0 + w * 32 + mf * 16 + kg * 4 + q;
        if (grow < M) {
          const short v = (short)bf16_rn(acc[mf][nf][q]);
          if (!ctx) {
            const int ntc = col >> 4, aa = col & 15;
            featpB[((size_t)ntc * 3136 + grow) * 16 + aa] = v;
          } else {
            const int gate = col >> 10, ntc = (col >> 4) & 63, jj = col & 15;
            featCtx[((size_t)ntc * 3136 + grow) * 64 + gate * 16 + jj] = v;
          }
        }
      }
  }
}

// ---------------------------------------------------------------------------
// Prep GEMM (global_load_lds): gxg[2048][4096] = [xg hi+lo]@Wxg^T + bg.
// Grid (16, 32), K=640.
// ---------------------------------------------------------------------------
__global__ __launch_bounds__(256) void tgemm3_k(
    const short* __restrict__ Ah, const short* __restrict__ Al,
    const short* __restrict__ Wb, const float* __restrict__ bias,
    float* __restrict__ outs)
{
  __shared__ short lAh[128 * 32];
  __shared__ short lAl[128 * 32];
  __shared__ short lW [128 * 32];
  const int tid = threadIdx.x;
  const int w = tid >> 6, lane = tid & 63;
  const int r = lane & 15, kg = lane >> 4;
  const int m0 = blockIdx.x * 128;
  const int n0 = blockIdx.y * 128;
  const int srow = tid >> 2, scol = (tid & 3) * 8;

  f32x4 acc[2][8] = {};
  for (int k0 = 0; k0 < XGLEN; k0 += 32) {
    __syncthreads();
#pragma unroll
    for (int j = 0; j < 2; ++j) {
      const int row = j * 64 + srow;
      const size_t lbase = (size_t)j * 4096 + (size_t)w * 1024;
      gload16(&Ah[(size_t)(m0 + row) * XGLEN + k0 + scol], (char*)lAh + lbase);
      gload16(&Al[(size_t)(m0 + row) * XGLEN + k0 + scol], (char*)lAl + lbase);
      gload16(&Wb[(size_t)(n0 + row) * XGLEN + k0 + scol], (char*)lW + lbase);
    }
    __syncthreads();
    bf16x8 ah0 = *(const bf16x8*)&lAh[(w * 32 +  0 + r) * 32 + kg * 8];
    bf16x8 ah1 = *(const bf16x8*)&lAh[(w * 32 + 16 + r) * 32 + kg * 8];
    bf16x8 al0 = *(const bf16x8*)&lAl[(w * 32 +  0 + r) * 32 + kg * 8];
    bf16x8 al1 = *(const bf16x8*)&lAl[(w * 32 + 16 + r) * 32 + kg * 8];
#pragma unroll
    for (int nf = 0; nf < 8; ++nf) {
      bf16x8 wf = *(const bf16x8*)&lW[(nf * 16 + r) * 32 + kg * 8];
      acc[0][nf] = __builtin_amdgcn_mfma_f32_16x16x32_bf16(ah0, wf, acc[0][nf], 0, 0, 0);
      acc[0][nf] = __builtin_amdgcn_mfma_f32_16x16x32_bf16(al0, wf, acc[0][nf], 0, 0, 0);
      acc[1][nf] = __builtin_amdgcn_mfma_f32_16x16x32_bf16(ah1, wf, acc[1][nf], 0, 0, 0);
      acc[1][nf] = __builtin_amdgcn_mfma_f32_16x16x32_bf16(al1, wf, acc[1][nf], 0, 0, 0);
    }
  }
#pragma unroll
  for (int nf = 0; nf < 8; ++nf) {
    const int colv = n0 + nf * 16 + r;
    const float bv = bias[colv];
#pragma unroll
    for (int mf = 0; mf < 2; ++mf)
#pragma unroll
      for (int q = 0; q < 4; ++q) {
        const int grow = m0 + w * 32 + mf * 16 + kg * 4 + q;
        outs[(size_t)grow * 4096 + colv] = acc[mf][nf][q] + bv;
      }
  }
}

// ---------------------------------------------------------------------------
// Batched fc GEMM (global_load_lds staging, linear LDS). Grid (16, 94).
// ---------------------------------------------------------------------------
__global__ __launch_bounds__(256) void bgemm_k(
    const short* __restrict__ Ah, const short* __restrict__ Al,
    const short* __restrict__ Wb, const float* __restrict__ bias,
    float* __restrict__ outs)
{
  __shared__ short lAh[128 * 32];
  __shared__ short lAl[128 * 32];
  __shared__ short lW [128 * 32];
  const int tid = threadIdx.x;
  const int w = tid >> 6, lane = tid & 63;
  const int r = lane & 15, kg = lane >> 4;
  const int m0 = blockIdx.x * 128;
  const int n0 = blockIdx.y * 128;
  const int srow = tid >> 2, scol = (tid & 3) * 8;

  f32x4 acc[2][8] = {};
  for (int k0 = 0; k0 < HH; k0 += 32) {
    __syncthreads();
#pragma unroll
    for (int j = 0; j < 2; ++j) {
      const int row = j * 64 + srow;
      int wr = n0 + row; if (wr >= VV) wr = VV - 1;
      const size_t lbase = (size_t)j * 4096 + (size_t)w * 1024;
      gload16(&Ah[(size_t)(m0 + row) * HH + k0 + scol], (char*)lAh + lbase);
      gload16(&Al[(size_t)(m0 + row) * HH + k0 + scol], (char*)lAl + lbase);
      gload16(&Wb[(size_t)wr * HH + k0 + scol], (char*)lW + lbase);
    }
    __syncthreads();
    bf16x8 ah0 = *(const bf16x8*)&lAh[(w * 32 +  0 + r) * 32 + kg * 8];
    bf16x8 ah1 = *(const bf16x8*)&lAh[(w * 32 + 16 + r) * 32 + kg * 8];
    bf16x8 al0 = *(const bf16x8*)&lAl[(w * 32 +  0 + r) * 32 + kg * 8];
    bf16x8 al1 = *(const bf16x8*)&lAl[(w * 32 + 16 + r) * 32 + kg * 8];
#pragma unroll
    for (int nf = 0; nf < 8; ++nf) {
      bf16x8 wf = *(const bf16x8*)&lW[(nf * 16 + r) * 32 + kg * 8];
      acc[0][nf] = __builtin_amdgcn_mfma_f32_16x16x32_bf16(ah0, wf, acc[0][nf], 0, 0, 0);
      acc[0][nf] = __builtin_amdgcn_mfma_f32_16x16x32_bf16(al0, wf, acc[0][nf], 0, 0, 0);
      acc[1][nf] = __builtin_amdgcn_mfma_f32_16x16x32_bf16(ah1, wf, acc[1][nf], 0, 0, 0);
      acc[1][nf] = __builtin_amdgcn_mfma_f32_16x16x32_bf16(al1, wf, acc[1][nf], 0, 0, 0);
    }
  }
#pragma unroll
  for (int nf = 0; nf < 8; ++nf) {
    const int colv = n0 + nf * 16 + r;
    if (colv < VV) {
      const float bv = bias[colv];
#pragma unroll
      for (int mf = 0; mf < 2; ++mf)
#pragma unroll
        for (int q = 0; q < 4; ++q) {
          const int grow = m0 + w * 32 + mf * 16 + kg * 4 + q;  // = t*64 + b
          const int tt = grow >> 6, b = grow & 63;
          outs[((size_t)b * TT + tt) * VV + colv] = acc[mf][nf][q] + bv;
        }
    }
  }
}

// ---------------------------------------------------------------------------
// Fused h0/c0: grid 64; bid<32 -> h0 (split out), else c0 (f32 out).
// ---------------------------------------------------------------------------
__global__ __launch_bounds__(256) void h0c0_k(
    const short* __restrict__ mfb,
    const short* __restrict__ Wh0b, const float* __restrict__ bh0,
    const short* __restrict__ Wc0b, const float* __restrict__ bc0,
    short* __restrict__ h0H, short* __restrict__ h0L,
    float* __restrict__ cbuf)
{
  const int tid = threadIdx.x;
  const int w = tid >> 6, l = tid & 63;
  const int r = l & 15, kg = l >> 4;
  const bool cpath = blockIdx.x >= 32;
  const int nb = blockIdx.x & 31;
  const short* Wb = cpath ? Wc0b : Wh0b;
  const float* bias = cpath ? bc0 : bh0;
  const int nslice = w >> 1, mbase = (w & 1) * 2;
  const int n0 = nb * 32 + nslice * 16;
  const int nrow = n0 + r;
  const short* wp = Wb + (size_t)nrow * FF + kg * 8;
  const short* ap = mfb + (size_t)(mbase * 16 + r) * FF + kg * 8;
  f32x4 acc[2] = {};
  for (int k0 = 0; k0 < FF; k0 += 32) {
    bf16x8 bf = *(const bf16x8*)(wp + k0);
#pragma unroll
    for (int m = 0; m < 2; ++m) {
      bf16x8 af = *(const bf16x8*)(ap + (size_t)(16 * m) * FF + k0);
      acc[m] = __builtin_amdgcn_mfma_f32_16x16x32_bf16(af, bf, acc[m], 0, 0, 0);
    }
  }
  const float bv = bias[nrow];
#pragma unroll
  for (int m = 0; m < 2; ++m)
#pragma unroll
    for (int q = 0; q < 4; ++q) {
      const int mm = (mbase + m) * 16 + kg * 4 + q;
      const float v = acc[m][q] + bv;
      if (cpath) {
        cbuf[(size_t)mm * HH + nrow] = v;
      } else {
        short hi, lo; split2(v, hi, lo);
        h0H[(size_t)mm * HH + nrow] = hi;
        h0L[(size_t)mm * HH + nrow] = lo;
      }
    }
}

// ---------------------------------------------------------------------------
// Combined transpose+cast: grid (32, 96): y<32 -> att_U, else att_W.
// ---------------------------------------------------------------------------
__global__ __launch_bounds__(256) void transpose2_k(
    const float* __restrict__ attU, short* __restrict__ attUt,
    const float* __restrict__ attW, short* __restrict__ attWt)
{
  __shared__ float tile[32][33];
  const bool isW = blockIdx.y >= 32;
  const float* in = isW ? attW : attU;
  short* out = isW ? attWt : attUt;
  const int R = isW ? FF : HH;
  const int br = (isW ? (blockIdx.y - 32) : blockIdx.y) * 32;
  const int bc = blockIdx.x * 32;
  int tx = threadIdx.x & 31, ty4 = (threadIdx.x >> 5) << 2;
#pragma unroll
  for (int i = 0; i < 4; ++i)
    tile[ty4 + i][tx] = in[(size_t)(br + ty4 + i) * HH + bc + tx];
  __syncthreads();
#pragma unroll
  for (int i = 0; i < 4; ++i)
    out[(size_t)(bc + ty4 + i) * R + br + tx] = (short)bf16_rn(tile[tx][ty4 + i]);
}

// ---------------------------------------------------------------------------
// Fused elementwise prep, 8-wide vectorized.
// ---------------------------------------------------------------------------
#define S_FEATB   6422528ULL                       /* 64*49*2048      */
#define C1  (S_FEATB)
#define C2  (C1 + 12288000ULL)                     /* fc_W 12000*1024 */
#define C3  (C2 + 4194304ULL)                      /* W_hh 4096*1024  */
#define C4  (C3 + 2097152ULL)                      /* Wh0 1024*2048   */
#define C5  (C4 + 2097152ULL)                      /* Wc0 1024*2048   */
#define C6  (C5 + 2621440ULL)                      /* Wxg 4096*640    */
#define C7  (C6 + 8388608ULL)                      /* Wctx 4096*2048  */
#define C8  (C7 + 1310720ULL)                      /* xg 2048*640     */
#define C9  (C8 + 4096ULL)                         /* bg              */
#define C10 (C9 + 131072ULL)                       /* mean 64*2048    */

__global__ __launch_bounds__(256) void prep_k(
    const float* __restrict__ features, const float* __restrict__ fc_W,
    const float* __restrict__ W_hh, const float* __restrict__ Wh0,
    const float* __restrict__ Wc0, const float* __restrict__ W_ih,
    const int* __restrict__ captions, const float* __restrict__ emb,
    const float* __restrict__ cat,
    const float* __restrict__ b_ih, const float* __restrict__ b_hh,
    short* __restrict__ featb, short* __restrict__ fcWb,
    short* __restrict__ Whb, short* __restrict__ Wh0b,
    short* __restrict__ Wc0b, short* __restrict__ Wxg,
    short* __restrict__ Wctxb, short* __restrict__ xgH,
    short* __restrict__ xgL, float* __restrict__ bg,
    short* __restrict__ mfb)
{
  const size_t stride = (size_t)gridDim.x * 256;
  for (size_t ii = (size_t)blockIdx.x * 256 + threadIdx.x; ii < (C10 >> 3);
       ii += stride) {
    const size_t i = ii << 3;
    float f[8];
    if (i < C1) {
      *(float4*)&f[0] = *(const float4*)&features[i];
      *(float4*)&f[4] = *(const float4*)&features[i + 4];
      *(bf16x8*)&featb[i] = cvt8(f);
    } else if (i < C2) {
      const size_t j = i - C1;
      *(float4*)&f[0] = *(const float4*)&fc_W[j];
      *(float4*)&f[4] = *(const float4*)&fc_W[j + 4];
      *(bf16x8*)&fcWb[j] = cvt8(f);
    } else if (i < C3) {
      const size_t j = i - C2;
      *(float4*)&f[0] = *(const float4*)&W_hh[j];
      *(float4*)&f[4] = *(const float4*)&W_hh[j + 4];
      *(bf16x8*)&Whb[j] = cvt8(f);
    } else if (i < C4) {
      const size_t j = i - C3;
      *(float4*)&f[0] = *(const float4*)&Wh0[j];
      *(float4*)&f[4] = *(const float4*)&Wh0[j + 4];
      *(bf16x8*)&Wh0b[j] = cvt8(f);
    } else if (i < C5) {
      const size_t j = i - C4;
      *(float4*)&f[0] = *(const float4*)&Wc0[j];
      *(float4*)&f[4] = *(const float4*)&Wc0[j + 4];
      *(bf16x8*)&Wc0b[j] = cvt8(f);
    } else if (i < C6) {
      const size_t j = i - C5;
      const int n = (int)(j / XGLEN), k = (int)(j % XGLEN);
      const int ks = (k < EE) ? k : (EE + FF + (k - EE));
      const float* src = &W_ih[(size_t)n * XKLEN + ks];
      *(float4*)&f[0] = *(const float4*)&src[0];
      *(float4*)&f[4] = *(const float4*)&src[4];
      *(bf16x8*)&Wxg[j] = cvt8(f);
    } else if (i < C7) {
      const size_t j = i - C6;
      const int n = (int)(j / FF), k = (int)(j % FF);
      const float* src = &W_ih[(size_t)n * XKLEN + EE + k];
      *(float4*)&f[0] = *(const float4*)&src[0];
      *(float4*)&f[4] = *(const float4*)&src[4];
      *(bf16x8*)&Wctxb[j] = cvt8(f);
    } else if (i < C8) {
      const size_t j = i - C7;
      const int row = (int)(j / XGLEN), k = (int)(j % XGLEN);
      const int t = row >> 6, b = row & 63;
      const float* src;
      if (k < EE) {
        const int cap = captions[b * TT + t];
        src = &emb[(size_t)cap * EE + k];
      } else {
        src = &cat[(size_t)b * CDIM + (k - EE)];
      }
      *(float4*)&f[0] = *(const float4*)&src[0];
      *(float4*)&f[4] = *(const float4*)&src[4];
      bf16x8 hi8, lo8;
#pragma unroll
      for (int e = 0; e < 8; ++e) {
        short h, l2; split2(f[e], h, l2);
        hi8[e] = h; lo8[e] = l2;
      }
      *(bf16x8*)&xgH[j] = hi8;
      *(bf16x8*)&xgL[j] = lo8;
    } else if (i < C9) {
      const size_t j = i - C8;
      float4 a0 = *(const float4*)&b_ih[j];
      float4 a1 = *(const float4*)&b_ih[j + 4];
      float4 c0 = *(const float4*)&b_hh[j];
      float4 c1 = *(const float4*)&b_hh[j + 4];
      float4 o0 = make_float4(a0.x + c0.x, a0.y + c0.y, a0.z + c0.z, a0.w + c0.w);
      float4 o1 = make_float4(a1.x + c1.x, a1.y + c1.y, a1.z + c1.z, a1.w + c1.w);
      *(float4*)&bg[j] = o0;
      *(float4*)&bg[j + 4] = o1;
    } else {
      const size_t j = i - C9;
      const int b = (int)(j >> 11), f0 = (int)(j & 2047);
      float s[8] = {};
      for (int l = 0; l < LL; ++l) {
        const float* src = &features[((size_t)b * LL + l) * FF + f0];
        float4 u0 = *(const float4*)&src[0];
        float4 u1 = *(const float4*)&src[4];
        s[0] += u0.x; s[1] += u0.y; s[2] += u0.z; s[3] += u0.w;
        s[4] += u1.x; s[5] += u1.y; s[6] += u1.z; s[7] += u1.w;
      }
#pragma unroll
      for (int e = 0; e < 8; ++e) s[e] *= (1.f / 49.f);
      *(bf16x8*)&mfb[j] = cvt8(s);
    }
  }
}

extern "C" void kernel_launch(void* const* d_in, const int* in_sizes, int n_in,
                              void* d_out, int out_size, void* d_ws, size_t ws_size,
                              hipStream_t stream) {
  const int*   captions = (const int*)  d_in[0];
  const float* features = (const float*)d_in[1];
  const float* category = (const float*)d_in[2];
  const float* emb      = (const float*)d_in[3];
  const float* W_ih     = (const float*)d_in[4];
  const float* b_ih     = (const float*)d_in[5];
  const float* W_hh     = (const float*)d_in[6];
  const float* b_hh     = (const float*)d_in[7];
  const float* fc_W     = (const float*)d_in[8];
  const float* fc_b     = (const float*)d_in[9];
  const float* Wh0      = (const float*)d_in[10];
  const float* bh0      = (const float*)d_in[11];
  const float* Wc0      = (const float*)d_in[12];
  const float* bc0      = (const float*)d_in[13];
  const float* att_W    = (const float*)d_in[14];
  const float* att_U    = (const float*)d_in[15];
  const float* att_v    = (const float*)d_in[16];

  float* outs  = (float*)d_out;
  float* w_out = outs + (size_t)BB * TT * VV;

  char* p = (char*)d_ws;
  auto alloc = [&](size_t bytes) {
    char* q = p; p += (bytes + 255) & ~(size_t)255; return q;
  };
  short* attUt  = (short*)alloc((size_t)HH * HH * 2);
  short* attWt  = (short*)alloc((size_t)HH * FF * 2);
  short* featb  = (short*)alloc((size_t)BB * LL * FF * 2);   // prep only; reused as hall
  short* fcWb   = (short*)alloc((size_t)VV * HH * 2);
  short* Wctxb  = (short*)alloc((size_t)4096 * FF * 2);
  short* Whb    = (short*)alloc((size_t)4096 * HH * 2);
  short* Wxg    = (short*)alloc((size_t)4096 * XGLEN * 2);
  short* Wh0b   = (short*)alloc((size_t)HH * FF * 2);
  short* Wc0b   = (short*)alloc((size_t)HH * FF * 2);
  short* mfb    = (short*)alloc((size_t)BB * FF * 2);
  short* h0H    = (short*)alloc((size_t)BB * HH * 2);
  short* h0L    = (short*)alloc((size_t)BB * HH * 2);
  short* xgH    = (short*)alloc((size_t)2048 * XGLEN * 2);
  short* xgL    = (short*)alloc((size_t)2048 * XGLEN * 2);
  short* featpB = (short*)alloc((size_t)64 * 3136 * 16 * 2); // [nt][3136][16] bf16
  short* featCtx= (short*)alloc((size_t)64 * 3136 * 64 * 2);
  float* gxg    = (float*)alloc((size_t)2048 * 4096 * 4);    // xg@Wxg^T + bg
  float* ghh    = (float*)alloc((size_t)64 * 4096 * 4);      // h@Whb^T
  float* cbuf   = (float*)alloc((size_t)BB * HH * 4);
  float* partS  = (float*)alloc((size_t)64 * 3136 * 4);
  float* bg     = (float*)alloc(4096 * 4);
  // h history (= h(t) for t=0..31) aliases featb (dead after prep GEMMs).
  short* hallH = featb;
  short* hallL = featb + (size_t)TT * BB * HH;

  // ---- one-time prep: 5 dispatches ----
  prep_k<<<2048, 256, 0, stream>>>(
      features, fc_W, W_hh, Wh0, Wc0, W_ih, captions, emb, category,
      b_ih, b_hh,
      featb, fcWb, Whb, Wh0b, Wc0b, Wxg, Wctxb, xgH, xgL, bg, mfb);
  transpose2_k<<<dim3(32, 96), 256, 0, stream>>>(att_U, attUt, att_W, attWt);
  h0c0_k<<<64, 256, 0, stream>>>(mfb, Wh0b, bh0, Wc0b, bc0, h0H, h0L, cbuf);
  tgemm2_k<<<dim3(25, 40), 256, 0, stream>>>(featb, attWt, Wctxb, featpB, featCtx);
  tgemm3_k<<<dim3(16, 32), 256, 0, stream>>>(xgH, xgL, Wxg, bg, gxg);

  // ---- timestep loop: 2 dispatches per step (step1 overlaps hU + gates) ----
  for (int t = 0; t < TT; ++t) {
    const short* hHi = (t == 0) ? h0H : hallH + (size_t)(t - 1) * BB * HH;
    const short* hLi = (t == 0) ? h0L : hallL + (size_t)(t - 1) * BB * HH;
    step1_k<<<512, 256, 0, stream>>>(
        hHi, hLi, attUt, featpB, att_v, Whb, partS, ghh);
    step2_k<<<256, 256, 0, stream>>>(
        featCtx, partS, ghh, gxg, cbuf,
        hallH + (size_t)t * BB * HH, hallL + (size_t)t * BB * HH, w_out, t);
  }

  // ---- deferred batched fc ----
  bgemm_k<<<dim3(16, 94), 256, 0, stream>>>(hallH, hallL, fcWb, fc_b, outs);
}

// Round 22
// 1472.565 us; speedup vs baseline: 1.4702x; 1.0745x over previous
//
#include <hip/hip_runtime.h>
#include <hip/hip_bf16.h>

#define BB 64
#define TT 32
#define VV 12000
#define EE 512
#define FF 2048
#define CDIM 128
#define HH 1024
#define LL 49
#define XKLEN 2688   /* E + F + C */
#define XGLEN 640    /* E + C : per-step gathered input */

typedef __attribute__((ext_vector_type(8))) short bf16x8;
typedef __attribute__((ext_vector_type(4))) float f32x4;

__device__ __forceinline__ unsigned short bf16_rn(float x) {
  unsigned u = __float_as_uint(x);
  u += 0x7FFFu + ((u >> 16) & 1u);
  return (unsigned short)(u >> 16);
}
__device__ __forceinline__ float bf16_tof(unsigned short h) {
  return __uint_as_float(((unsigned)h) << 16);
}
__device__ __forceinline__ void split2(float x, short& hi, short& lo) {
  unsigned short h = bf16_rn(x);
  float r = x - bf16_tof(h);
  hi = (short)h;
  lo = (short)bf16_rn(r);
}
__device__ __forceinline__ bf16x8 cvt8(const float* f) {
  bf16x8 o;
#pragma unroll
  for (int e = 0; e < 8; ++e) o[e] = (short)bf16_rn(f[e]);
  return o;
}
__device__ __forceinline__ void gload16(const void* g, void* l) {
  __builtin_amdgcn_global_load_lds(
      (const __attribute__((address_space(1))) void*)g,
      (__attribute__((address_space(3))) void*)l, 16, 0, 0);
}
// v_exp_f32-based fast transcendentals (~1e-6 rel err, far below bf16 noise)
__device__ __forceinline__ float fast_tanh(float x) {
  return 1.f - 2.f / (__expf(2.f * x) + 1.f);
}
__device__ __forceinline__ float fast_sig(float x) {
  return 1.f / (1.f + __expf(-x));
}

// ---------------------------------------------------------------------------
// STEP1 (768 blocks): all halves depend only on h(t-1).
//  blocks 0..255  : hU tile + partial scores -> partS [64 nt][64 b][49 l]
//  blocks 256..767: gates MFMA h@Whb^T (hi/lo, K split 2 blocks x 512)
//                   + LDS reduce -> ghh[2][64][4096]
// ---------------------------------------------------------------------------
__global__ __launch_bounds__(256) void step1_k(
    const short* __restrict__ hHi, const short* __restrict__ hLi,
    const short* __restrict__ attUt,   // [1024][1024] bf16
    const short* __restrict__ featpB,  // [64][3136][16] bf16
    const float* __restrict__ att_v,
    const short* __restrict__ Whb,     // [4096][1024] bf16
    float* __restrict__ partS,         // [64][64][49]
    float* __restrict__ ghh)           // [2][64][4096] f32
{
  __shared__ float red4[4][64][5];
  __shared__ float hu_s[16][17];
  __shared__ float av_s[16];
  __shared__ float red3[3][64][17];
  const int tid = threadIdx.x;
  const int w = tid >> 6, lane = tid & 63;
  const int r = lane & 15, kg = lane >> 4;

  if (blockIdx.x < 256) {
    // ---- hupart half ----
    const int bid = blockIdx.x;
    const int id = (bid & 7) * 32 + (bid >> 3);
    const int nt = id >> 2, mh = id & 3;
    const int kb = w * 256;

    if (tid < 16) av_s[tid] = att_v[nt * 16 + tid];

    const short* wp = attUt + (size_t)(nt * 16 + r) * HH + kb + kg * 8;
    const short* ap = hHi + (size_t)(mh * 16 + r) * HH + kb + kg * 8;
    f32x4 acc = {};
#pragma unroll
    for (int k0 = 0; k0 < 256; k0 += 32) {
      bf16x8 bf = *(const bf16x8*)(wp + k0);
      bf16x8 af = *(const bf16x8*)(ap + k0);
      acc = __builtin_amdgcn_mfma_f32_16x16x32_bf16(af, bf, acc, 0, 0, 0);
    }
#pragma unroll
    for (int q = 0; q < 4; ++q)
      red4[w][lane][q] = acc[q];
    __syncthreads();

    {
      const int bl = tid >> 4, a = tid & 15;
      const int sl = (bl >> 2) * 16 + a;
      const int ii = bl & 3;
      hu_s[bl][a] = red4[0][sl][ii] + red4[1][sl][ii]
                  + red4[2][sl][ii] + red4[3][sl][ii];
    }
    __syncthreads();

    for (int task = tid; task < 16 * LL; task += 256) {
      const int bl = task / LL, l = task - bl * LL;
      const int b = mh * 16 + bl;
      const short* fp = featpB + ((size_t)nt * 3136 + (size_t)b * LL + l) * 16;
      bf16x8 v0 = *(const bf16x8*)&fp[0];
      bf16x8 v1 = *(const bf16x8*)&fp[8];
      float s = 0.f;
#pragma unroll
      for (int a = 0; a < 8; ++a)
        s += fast_tanh(bf16_tof((unsigned short)v0[a]) + hu_s[bl][a]) * av_s[a];
#pragma unroll
      for (int a = 0; a < 8; ++a)
        s += fast_tanh(bf16_tof((unsigned short)v1[a]) + hu_s[bl][8 + a]) * av_s[8 + a];
      partS[(size_t)nt * 3136 + (size_t)mh * 784 + task] = s;
    }
  } else {
    // ---- gates half: ghh[kq] partial of h @ Whb^T (K split 2 x 512) ----
    const int b2 = blockIdx.x - 256;           // 0..511
    const int id = (b2 & 7) * 64 + (b2 >> 3);  // XCD-chunked
    const int nt = id >> 3;
    const int mq = (id >> 1) & 3;
    const int kq = id & 1;
    const int ks = kq * 512;
    const int brow = mq * 16 + r;
    f32x4 acc0 = {}, acc1 = {}, acc2 = {}, acc3 = {};
#pragma unroll
    for (int c = 0; c < 4; ++c) {
      const int hk = ks + (w * 4 + c) * 32;
      const short* a_h = hHi + (size_t)brow * HH + hk + kg * 8;
      const short* a_l = hLi + (size_t)brow * HH + hk + kg * 8;
      const short* w0p = Whb + (size_t)(0 * 1024 + nt * 16 + r) * HH + hk + kg * 8;
      const short* w1p = Whb + (size_t)(1 * 1024 + nt * 16 + r) * HH + hk + kg * 8;
      const short* w2p = Whb + (size_t)(2 * 1024 + nt * 16 + r) * HH + hk + kg * 8;
      const short* w3p = Whb + (size_t)(3 * 1024 + nt * 16 + r) * HH + hk + kg * 8;
      bf16x8 af  = *(const bf16x8*)a_h;
      bf16x8 alf = *(const bf16x8*)a_l;
      bf16x8 b0 = *(const bf16x8*)w0p;
      acc0 = __builtin_amdgcn_mfma_f32_16x16x32_bf16(af,  b0, acc0, 0, 0, 0);
      acc0 = __builtin_amdgcn_mfma_f32_16x16x32_bf16(alf, b0, acc0, 0, 0, 0);
      bf16x8 b1 = *(const bf16x8*)w1p;
      acc1 = __builtin_amdgcn_mfma_f32_16x16x32_bf16(af,  b1, acc1, 0, 0, 0);
      acc1 = __builtin_amdgcn_mfma_f32_16x16x32_bf16(alf, b1, acc1, 0, 0, 0);
      bf16x8 b2v = *(const bf16x8*)w2p;
      acc2 = __builtin_amdgcn_mfma_f32_16x16x32_bf16(af,  b2v, acc2, 0, 0, 0);
      acc2 = __builtin_amdgcn_mfma_f32_16x16x32_bf16(alf, b2v, acc2, 0, 0, 0);
      bf16x8 b3 = *(const bf16x8*)w3p;
      acc3 = __builtin_amdgcn_mfma_f32_16x16x32_bf16(af,  b3, acc3, 0, 0, 0);
      acc3 = __builtin_amdgcn_mfma_f32_16x16x32_bf16(alf, b3, acc3, 0, 0, 0);
    }
    if (w != 0) {
#pragma unroll
      for (int q = 0; q < 4; ++q) {
        red3[w - 1][lane][0 * 4 + q] = acc0[q];
        red3[w - 1][lane][1 * 4 + q] = acc1[q];
        red3[w - 1][lane][2 * 4 + q] = acc2[q];
        red3[w - 1][lane][3 * 4 + q] = acc3[q];
      }
    }
    __syncthreads();
    if (w == 0) {
      const int j = nt * 16 + r;
#pragma unroll
      for (int q = 0; q < 4; ++q) {
        const int b = mq * 16 + kg * 4 + q;
        float g0 = acc0[q], g1 = acc1[q], g2 = acc2[q], g3 = acc3[q];
#pragma unroll
        for (int p = 0; p < 3; ++p) {
          g0 += red3[p][lane][0 * 4 + q];
          g1 += red3[p][lane][1 * 4 + q];
          g2 += red3[p][lane][2 * 4 + q];
          g3 += red3[p][lane][3 * 4 + q];
        }
        float* gh = ghh + (size_t)kq * 64 * 4096 + (size_t)b * 4096;
        gh[0 * 1024 + j] = g0;
        gh[1 * 1024 + j] = g1;
        gh[2 * 1024 + j] = g2;
        gh[3 * 1024 + j] = g3;
      }
    }
  }
}

// ---------------------------------------------------------------------------
// STEP2 (256 blocks): score-sum + softmax + ctx weighted-sum + LSTM epilogue
// (all 256 threads: 16 b x 16 j). Sums 2 ghh K-partials.
// ---------------------------------------------------------------------------
__global__ __launch_bounds__(256) void step2_k(
    const short* __restrict__ featCtx,  // [64][3136][64] bf16
    const float* __restrict__ partS,    // [64 nt][64 b][49 l]
    const float* __restrict__ ghh,      // [2][64][4096]
    const float* __restrict__ gxg,      // [2048][4096] = xg@Wxg^T + bg
    float* __restrict__ cbuf,
    short* __restrict__ hHo, short* __restrict__ hLo,
    float* __restrict__ w_out, int t)
{
  __shared__ float sw[16][52];
  __shared__ float ctx_p[2][16][72];
  const int tid = threadIdx.x;
  const int w = tid >> 6, lane = tid & 63;
  const int bid = blockIdx.x;
  const int id = (bid & 7) * 32 + (bid >> 3);
  const int nt = id >> 2, mq = id & 3;

  // Phase A: raw scores (coalesced nt-major reads)
  for (int idx = tid; idx < 16 * LL; idx += 256) {
    const float* ps = partS + (size_t)mq * 784 + idx;
    float s = 0.f;
#pragma unroll 8
    for (int a = 0; a < 64; ++a) s += ps[(size_t)a * 3136];
    sw[idx / LL][idx % LL] = s;
  }
  __syncthreads();
#pragma unroll
  for (int i = 0; i < 4; ++i) {
    const int bl = w * 4 + i;
    float v = (lane < LL) ? sw[bl][lane] : -1e30f;
    float m = v;
#pragma unroll
    for (int off = 32; off > 0; off >>= 1) m = fmaxf(m, __shfl_xor(m, off));
    float e = (lane < LL) ? __expf(v - m) : 0.f;
    float s = e;
#pragma unroll
    for (int off = 32; off > 0; off >>= 1) s += __shfl_xor(s, off);
    float ww = e / s;
    if (lane < LL) {
      sw[bl][lane] = ww;
      if (nt == 0)
        w_out[((size_t)(mq * 16 + bl) * TT + t) * LL + lane] = ww;
    }
  }
  __syncthreads();

  // Phase B: ctx partials; 16B loads, 2-way l-split.
  {
    const int bl = tid >> 4, tsub = tid & 15;
    const int e8 = (tsub & 7) * 8, lpar = tsub >> 3;
    const size_t base =
        ((size_t)nt * 3136 + (size_t)(mq * 16 + bl) * LL) * 64 + e8;
    float s[8] = {};
    for (int l = lpar; l < LL; l += 2) {
      bf16x8 v = *(const bf16x8*)&featCtx[base + (size_t)l * 64];
      const float wl = sw[bl][l];
#pragma unroll
      for (int e = 0; e < 8; ++e)
        s[e] += wl * bf16_tof((unsigned short)v[e]);
    }
#pragma unroll
    for (int e = 0; e < 8; ++e)
      ctx_p[lpar][bl][e8 + e] = s[e];
  }
  __syncthreads();

  // Epilogue: all 256 threads; thread = (bl, jr)
  {
    const int bl = tid >> 4, jr = tid & 15;
    const int b = mq * 16 + bl;
    const int j = nt * 16 + jr;
    const float* gh0 = ghh + (size_t)b * 4096;
    const float* gh1 = ghh + (size_t)64 * 4096 + (size_t)b * 4096;
    const float* gx = gxg + ((size_t)t * 64 + b) * 4096;
    float gi = gh0[0 * 1024 + j] + gh1[0 * 1024 + j] + gx[0 * 1024 + j]
             + ctx_p[0][bl][0 * 16 + jr] + ctx_p[1][bl][0 * 16 + jr];
    float gf = gh0[1 * 1024 + j] + gh1[1 * 1024 + j] + gx[1 * 1024 + j]
             + ctx_p[0][bl][1 * 16 + jr] + ctx_p[1][bl][1 * 16 + jr];
    float gg = gh0[2 * 1024 + j] + gh1[2 * 1024 + j] + gx[2 * 1024 + j]
             + ctx_p[0][bl][2 * 16 + jr] + ctx_p[1][bl][2 * 16 + jr];
    float go = gh0[3 * 1024 + j] + gh1[3 * 1024 + j] + gx[3 * 1024 + j]
             + ctx_p[0][bl][3 * 16 + jr] + ctx_p[1][bl][3 * 16 + jr];
    float si = fast_sig(gi);
    float sf = fast_sig(gf);
    float so = fast_sig(go);
    const size_t ci = (size_t)b * HH + j;
    float cc = sf * cbuf[ci] + si * fast_tanh(gg);
    float hh = so * fast_tanh(cc);
    cbuf[ci] = cc;
    short hi, lo; split2(hh, hi, lo);
    hHo[ci] = hi;
    hLo[ci] = lo;
  }
}

// ---------------------------------------------------------------------------
// Combined prep GEMM (global_load_lds staging, linear LDS [128][32]).
// Grid (25, 40).
// ---------------------------------------------------------------------------
__global__ __launch_bounds__(256) void tgemm2_k(
    const short* __restrict__ A,
    const short* __restrict__ attWt,   // [1024][2048]
    const short* __restrict__ Wctxb,   // [4096][2048]
    short* __restrict__ featpB, short* __restrict__ featCtx)
{
  __shared__ short lA[128 * 32];
  __shared__ short lW[128 * 32];
  const int tid = threadIdx.x;
  const int w = tid >> 6, lane = tid & 63;
  const int r = lane & 15, kg = lane >> 4;
  const int M = BB * LL, K = FF;
  const bool ctx = (blockIdx.y >= 8);
  const short* Wb = ctx ? Wctxb : attWt;
  const int n0 = (ctx ? (blockIdx.y - 8) : blockIdx.y) * 128;
  const int m0 = blockIdx.x * 128;
  const int srow = tid >> 2, scol = (tid & 3) * 8;

  f32x4 acc[2][8] = {};
  for (int k0 = 0; k0 < K; k0 += 32) {
    __syncthreads();
#pragma unroll
    for (int j = 0; j < 2; ++j) {
      const int row = j * 64 + srow;
      int ar = m0 + row; if (ar >= M) ar = M - 1;
      const size_t lbase = (size_t)j * 4096 + (size_t)w * 1024;  // bytes
      gload16(&A[(size_t)ar * K + k0 + scol], (char*)lA + lbase);
      gload16(&Wb[(size_t)(n0 + row) * K + k0 + scol], (char*)lW + lbase);
    }
    __syncthreads();
    bf16x8 a0 = *(const bf16x8*)&lA[(w * 32 +  0 + r) * 32 + kg * 8];
    bf16x8 a1 = *(const bf16x8*)&lA[(w * 32 + 16 + r) * 32 + kg * 8];
#pragma unroll
    for (int nf = 0; nf < 8; ++nf) {
      bf16x8 wf = *(const bf16x8*)&lW[(nf * 16 + r) * 32 + kg * 8];
      acc[0][nf] = __builtin_amdgcn_mfma_f32_16x16x32_bf16(a0, wf, acc[0][nf], 0, 0, 0);
      acc[1][nf] = __builtin_amdgcn_mfma_f32_16x16x32_bf16(a1, wf, acc[1][nf], 0, 0, 0);
    }
  }
#pragma unroll
  for (int nf = 0; nf < 8; ++nf) {
    const int col = n0 + nf * 16 + r;
#pragma unroll
    for (int mf = 0; mf < 2; ++mf)
#pragma unroll
      for (int q = 0; q < 4; ++q) {
        const int grow = m0 + w * 32 + mf * 16 + kg * 4 + q;
        if (grow < M) {
          const short v = (short)bf16_rn(acc[mf][nf][q]);
          if (!ctx) {
            const int ntc = col >> 4, aa = col & 15;
            featpB[((size_t)ntc * 3136 + grow) * 16 + aa] = v;
          } else {
            const int gate = col >> 10, ntc = (col >> 4) & 63, jj = col & 15;
            featCtx[((size_t)ntc * 3136 + grow) * 64 + gate * 16 + jj] = v;
          }
        }
      }
  }
}

// ---------------------------------------------------------------------------
// Prep GEMM (global_load_lds): gxg[2048][4096] = [xg hi+lo]@Wxg^T + bg.
// Grid (16, 32), K=640.
// ---------------------------------------------------------------------------
__global__ __launch_bounds__(256) void tgemm3_k(
    const short* __restrict__ Ah, const short* __restrict__ Al,
    const short* __restrict__ Wb, const float* __restrict__ bias,
    float* __restrict__ outs)
{
  __shared__ short lAh[128 * 32];
  __shared__ short lAl[128 * 32];
  __shared__ short lW [128 * 32];
  const int tid = threadIdx.x;
  const int w = tid >> 6, lane = tid & 63;
  const int r = lane & 15, kg = lane >> 4;
  const int m0 = blockIdx.x * 128;
  const int n0 = blockIdx.y * 128;
  const int srow = tid >> 2, scol = (tid & 3) * 8;

  f32x4 acc[2][8] = {};
  for (int k0 = 0; k0 < XGLEN; k0 += 32) {
    __syncthreads();
#pragma unroll
    for (int j = 0; j < 2; ++j) {
      const int row = j * 64 + srow;
      const size_t lbase = (size_t)j * 4096 + (size_t)w * 1024;
      gload16(&Ah[(size_t)(m0 + row) * XGLEN + k0 + scol], (char*)lAh + lbase);
      gload16(&Al[(size_t)(m0 + row) * XGLEN + k0 + scol], (char*)lAl + lbase);
      gload16(&Wb[(size_t)(n0 + row) * XGLEN + k0 + scol], (char*)lW + lbase);
    }
    __syncthreads();
    bf16x8 ah0 = *(const bf16x8*)&lAh[(w * 32 +  0 + r) * 32 + kg * 8];
    bf16x8 ah1 = *(const bf16x8*)&lAh[(w * 32 + 16 + r) * 32 + kg * 8];
    bf16x8 al0 = *(const bf16x8*)&lAl[(w * 32 +  0 + r) * 32 + kg * 8];
    bf16x8 al1 = *(const bf16x8*)&lAl[(w * 32 + 16 + r) * 32 + kg * 8];
#pragma unroll
    for (int nf = 0; nf < 8; ++nf) {
      bf16x8 wf = *(const bf16x8*)&lW[(nf * 16 + r) * 32 + kg * 8];
      acc[0][nf] = __builtin_amdgcn_mfma_f32_16x16x32_bf16(ah0, wf, acc[0][nf], 0, 0, 0);
      acc[0][nf] = __builtin_amdgcn_mfma_f32_16x16x32_bf16(al0, wf, acc[0][nf], 0, 0, 0);
      acc[1][nf] = __builtin_amdgcn_mfma_f32_16x16x32_bf16(ah1, wf, acc[1][nf], 0, 0, 0);
      acc[1][nf] = __builtin_amdgcn_mfma_f32_16x16x32_bf16(al1, wf, acc[1][nf], 0, 0, 0);
    }
  }
#pragma unroll
  for (int nf = 0; nf < 8; ++nf) {
    const int colv = n0 + nf * 16 + r;
    const float bv = bias[colv];
#pragma unroll
    for (int mf = 0; mf < 2; ++mf)
#pragma unroll
      for (int q = 0; q < 4; ++q) {
        const int grow = m0 + w * 32 + mf * 16 + kg * 4 + q;
        outs[(size_t)grow * 4096 + colv] = acc[mf][nf][q] + bv;
      }
  }
}

// ---------------------------------------------------------------------------
// Batched fc GEMM (global_load_lds staging, linear LDS). Grid (16, 94).
// ---------------------------------------------------------------------------
__global__ __launch_bounds__(256) void bgemm_k(
    const short* __restrict__ Ah, const short* __restrict__ Al,
    const short* __restrict__ Wb, const float* __restrict__ bias,
    float* __restrict__ outs)
{
  __shared__ short lAh[128 * 32];
  __shared__ short lAl[128 * 32];
  __shared__ short lW [128 * 32];
  const int tid = threadIdx.x;
  const int w = tid >> 6, lane = tid & 63;
  const int r = lane & 15, kg = lane >> 4;
  const int m0 = blockIdx.x * 128;
  const int n0 = blockIdx.y * 128;
  const int srow = tid >> 2, scol = (tid & 3) * 8;

  f32x4 acc[2][8] = {};
  for (int k0 = 0; k0 < HH; k0 += 32) {
    __syncthreads();
#pragma unroll
    for (int j = 0; j < 2; ++j) {
      const int row = j * 64 + srow;
      int wr = n0 + row; if (wr >= VV) wr = VV - 1;
      const size_t lbase = (size_t)j * 4096 + (size_t)w * 1024;
      gload16(&Ah[(size_t)(m0 + row) * HH + k0 + scol], (char*)lAh + lbase);
      gload16(&Al[(size_t)(m0 + row) * HH + k0 + scol], (char*)lAl + lbase);
      gload16(&Wb[(size_t)wr * HH + k0 + scol], (char*)lW + lbase);
    }
    __syncthreads();
    bf16x8 ah0 = *(const bf16x8*)&lAh[(w * 32 +  0 + r) * 32 + kg * 8];
    bf16x8 ah1 = *(const bf16x8*)&lAh[(w * 32 + 16 + r) * 32 + kg * 8];
    bf16x8 al0 = *(const bf16x8*)&lAl[(w * 32 +  0 + r) * 32 + kg * 8];
    bf16x8 al1 = *(const bf16x8*)&lAl[(w * 32 + 16 + r) * 32 + kg * 8];
#pragma unroll
    for (int nf = 0; nf < 8; ++nf) {
      bf16x8 wf = *(const bf16x8*)&lW[(nf * 16 + r) * 32 + kg * 8];
      acc[0][nf] = __builtin_amdgcn_mfma_f32_16x16x32_bf16(ah0, wf, acc[0][nf], 0, 0, 0);
      acc[0][nf] = __builtin_amdgcn_mfma_f32_16x16x32_bf16(al0, wf, acc[0][nf], 0, 0, 0);
      acc[1][nf] = __builtin_amdgcn_mfma_f32_16x16x32_bf16(ah1, wf, acc[1][nf], 0, 0, 0);
      acc[1][nf] = __builtin_amdgcn_mfma_f32_16x16x32_bf16(al1, wf, acc[1][nf], 0, 0, 0);
    }
  }
#pragma unroll
  for (int nf = 0; nf < 8; ++nf) {
    const int colv = n0 + nf * 16 + r;
    if (colv < VV) {
      const float bv = bias[colv];
#pragma unroll
      for (int mf = 0; mf < 2; ++mf)
#pragma unroll
        for (int q = 0; q < 4; ++q) {
          const int grow = m0 + w * 32 + mf * 16 + kg * 4 + q;  // = t*64 + b
          const int tt = grow >> 6, b = grow & 63;
          outs[((size_t)b * TT + tt) * VV + colv] = acc[mf][nf][q] + bv;
        }
    }
  }
}

// ---------------------------------------------------------------------------
// Fused h0/c0: grid 64; bid<32 -> h0 (split out), else c0 (f32 out).
// ---------------------------------------------------------------------------
__global__ __launch_bounds__(256) void h0c0_k(
    const short* __restrict__ mfb,
    const short* __restrict__ Wh0b, const float* __restrict__ bh0,
    const short* __restrict__ Wc0b, const float* __restrict__ bc0,
    short* __restrict__ h0H, short* __restrict__ h0L,
    float* __restrict__ cbuf)
{
  const int tid = threadIdx.x;
  const int w = tid >> 6, l = tid & 63;
  const int r = l & 15, kg = l >> 4;
  const bool cpath = blockIdx.x >= 32;
  const int nb = blockIdx.x & 31;
  const short* Wb = cpath ? Wc0b : Wh0b;
  const float* bias = cpath ? bc0 : bh0;
  const int nslice = w >> 1, mbase = (w & 1) * 2;
  const int n0 = nb * 32 + nslice * 16;
  const int nrow = n0 + r;
  const short* wp = Wb + (size_t)nrow * FF + kg * 8;
  const short* ap = mfb + (size_t)(mbase * 16 + r) * FF + kg * 8;
  f32x4 acc[2] = {};
  for (int k0 = 0; k0 < FF; k0 += 32) {
    bf16x8 bf = *(const bf16x8*)(wp + k0);
#pragma unroll
    for (int m = 0; m < 2; ++m) {
      bf16x8 af = *(const bf16x8*)(ap + (size_t)(16 * m) * FF + k0);
      acc[m] = __builtin_amdgcn_mfma_f32_16x16x32_bf16(af, bf, acc[m], 0, 0, 0);
    }
  }
  const float bv = bias[nrow];
#pragma unroll
  for (int m = 0; m < 2; ++m)
#pragma unroll
    for (int q = 0; q < 4; ++q) {
      const int mm = (mbase + m) * 16 + kg * 4 + q;
      const float v = acc[m][q] + bv;
      if (cpath) {
        cbuf[(size_t)mm * HH + nrow] = v;
      } else {
        short hi, lo; split2(v, hi, lo);
        h0H[(size_t)mm * HH + nrow] = hi;
        h0L[(size_t)mm * HH + nrow] = lo;
      }
    }
}

// ---------------------------------------------------------------------------
// Combined transpose+cast: grid (32, 96): y<32 -> att_U, else att_W.
// ---------------------------------------------------------------------------
__global__ __launch_bounds__(256) void transpose2_k(
    const float* __restrict__ attU, short* __restrict__ attUt,
    const float* __restrict__ attW, short* __restrict__ attWt)
{
  __shared__ float tile[32][33];
  const bool isW = blockIdx.y >= 32;
  const float* in = isW ? attW : attU;
  short* out = isW ? attWt : attUt;
  const int R = isW ? FF : HH;
  const int br = (isW ? (blockIdx.y - 32) : blockIdx.y) * 32;
  const int bc = blockIdx.x * 32;
  int tx = threadIdx.x & 31, ty4 = (threadIdx.x >> 5) << 2;
#pragma unroll
  for (int i = 0; i < 4; ++i)
    tile[ty4 + i][tx] = in[(size_t)(br + ty4 + i) * HH + bc + tx];
  __syncthreads();
#pragma unroll
  for (int i = 0; i < 4; ++i)
    out[(size_t)(bc + ty4 + i) * R + br + tx] = (short)bf16_rn(tile[tx][ty4 + i]);
}

// ---------------------------------------------------------------------------
// Fused elementwise prep, 8-wide vectorized.
// ---------------------------------------------------------------------------
#define S_FEATB   6422528ULL                       /* 64*49*2048      */
#define C1  (S_FEATB)
#define C2  (C1 + 12288000ULL)                     /* fc_W 12000*1024 */
#define C3  (C2 + 4194304ULL)                      /* W_hh 4096*1024  */
#define C4  (C3 + 2097152ULL)                      /* Wh0 1024*2048   */
#define C5  (C4 + 2097152ULL)                      /* Wc0 1024*2048   */
#define C6  (C5 + 2621440ULL)                      /* Wxg 4096*640    */
#define C7  (C6 + 8388608ULL)                      /* Wctx 4096*2048  */
#define C8  (C7 + 1310720ULL)                      /* xg 2048*640     */
#define C9  (C8 + 4096ULL)                         /* bg              */
#define C10 (C9 + 131072ULL)                       /* mean 64*2048    */

__global__ __launch_bounds__(256) void prep_k(
    const float* __restrict__ features, const float* __restrict__ fc_W,
    const float* __restrict__ W_hh, const float* __restrict__ Wh0,
    const float* __restrict__ Wc0, const float* __restrict__ W_ih,
    const int* __restrict__ captions, const float* __restrict__ emb,
    const float* __restrict__ cat,
    const float* __restrict__ b_ih, const float* __restrict__ b_hh,
    short* __restrict__ featb, short* __restrict__ fcWb,
    short* __restrict__ Whb, short* __restrict__ Wh0b,
    short* __restrict__ Wc0b, short* __restrict__ Wxg,
    short* __restrict__ Wctxb, short* __restrict__ xgH,
    short* __restrict__ xgL, float* __restrict__ bg,
    short* __restrict__ mfb)
{
  const size_t stride = (size_t)gridDim.x * 256;
  for (size_t ii = (size_t)blockIdx.x * 256 + threadIdx.x; ii < (C10 >> 3);
       ii += stride) {
    const size_t i = ii << 3;
    float f[8];
    if (i < C1) {
      *(float4*)&f[0] = *(const float4*)&features[i];
      *(float4*)&f[4] = *(const float4*)&features[i + 4];
      *(bf16x8*)&featb[i] = cvt8(f);
    } else if (i < C2) {
      const size_t j = i - C1;
      *(float4*)&f[0] = *(const float4*)&fc_W[j];
      *(float4*)&f[4] = *(const float4*)&fc_W[j + 4];
      *(bf16x8*)&fcWb[j] = cvt8(f);
    } else if (i < C3) {
      const size_t j = i - C2;
      *(float4*)&f[0] = *(const float4*)&W_hh[j];
      *(float4*)&f[4] = *(const float4*)&W_hh[j + 4];
      *(bf16x8*)&Whb[j] = cvt8(f);
    } else if (i < C4) {
      const size_t j = i - C3;
      *(float4*)&f[0] = *(const float4*)&Wh0[j];
      *(float4*)&f[4] = *(const float4*)&Wh0[j + 4];
      *(bf16x8*)&Wh0b[j] = cvt8(f);
    } else if (i < C5) {
      const size_t j = i - C4;
      *(float4*)&f[0] = *(const float4*)&Wc0[j];
      *(float4*)&f[4] = *(const float4*)&Wc0[j + 4];
      *(bf16x8*)&Wc0b[j] = cvt8(f);
    } else if (i < C6) {
      const size_t j = i - C5;
      const int n = (int)(j / XGLEN), k = (int)(j % XGLEN);
      const int ks = (k < EE) ? k : (EE + FF + (k - EE));
      const float* src = &W_ih[(size_t)n * XKLEN + ks];
      *(float4*)&f[0] = *(const float4*)&src[0];
      *(float4*)&f[4] = *(const float4*)&src[4];
      *(bf16x8*)&Wxg[j] = cvt8(f);
    } else if (i < C7) {
      const size_t j = i - C6;
      const int n = (int)(j / FF), k = (int)(j % FF);
      const float* src = &W_ih[(size_t)n * XKLEN + EE + k];
      *(float4*)&f[0] = *(const float4*)&src[0];
      *(float4*)&f[4] = *(const float4*)&src[4];
      *(bf16x8*)&Wctxb[j] = cvt8(f);
    } else if (i < C8) {
      const size_t j = i - C7;
      const int row = (int)(j / XGLEN), k = (int)(j % XGLEN);
      const int t = row >> 6, b = row & 63;
      const float* src;
      if (k < EE) {
        const int cap = captions[b * TT + t];
        src = &emb[(size_t)cap * EE + k];
      } else {
        src = &cat[(size_t)b * CDIM + (k - EE)];
      }
      *(float4*)&f[0] = *(const float4*)&src[0];
      *(float4*)&f[4] = *(const float4*)&src[4];
      bf16x8 hi8, lo8;
#pragma unroll
      for (int e = 0; e < 8; ++e) {
        short h, l2; split2(f[e], h, l2);
        hi8[e] = h; lo8[e] = l2;
      }
      *(bf16x8*)&xgH[j] = hi8;
      *(bf16x8*)&xgL[j] = lo8;
    } else if (i < C9) {
      const size_t j = i - C8;
      float4 a0 = *(const float4*)&b_ih[j];
      float4 a1 = *(const float4*)&b_ih[j + 4];
      float4 c0 = *(const float4*)&b_hh[j];
      float4 c1 = *(const float4*)&b_hh[j + 4];
      float4 o0 = make_float4(a0.x + c0.x, a0.y + c0.y, a0.z + c0.z, a0.w + c0.w);
      float4 o1 = make_float4(a1.x + c1.x, a1.y + c1.y, a1.z + c1.z, a1.w + c1.w);
      *(float4*)&bg[j] = o0;
      *(float4*)&bg[j + 4] = o1;
    } else {
      const size_t j = i - C9;
      const int b = (int)(j >> 11), f0 = (int)(j & 2047);
      float s[8] = {};
      for (int l = 0; l < LL; ++l) {
        const float* src = &features[((size_t)b * LL + l) * FF + f0];
        float4 u0 = *(const float4*)&src[0];
        float4 u1 = *(const float4*)&src[4];
        s[0] += u0.x; s[1] += u0.y; s[2] += u0.z; s[3] += u0.w;
        s[4] += u1.x; s[5] += u1.y; s[6] += u1.z; s[7] += u1.w;
      }
#pragma unroll
      for (int e = 0; e < 8; ++e) s[e] *= (1.f / 49.f);
      *(bf16x8*)&mfb[j] = cvt8(s);
    }
  }
}

extern "C" void kernel_launch(void* const* d_in, const int* in_sizes, int n_in,
                              void* d_out, int out_size, void* d_ws, size_t ws_size,
                              hipStream_t stream) {
  const int*   captions = (const int*)  d_in[0];
  const float* features = (const float*)d_in[1];
  const float* category = (const float*)d_in[2];
  const float* emb      = (const float*)d_in[3];
  const float* W_ih     = (const float*)d_in[4];
  const float* b_ih     = (const float*)d_in[5];
  const float* W_hh     = (const float*)d_in[6];
  const float* b_hh     = (const float*)d_in[7];
  const float* fc_W     = (const float*)d_in[8];
  const float* fc_b     = (const float*)d_in[9];
  const float* Wh0      = (const float*)d_in[10];
  const float* bh0      = (const float*)d_in[11];
  const float* Wc0      = (const float*)d_in[12];
  const float* bc0      = (const float*)d_in[13];
  const float* att_W    = (const float*)d_in[14];
  const float* att_U    = (const float*)d_in[15];
  const float* att_v    = (const float*)d_in[16];

  float* outs  = (float*)d_out;
  float* w_out = outs + (size_t)BB * TT * VV;

  char* p = (char*)d_ws;
  auto alloc = [&](size_t bytes) {
    char* q = p; p += (bytes + 255) & ~(size_t)255; return q;
  };
  short* attUt  = (short*)alloc((size_t)HH * HH * 2);
  short* attWt  = (short*)alloc((size_t)HH * FF * 2);
  short* featb  = (short*)alloc((size_t)BB * LL * FF * 2);   // prep only; reused as hall
  short* fcWb   = (short*)alloc((size_t)VV * HH * 2);
  short* Wctxb  = (short*)alloc((size_t)4096 * FF * 2);
  short* Whb    = (short*)alloc((size_t)4096 * HH * 2);
  short* Wxg    = (short*)alloc((size_t)4096 * XGLEN * 2);
  short* Wh0b   = (short*)alloc((size_t)HH * FF * 2);
  short* Wc0b   = (short*)alloc((size_t)HH * FF * 2);
  short* mfb    = (short*)alloc((size_t)BB * FF * 2);
  short* h0H    = (short*)alloc((size_t)BB * HH * 2);
  short* h0L    = (short*)alloc((size_t)BB * HH * 2);
  short* xgH    = (short*)alloc((size_t)2048 * XGLEN * 2);
  short* xgL    = (short*)alloc((size_t)2048 * XGLEN * 2);
  short* featpB = (short*)alloc((size_t)64 * 3136 * 16 * 2); // [nt][3136][16] bf16
  short* featCtx= (short*)alloc((size_t)64 * 3136 * 64 * 2);
  float* gxg    = (float*)alloc((size_t)2048 * 4096 * 4);    // xg@Wxg^T + bg
  float* ghh    = (float*)alloc((size_t)2 * 64 * 4096 * 4);  // h@Whb^T (2 K-partials)
  float* cbuf   = (float*)alloc((size_t)BB * HH * 4);
  float* partS  = (float*)alloc((size_t)64 * 3136 * 4);
  float* bg     = (float*)alloc(4096 * 4);
  // h history (= h(t) for t=0..31) aliases featb (dead after prep GEMMs).
  short* hallH = featb;
  short* hallL = featb + (size_t)TT * BB * HH;

  // ---- one-time prep: 5 dispatches ----
  prep_k<<<2048, 256, 0, stream>>>(
      features, fc_W, W_hh, Wh0, Wc0, W_ih, captions, emb, category,
      b_ih, b_hh,
      featb, fcWb, Whb, Wh0b, Wc0b, Wxg, Wctxb, xgH, xgL, bg, mfb);
  transpose2_k<<<dim3(32, 96), 256, 0, stream>>>(att_U, attUt, att_W, attWt);
  h0c0_k<<<64, 256, 0, stream>>>(mfb, Wh0b, bh0, Wc0b, bc0, h0H, h0L, cbuf);
  tgemm2_k<<<dim3(25, 40), 256, 0, stream>>>(featb, attWt, Wctxb, featpB, featCtx);
  tgemm3_k<<<dim3(16, 32), 256, 0, stream>>>(xgH, xgL, Wxg, bg, gxg);

  // ---- timestep loop: 2 dispatches per step ----
  for (int t = 0; t < TT; ++t) {
    const short* hHi = (t == 0) ? h0H : hallH + (size_t)(t - 1) * BB * HH;
    const short* hLi = (t == 0) ? h0L : hallL + (size_t)(t - 1) * BB * HH;
    step1_k<<<768, 256, 0, stream>>>(
        hHi, hLi, attUt, featpB, att_v, Whb, partS, ghh);
    step2_k<<<256, 256, 0, stream>>>(
        featCtx, partS, ghh, gxg, cbuf,
        hallH + (size_t)t * BB * HH, hallL + (size_t)t * BB * HH, w_out, t);
  }

  // ---- deferred batched fc ----
  bgemm_k<<<dim3(16, 94), 256, 0, stream>>>(hallH, hallL, fcWb, fc_b, outs);
}

// Round 23
// 1458.830 us; speedup vs baseline: 1.4840x; 1.0094x over previous
//
#include <hip/hip_runtime.h>
#include <hip/hip_bf16.h>

#define BB 64
#define TT 32
#define VV 12000
#define EE 512
#define FF 2048
#define CDIM 128
#define HH 1024
#define LL 49
#define XKLEN 2688   /* E + F + C */
#define XGLEN 640    /* E + C : per-step gathered input */

typedef __attribute__((ext_vector_type(8))) short bf16x8;
typedef __attribute__((ext_vector_type(4))) float f32x4;

__device__ __forceinline__ unsigned short bf16_rn(float x) {
  unsigned u = __float_as_uint(x);
  u += 0x7FFFu + ((u >> 16) & 1u);
  return (unsigned short)(u >> 16);
}
__device__ __forceinline__ float bf16_tof(unsigned short h) {
  return __uint_as_float(((unsigned)h) << 16);
}
__device__ __forceinline__ void split2(float x, short& hi, short& lo) {
  unsigned short h = bf16_rn(x);
  float r = x - bf16_tof(h);
  hi = (short)h;
  lo = (short)bf16_rn(r);
}
__device__ __forceinline__ bf16x8 cvt8(const float* f) {
  bf16x8 o;
#pragma unroll
  for (int e = 0; e < 8; ++e) o[e] = (short)bf16_rn(f[e]);
  return o;
}
__device__ __forceinline__ void gload16(const void* g, void* l) {
  __builtin_amdgcn_global_load_lds(
      (const __attribute__((address_space(1))) void*)g,
      (__attribute__((address_space(3))) void*)l, 16, 0, 0);
}
__device__ __forceinline__ float fast_tanh(float x) {
  return 1.f - 2.f / (__expf(2.f * x) + 1.f);
}
__device__ __forceinline__ float fast_sig(float x) {
  return 1.f / (1.f + __expf(-x));
}

// ---------------------------------------------------------------------------
// STEP1 (768 blocks): all halves depend only on h(t-1).
//  blocks 0..255  : hU tile + partial scores -> partS [64 nt][64 b][49 l]
//  blocks 256..767: gates MFMA h@Whb^T (hi/lo, K split 2 blocks x 512)
//                   + LDS reduce -> ghh[2][64][4096]
// ---------------------------------------------------------------------------
__global__ __launch_bounds__(256) void step1_k(
    const short* __restrict__ hHi, const short* __restrict__ hLi,
    const short* __restrict__ attUt,   // [1024][1024] bf16
    const short* __restrict__ featpB,  // [64][3136][16] bf16
    const float* __restrict__ att_v,
    const short* __restrict__ Whb,     // [4096][1024] bf16
    float* __restrict__ partS,         // [64][64][49]
    float* __restrict__ ghh)           // [2][64][4096] f32
{
  __shared__ float red4[4][64][5];
  __shared__ float hu_s[16][17];
  __shared__ float av_s[16];
  __shared__ float red3[3][64][17];
  const int tid = threadIdx.x;
  const int w = tid >> 6, lane = tid & 63;
  const int r = lane & 15, kg = lane >> 4;

  if (blockIdx.x < 256) {
    // ---- hupart half ----
    const int bid = blockIdx.x;
    const int id = (bid & 7) * 32 + (bid >> 3);
    const int nt = id >> 2, mh = id & 3;
    const int kb = w * 256;

    if (tid < 16) av_s[tid] = att_v[nt * 16 + tid];

    const short* wp = attUt + (size_t)(nt * 16 + r) * HH + kb + kg * 8;
    const short* ap = hHi + (size_t)(mh * 16 + r) * HH + kb + kg * 8;
    f32x4 acc = {};
#pragma unroll
    for (int k0 = 0; k0 < 256; k0 += 32) {
      bf16x8 bf = *(const bf16x8*)(wp + k0);
      bf16x8 af = *(const bf16x8*)(ap + k0);
      acc = __builtin_amdgcn_mfma_f32_16x16x32_bf16(af, bf, acc, 0, 0, 0);
    }
#pragma unroll
    for (int q = 0; q < 4; ++q)
      red4[w][lane][q] = acc[q];
    __syncthreads();

    {
      const int bl = tid >> 4, a = tid & 15;
      const int sl = (bl >> 2) * 16 + a;
      const int ii = bl & 3;
      hu_s[bl][a] = red4[0][sl][ii] + red4[1][sl][ii]
                  + red4[2][sl][ii] + red4[3][sl][ii];
    }
    __syncthreads();

    for (int task = tid; task < 16 * LL; task += 256) {
      const int bl = task / LL, l = task - bl * LL;
      const int b = mh * 16 + bl;
      const short* fp = featpB + ((size_t)nt * 3136 + (size_t)b * LL + l) * 16;
      bf16x8 v0 = *(const bf16x8*)&fp[0];
      bf16x8 v1 = *(const bf16x8*)&fp[8];
      float s = 0.f;
#pragma unroll
      for (int a = 0; a < 8; ++a)
        s += fast_tanh(bf16_tof((unsigned short)v0[a]) + hu_s[bl][a]) * av_s[a];
#pragma unroll
      for (int a = 0; a < 8; ++a)
        s += fast_tanh(bf16_tof((unsigned short)v1[a]) + hu_s[bl][8 + a]) * av_s[8 + a];
      partS[(size_t)nt * 3136 + (size_t)mh * 784 + task] = s;
    }
  } else {
    // ---- gates half: ghh[kq] partial of h @ Whb^T (K split 2 x 512) ----
    const int b2 = blockIdx.x - 256;           // 0..511
    const int id = (b2 & 7) * 64 + (b2 >> 3);  // XCD-chunked
    const int nt = id >> 3;
    const int mq = (id >> 1) & 3;
    const int kq = id & 1;
    const int ks = kq * 512;
    const int brow = mq * 16 + r;
    f32x4 acc0 = {}, acc1 = {}, acc2 = {}, acc3 = {};
#pragma unroll
    for (int c = 0; c < 4; ++c) {
      const int hk = ks + (w * 4 + c) * 32;
      const short* a_h = hHi + (size_t)brow * HH + hk + kg * 8;
      const short* a_l = hLi + (size_t)brow * HH + hk + kg * 8;
      const short* w0p = Whb + (size_t)(0 * 1024 + nt * 16 + r) * HH + hk + kg * 8;
      const short* w1p = Whb + (size_t)(1 * 1024 + nt * 16 + r) * HH + hk + kg * 8;
      const short* w2p = Whb + (size_t)(2 * 1024 + nt * 16 + r) * HH + hk + kg * 8;
      const short* w3p = Whb + (size_t)(3 * 1024 + nt * 16 + r) * HH + hk + kg * 8;
      bf16x8 af  = *(const bf16x8*)a_h;
      bf16x8 alf = *(const bf16x8*)a_l;
      bf16x8 b0 = *(const bf16x8*)w0p;
      acc0 = __builtin_amdgcn_mfma_f32_16x16x32_bf16(af,  b0, acc0, 0, 0, 0);
      acc0 = __builtin_amdgcn_mfma_f32_16x16x32_bf16(alf, b0, acc0, 0, 0, 0);
      bf16x8 b1 = *(const bf16x8*)w1p;
      acc1 = __builtin_amdgcn_mfma_f32_16x16x32_bf16(af,  b1, acc1, 0, 0, 0);
      acc1 = __builtin_amdgcn_mfma_f32_16x16x32_bf16(alf, b1, acc1, 0, 0, 0);
      bf16x8 b2v = *(const bf16x8*)w2p;
      acc2 = __builtin_amdgcn_mfma_f32_16x16x32_bf16(af,  b2v, acc2, 0, 0, 0);
      acc2 = __builtin_amdgcn_mfma_f32_16x16x32_bf16(alf, b2v, acc2, 0, 0, 0);
      bf16x8 b3 = *(const bf16x8*)w3p;
      acc3 = __builtin_amdgcn_mfma_f32_16x16x32_bf16(af,  b3, acc3, 0, 0, 0);
      acc3 = __builtin_amdgcn_mfma_f32_16x16x32_bf16(alf, b3, acc3, 0, 0, 0);
    }
    if (w != 0) {
#pragma unroll
      for (int q = 0; q < 4; ++q) {
        red3[w - 1][lane][0 * 4 + q] = acc0[q];
        red3[w - 1][lane][1 * 4 + q] = acc1[q];
        red3[w - 1][lane][2 * 4 + q] = acc2[q];
        red3[w - 1][lane][3 * 4 + q] = acc3[q];
      }
    }
    __syncthreads();
    if (w == 0) {
      const int j = nt * 16 + r;
#pragma unroll
      for (int q = 0; q < 4; ++q) {
        const int b = mq * 16 + kg * 4 + q;
        float g0 = acc0[q], g1 = acc1[q], g2 = acc2[q], g3 = acc3[q];
#pragma unroll
        for (int p = 0; p < 3; ++p) {
          g0 += red3[p][lane][0 * 4 + q];
          g1 += red3[p][lane][1 * 4 + q];
          g2 += red3[p][lane][2 * 4 + q];
          g3 += red3[p][lane][3 * 4 + q];
        }
        float* gh = ghh + (size_t)kq * 64 * 4096 + (size_t)b * 4096;
        gh[0 * 1024 + j] = g0;
        gh[1 * 1024 + j] = g1;
        gh[2 * 1024 + j] = g2;
        gh[3 * 1024 + j] = g3;
      }
    }
  }
}

// ---------------------------------------------------------------------------
// STEP2 (256 blocks): score-sum + softmax + ctx weighted-sum + LSTM epilogue.
// ---------------------------------------------------------------------------
__global__ __launch_bounds__(256) void step2_k(
    const short* __restrict__ featCtx,  // [64][3136][64] bf16
    const float* __restrict__ partS,    // [64 nt][64 b][49 l]
    const float* __restrict__ ghh,      // [2][64][4096]
    const float* __restrict__ gxg,      // [2048][4096] = xg@Wxg^T + bg
    float* __restrict__ cbuf,
    short* __restrict__ hHo, short* __restrict__ hLo,
    float* __restrict__ w_out, int t)
{
  __shared__ float sw[16][52];
  __shared__ float ctx_p[2][16][72];
  const int tid = threadIdx.x;
  const int w = tid >> 6, lane = tid & 63;
  const int bid = blockIdx.x;
  const int id = (bid & 7) * 32 + (bid >> 3);
  const int nt = id >> 2, mq = id & 3;

  for (int idx = tid; idx < 16 * LL; idx += 256) {
    const float* ps = partS + (size_t)mq * 784 + idx;
    float s = 0.f;
#pragma unroll 8
    for (int a = 0; a < 64; ++a) s += ps[(size_t)a * 3136];
    sw[idx / LL][idx % LL] = s;
  }
  __syncthreads();
#pragma unroll
  for (int i = 0; i < 4; ++i) {
    const int bl = w * 4 + i;
    float v = (lane < LL) ? sw[bl][lane] : -1e30f;
    float m = v;
#pragma unroll
    for (int off = 32; off > 0; off >>= 1) m = fmaxf(m, __shfl_xor(m, off));
    float e = (lane < LL) ? __expf(v - m) : 0.f;
    float s = e;
#pragma unroll
    for (int off = 32; off > 0; off >>= 1) s += __shfl_xor(s, off);
    float ww = e / s;
    if (lane < LL) {
      sw[bl][lane] = ww;
      if (nt == 0)
        w_out[((size_t)(mq * 16 + bl) * TT + t) * LL + lane] = ww;
    }
  }
  __syncthreads();

  {
    const int bl = tid >> 4, tsub = tid & 15;
    const int e8 = (tsub & 7) * 8, lpar = tsub >> 3;
    const size_t base =
        ((size_t)nt * 3136 + (size_t)(mq * 16 + bl) * LL) * 64 + e8;
    float s[8] = {};
    for (int l = lpar; l < LL; l += 2) {
      bf16x8 v = *(const bf16x8*)&featCtx[base + (size_t)l * 64];
      const float wl = sw[bl][l];
#pragma unroll
      for (int e = 0; e < 8; ++e)
        s[e] += wl * bf16_tof((unsigned short)v[e]);
    }
#pragma unroll
    for (int e = 0; e < 8; ++e)
      ctx_p[lpar][bl][e8 + e] = s[e];
  }
  __syncthreads();

  {
    const int bl = tid >> 4, jr = tid & 15;
    const int b = mq * 16 + bl;
    const int j = nt * 16 + jr;
    const float* gh0 = ghh + (size_t)b * 4096;
    const float* gh1 = ghh + (size_t)64 * 4096 + (size_t)b * 4096;
    const float* gx = gxg + ((size_t)t * 64 + b) * 4096;
    float gi = gh0[0 * 1024 + j] + gh1[0 * 1024 + j] + gx[0 * 1024 + j]
             + ctx_p[0][bl][0 * 16 + jr] + ctx_p[1][bl][0 * 16 + jr];
    float gf = gh0[1 * 1024 + j] + gh1[1 * 1024 + j] + gx[1 * 1024 + j]
             + ctx_p[0][bl][1 * 16 + jr] + ctx_p[1][bl][1 * 16 + jr];
    float gg = gh0[2 * 1024 + j] + gh1[2 * 1024 + j] + gx[2 * 1024 + j]
             + ctx_p[0][bl][2 * 16 + jr] + ctx_p[1][bl][2 * 16 + jr];
    float go = gh0[3 * 1024 + j] + gh1[3 * 1024 + j] + gx[3 * 1024 + j]
             + ctx_p[0][bl][3 * 16 + jr] + ctx_p[1][bl][3 * 16 + jr];
    float si = fast_sig(gi);
    float sf = fast_sig(gf);
    float so = fast_sig(go);
    const size_t ci = (size_t)b * HH + j;
    float cc = sf * cbuf[ci] + si * fast_tanh(gg);
    float hh = so * fast_tanh(cc);
    cbuf[ci] = cc;
    short hi, lo; split2(hh, hi, lo);
    hHo[ci] = hi;
    hLo[ci] = lo;
  }
}

// ---------------------------------------------------------------------------
// Combined prep GEMMs (one dispatch, all inputs from prep_k):
//  blocks 0..999    : tgemm2 (featpB/featCtx remap GEMM, 128x128, K=2048)
//  blocks 1000..1511: tgemm3 (gxg = xg@Wxg^T + bg, K=640, hi/lo)
//  blocks 1512..1575: h0c0
// ---------------------------------------------------------------------------
__global__ __launch_bounds__(256) void pgemm_k(
    const short* __restrict__ A,       // featb [3136][2048]
    const short* __restrict__ attWt,   // [1024][2048]
    const short* __restrict__ Wctxb,   // [4096][2048]
    short* __restrict__ featpB, short* __restrict__ featCtx,
    const short* __restrict__ xgH, const short* __restrict__ xgL,
    const short* __restrict__ Wxg, const float* __restrict__ bg,
    float* __restrict__ gxg,
    const short* __restrict__ mfb,
    const short* __restrict__ Wh0b, const float* __restrict__ bh0,
    const short* __restrict__ Wc0b, const float* __restrict__ bc0,
    short* __restrict__ h0H, short* __restrict__ h0L,
    float* __restrict__ cbuf)
{
  __shared__ short lAh[128 * 32];
  __shared__ short lAl[128 * 32];
  __shared__ short lW [128 * 32];
  const int tid = threadIdx.x;
  const int w = tid >> 6, lane = tid & 63;
  const int r = lane & 15, kg = lane >> 4;
  const int srow = tid >> 2, scol = (tid & 3) * 8;
  const int bid = blockIdx.x;

  if (bid < 1000) {
    // ---- tgemm2 ----
    const int M = BB * LL, K = FF;
    const int m0 = (bid % 25) * 128;
    const int yy = bid / 25;
    const bool ctx = (yy >= 8);
    const short* Wb = ctx ? Wctxb : attWt;
    const int n0 = (ctx ? (yy - 8) : yy) * 128;

    f32x4 acc[2][8] = {};
    for (int k0 = 0; k0 < K; k0 += 32) {
      __syncthreads();
#pragma unroll
      for (int j = 0; j < 2; ++j) {
        const int row = j * 64 + srow;
        int ar = m0 + row; if (ar >= M) ar = M - 1;
        const size_t lbase = (size_t)j * 4096 + (size_t)w * 1024;
        gload16(&A[(size_t)ar * K + k0 + scol], (char*)lAh + lbase);
        gload16(&Wb[(size_t)(n0 + row) * K + k0 + scol], (char*)lW + lbase);
      }
      __syncthreads();
      bf16x8 a0 = *(const bf16x8*)&lAh[(w * 32 +  0 + r) * 32 + kg * 8];
      bf16x8 a1 = *(const bf16x8*)&lAh[(w * 32 + 16 + r) * 32 + kg * 8];
#pragma unroll
      for (int nf = 0; nf < 8; ++nf) {
        bf16x8 wf = *(const bf16x8*)&lW[(nf * 16 + r) * 32 + kg * 8];
        acc[0][nf] = __builtin_amdgcn_mfma_f32_16x16x32_bf16(a0, wf, acc[0][nf], 0, 0, 0);
        acc[1][nf] = __builtin_amdgcn_mfma_f32_16x16x32_bf16(a1, wf, acc[1][nf], 0, 0, 0);
      }
    }
#pragma unroll
    for (int nf = 0; nf < 8; ++nf) {
      const int col = n0 + nf * 16 + r;
#pragma unroll
      for (int mf = 0; mf < 2; ++mf)
#pragma unroll
        for (int q = 0; q < 4; ++q) {
          const int grow = m0 + w * 32 + mf * 16 + kg * 4 + q;
          if (grow < M) {
            const short v = (short)bf16_rn(acc[mf][nf][q]);
            if (!ctx) {
              const int ntc = col >> 4, aa = col & 15;
              featpB[((size_t)ntc * 3136 + grow) * 16 + aa] = v;
            } else {
              const int gate = col >> 10, ntc = (col >> 4) & 63, jj = col & 15;
              featCtx[((size_t)ntc * 3136 + grow) * 64 + gate * 16 + jj] = v;
            }
          }
        }
    }
  } else if (bid < 1512) {
    // ---- tgemm3: gxg = [xg hi+lo]@Wxg^T + bg ----
    const int b3 = bid - 1000;
    const int m0 = (b3 & 15) * 128;
    const int n0 = (b3 >> 4) * 128;

    f32x4 acc[2][8] = {};
    for (int k0 = 0; k0 < XGLEN; k0 += 32) {
      __syncthreads();
#pragma unroll
      for (int j = 0; j < 2; ++j) {
        const int row = j * 64 + srow;
        const size_t lbase = (size_t)j * 4096 + (size_t)w * 1024;
        gload16(&xgH[(size_t)(m0 + row) * XGLEN + k0 + scol], (char*)lAh + lbase);
        gload16(&xgL[(size_t)(m0 + row) * XGLEN + k0 + scol], (char*)lAl + lbase);
        gload16(&Wxg[(size_t)(n0 + row) * XGLEN + k0 + scol], (char*)lW + lbase);
      }
      __syncthreads();
      bf16x8 ah0 = *(const bf16x8*)&lAh[(w * 32 +  0 + r) * 32 + kg * 8];
      bf16x8 ah1 = *(const bf16x8*)&lAh[(w * 32 + 16 + r) * 32 + kg * 8];
      bf16x8 al0 = *(const bf16x8*)&lAl[(w * 32 +  0 + r) * 32 + kg * 8];
      bf16x8 al1 = *(const bf16x8*)&lAl[(w * 32 + 16 + r) * 32 + kg * 8];
#pragma unroll
      for (int nf = 0; nf < 8; ++nf) {
        bf16x8 wf = *(const bf16x8*)&lW[(nf * 16 + r) * 32 + kg * 8];
        acc[0][nf] = __builtin_amdgcn_mfma_f32_16x16x32_bf16(ah0, wf, acc[0][nf], 0, 0, 0);
        acc[0][nf] = __builtin_amdgcn_mfma_f32_16x16x32_bf16(al0, wf, acc[0][nf], 0, 0, 0);
        acc[1][nf] = __builtin_amdgcn_mfma_f32_16x16x32_bf16(ah1, wf, acc[1][nf], 0, 0, 0);
        acc[1][nf] = __builtin_amdgcn_mfma_f32_16x16x32_bf16(al1, wf, acc[1][nf], 0, 0, 0);
      }
    }
#pragma unroll
    for (int nf = 0; nf < 8; ++nf) {
      const int colv = n0 + nf * 16 + r;
      const float bv = bg[colv];
#pragma unroll
      for (int mf = 0; mf < 2; ++mf)
#pragma unroll
        for (int q = 0; q < 4; ++q) {
          const int grow = m0 + w * 32 + mf * 16 + kg * 4 + q;
          gxg[(size_t)grow * 4096 + colv] = acc[mf][nf][q] + bv;
        }
    }
  } else {
    // ---- h0c0 ----
    const int bh = bid - 1512;
    const bool cpath = bh >= 32;
    const int nb = bh & 31;
    const short* Wb = cpath ? Wc0b : Wh0b;
    const float* bias = cpath ? bc0 : bh0;
    const int nslice = w >> 1, mbase = (w & 1) * 2;
    const int n0 = nb * 32 + nslice * 16;
    const int nrow = n0 + r;
    const short* wp = Wb + (size_t)nrow * FF + kg * 8;
    const short* ap = mfb + (size_t)(mbase * 16 + r) * FF + kg * 8;
    f32x4 acc[2] = {};
    for (int k0 = 0; k0 < FF; k0 += 32) {
      bf16x8 bf = *(const bf16x8*)(wp + k0);
#pragma unroll
      for (int m = 0; m < 2; ++m) {
        bf16x8 af = *(const bf16x8*)(ap + (size_t)(16 * m) * FF + k0);
        acc[m] = __builtin_amdgcn_mfma_f32_16x16x32_bf16(af, bf, acc[m], 0, 0, 0);
      }
    }
    const float bv = bias[nrow];
#pragma unroll
    for (int m = 0; m < 2; ++m)
#pragma unroll
      for (int q = 0; q < 4; ++q) {
        const int mm = (mbase + m) * 16 + kg * 4 + q;
        const float v = acc[m][q] + bv;
        if (cpath) {
          cbuf[(size_t)mm * HH + nrow] = v;
        } else {
          short hi, lo; split2(v, hi, lo);
          h0H[(size_t)mm * HH + nrow] = hi;
          h0L[(size_t)mm * HH + nrow] = lo;
        }
      }
  }
}

// ---------------------------------------------------------------------------
// Batched fc GEMM (global_load_lds staging, linear LDS). Grid (16, 94).
// ---------------------------------------------------------------------------
__global__ __launch_bounds__(256) void bgemm_k(
    const short* __restrict__ Ah, const short* __restrict__ Al,
    const short* __restrict__ Wb, const float* __restrict__ bias,
    float* __restrict__ outs)
{
  __shared__ short lAh[128 * 32];
  __shared__ short lAl[128 * 32];
  __shared__ short lW [128 * 32];
  const int tid = threadIdx.x;
  const int w = tid >> 6, lane = tid & 63;
  const int r = lane & 15, kg = lane >> 4;
  const int m0 = blockIdx.x * 128;
  const int n0 = blockIdx.y * 128;
  const int srow = tid >> 2, scol = (tid & 3) * 8;

  f32x4 acc[2][8] = {};
  for (int k0 = 0; k0 < HH; k0 += 32) {
    __syncthreads();
#pragma unroll
    for (int j = 0; j < 2; ++j) {
      const int row = j * 64 + srow;
      int wr = n0 + row; if (wr >= VV) wr = VV - 1;
      const size_t lbase = (size_t)j * 4096 + (size_t)w * 1024;
      gload16(&Ah[(size_t)(m0 + row) * HH + k0 + scol], (char*)lAh + lbase);
      gload16(&Al[(size_t)(m0 + row) * HH + k0 + scol], (char*)lAl + lbase);
      gload16(&Wb[(size_t)wr * HH + k0 + scol], (char*)lW + lbase);
    }
    __syncthreads();
    bf16x8 ah0 = *(const bf16x8*)&lAh[(w * 32 +  0 + r) * 32 + kg * 8];
    bf16x8 ah1 = *(const bf16x8*)&lAh[(w * 32 + 16 + r) * 32 + kg * 8];
    bf16x8 al0 = *(const bf16x8*)&lAl[(w * 32 +  0 + r) * 32 + kg * 8];
    bf16x8 al1 = *(const bf16x8*)&lAl[(w * 32 + 16 + r) * 32 + kg * 8];
#pragma unroll
    for (int nf = 0; nf < 8; ++nf) {
      bf16x8 wf = *(const bf16x8*)&lW[(nf * 16 + r) * 32 + kg * 8];
      acc[0][nf] = __builtin_amdgcn_mfma_f32_16x16x32_bf16(ah0, wf, acc[0][nf], 0, 0, 0);
      acc[0][nf] = __builtin_amdgcn_mfma_f32_16x16x32_bf16(al0, wf, acc[0][nf], 0, 0, 0);
      acc[1][nf] = __builtin_amdgcn_mfma_f32_16x16x32_bf16(ah1, wf, acc[1][nf], 0, 0, 0);
      acc[1][nf] = __builtin_amdgcn_mfma_f32_16x16x32_bf16(al1, wf, acc[1][nf], 0, 0, 0);
    }
  }
#pragma unroll
  for (int nf = 0; nf < 8; ++nf) {
    const int colv = n0 + nf * 16 + r;
    if (colv < VV) {
      const float bv = bias[colv];
#pragma unroll
      for (int mf = 0; mf < 2; ++mf)
#pragma unroll
        for (int q = 0; q < 4; ++q) {
          const int grow = m0 + w * 32 + mf * 16 + kg * 4 + q;  // = t*64 + b
          const int tt = grow >> 6, b = grow & 63;
          outs[((size_t)b * TT + tt) * VV + colv] = acc[mf][nf][q] + bv;
        }
    }
  }
}

// ---------------------------------------------------------------------------
// Fused elementwise prep + weight transposes.
//  blocks 0..3071   : 32x32 transpose tiles (attU: 1024 tiles, attW: 2048)
//  blocks 3072..    : 8-wide grid-stride elementwise
// ---------------------------------------------------------------------------
#define S_FEATB   6422528ULL                       /* 64*49*2048      */
#define C1  (S_FEATB)
#define C2  (C1 + 12288000ULL)                     /* fc_W 12000*1024 */
#define C3  (C2 + 4194304ULL)                      /* W_hh 4096*1024  */
#define C4  (C3 + 2097152ULL)                      /* Wh0 1024*2048   */
#define C5  (C4 + 2097152ULL)                      /* Wc0 1024*2048   */
#define C6  (C5 + 2621440ULL)                      /* Wxg 4096*640    */
#define C7  (C6 + 8388608ULL)                      /* Wctx 4096*2048  */
#define C8  (C7 + 1310720ULL)                      /* xg 2048*640     */
#define C9  (C8 + 4096ULL)                         /* bg              */
#define C10 (C9 + 131072ULL)                       /* mean 64*2048    */

__global__ __launch_bounds__(256) void prep_k(
    const float* __restrict__ features, const float* __restrict__ fc_W,
    const float* __restrict__ W_hh, const float* __restrict__ Wh0,
    const float* __restrict__ Wc0, const float* __restrict__ W_ih,
    const int* __restrict__ captions, const float* __restrict__ emb,
    const float* __restrict__ cat,
    const float* __restrict__ b_ih, const float* __restrict__ b_hh,
    const float* __restrict__ attU, const float* __restrict__ attW,
    short* __restrict__ attUt, short* __restrict__ attWt,
    short* __restrict__ featb, short* __restrict__ fcWb,
    short* __restrict__ Whb, short* __restrict__ Wh0b,
    short* __restrict__ Wc0b, short* __restrict__ Wxg,
    short* __restrict__ Wctxb, short* __restrict__ xgH,
    short* __restrict__ xgL, float* __restrict__ bg,
    short* __restrict__ mfb)
{
  __shared__ float tile[32][33];
  if (blockIdx.x < 3072) {
    // ---- transpose tiles ----
    const int tb = blockIdx.x;
    const int by = tb >> 5;                 // 0..95
    const bool isW = by >= 32;
    const float* in = isW ? attW : attU;
    short* out = isW ? attWt : attUt;
    const int R = isW ? FF : HH;
    const int br = (isW ? (by - 32) : by) * 32;
    const int bc = (tb & 31) * 32;
    int tx = threadIdx.x & 31, ty4 = (threadIdx.x >> 5) << 2;
#pragma unroll
    for (int i = 0; i < 4; ++i)
      tile[ty4 + i][tx] = in[(size_t)(br + ty4 + i) * HH + bc + tx];
    __syncthreads();
#pragma unroll
    for (int i = 0; i < 4; ++i)
      out[(size_t)(bc + ty4 + i) * R + br + tx] = (short)bf16_rn(tile[tx][ty4 + i]);
    return;
  }
  const size_t nblk = gridDim.x - 3072;
  const size_t stride = nblk * 256;
  for (size_t ii = (size_t)(blockIdx.x - 3072) * 256 + threadIdx.x;
       ii < (C10 >> 3); ii += stride) {
    const size_t i = ii << 3;
    float f[8];
    if (i < C1) {
      *(float4*)&f[0] = *(const float4*)&features[i];
      *(float4*)&f[4] = *(const float4*)&features[i + 4];
      *(bf16x8*)&featb[i] = cvt8(f);
    } else if (i < C2) {
      const size_t j = i - C1;
      *(float4*)&f[0] = *(const float4*)&fc_W[j];
      *(float4*)&f[4] = *(const float4*)&fc_W[j + 4];
      *(bf16x8*)&fcWb[j] = cvt8(f);
    } else if (i < C3) {
      const size_t j = i - C2;
      *(float4*)&f[0] = *(const float4*)&W_hh[j];
      *(float4*)&f[4] = *(const float4*)&W_hh[j + 4];
      *(bf16x8*)&Whb[j] = cvt8(f);
    } else if (i < C4) {
      const size_t j = i - C3;
      *(float4*)&f[0] = *(const float4*)&Wh0[j];
      *(float4*)&f[4] = *(const float4*)&Wh0[j + 4];
      *(bf16x8*)&Wh0b[j] = cvt8(f);
    } else if (i < C5) {
      const size_t j = i - C4;
      *(float4*)&f[0] = *(const float4*)&Wc0[j];
      *(float4*)&f[4] = *(const float4*)&Wc0[j + 4];
      *(bf16x8*)&Wc0b[j] = cvt8(f);
    } else if (i < C6) {
      const size_t j = i - C5;
      const int n = (int)(j / XGLEN), k = (int)(j % XGLEN);
      const int ks = (k < EE) ? k : (EE + FF + (k - EE));
      const float* src = &W_ih[(size_t)n * XKLEN + ks];
      *(float4*)&f[0] = *(const float4*)&src[0];
      *(float4*)&f[4] = *(const float4*)&src[4];
      *(bf16x8*)&Wxg[j] = cvt8(f);
    } else if (i < C7) {
      const size_t j = i - C6;
      const int n = (int)(j / FF), k = (int)(j % FF);
      const float* src = &W_ih[(size_t)n * XKLEN + EE + k];
      *(float4*)&f[0] = *(const float4*)&src[0];
      *(float4*)&f[4] = *(const float4*)&src[4];
      *(bf16x8*)&Wctxb[j] = cvt8(f);
    } else if (i < C8) {
      const size_t j = i - C7;
      const int row = (int)(j / XGLEN), k = (int)(j % XGLEN);
      const int t = row >> 6, b = row & 63;
      const float* src;
      if (k < EE) {
        const int cap = captions[b * TT + t];
        src = &emb[(size_t)cap * EE + k];
      } else {
        src = &cat[(size_t)b * CDIM + (k - EE)];
      }
      *(float4*)&f[0] = *(const float4*)&src[0];
      *(float4*)&f[4] = *(const float4*)&src[4];
      bf16x8 hi8, lo8;
#pragma unroll
      for (int e = 0; e < 8; ++e) {
        short h, l2; split2(f[e], h, l2);
        hi8[e] = h; lo8[e] = l2;
      }
      *(bf16x8*)&xgH[j] = hi8;
      *(bf16x8*)&xgL[j] = lo8;
    } else if (i < C9) {
      const size_t j = i - C8;
      float4 a0 = *(const float4*)&b_ih[j];
      float4 a1 = *(const float4*)&b_ih[j + 4];
      float4 c0 = *(const float4*)&b_hh[j];
      float4 c1 = *(const float4*)&b_hh[j + 4];
      float4 o0 = make_float4(a0.x + c0.x, a0.y + c0.y, a0.z + c0.z, a0.w + c0.w);
      float4 o1 = make_float4(a1.x + c1.x, a1.y + c1.y, a1.z + c1.z, a1.w + c1.w);
      *(float4*)&bg[j] = o0;
      *(float4*)&bg[j + 4] = o1;
    } else {
      const size_t j = i - C9;
      const int b = (int)(j >> 11), f0 = (int)(j & 2047);
      float s[8] = {};
      for (int l = 0; l < LL; ++l) {
        const float* src = &features[((size_t)b * LL + l) * FF + f0];
        float4 u0 = *(const float4*)&src[0];
        float4 u1 = *(const float4*)&src[4];
        s[0] += u0.x; s[1] += u0.y; s[2] += u0.z; s[3] += u0.w;
        s[4] += u1.x; s[5] += u1.y; s[6] += u1.z; s[7] += u1.w;
      }
#pragma unroll
      for (int e = 0; e < 8; ++e) s[e] *= (1.f / 49.f);
      *(bf16x8*)&mfb[j] = cvt8(s);
    }
  }
}

extern "C" void kernel_launch(void* const* d_in, const int* in_sizes, int n_in,
                              void* d_out, int out_size, void* d_ws, size_t ws_size,
                              hipStream_t stream) {
  const int*   captions = (const int*)  d_in[0];
  const float* features = (const float*)d_in[1];
  const float* category = (const float*)d_in[2];
  const float* emb      = (const float*)d_in[3];
  const float* W_ih     = (const float*)d_in[4];
  const float* b_ih     = (const float*)d_in[5];
  const float* W_hh     = (const float*)d_in[6];
  const float* b_hh     = (const float*)d_in[7];
  const float* fc_W     = (const float*)d_in[8];
  const float* fc_b     = (const float*)d_in[9];
  const float* Wh0      = (const float*)d_in[10];
  const float* bh0      = (const float*)d_in[11];
  const float* Wc0      = (const float*)d_in[12];
  const float* bc0      = (const float*)d_in[13];
  const float* att_W    = (const float*)d_in[14];
  const float* att_U    = (const float*)d_in[15];
  const float* att_v    = (const float*)d_in[16];

  float* outs  = (float*)d_out;
  float* w_out = outs + (size_t)BB * TT * VV;

  char* p = (char*)d_ws;
  auto alloc = [&](size_t bytes) {
    char* q = p; p += (bytes + 255) & ~(size_t)255; return q;
  };
  short* attUt  = (short*)alloc((size_t)HH * HH * 2);
  short* attWt  = (short*)alloc((size_t)HH * FF * 2);
  short* featb  = (short*)alloc((size_t)BB * LL * FF * 2);   // prep only; reused as hall
  short* fcWb   = (short*)alloc((size_t)VV * HH * 2);
  short* Wctxb  = (short*)alloc((size_t)4096 * FF * 2);
  short* Whb    = (short*)alloc((size_t)4096 * HH * 2);
  short* Wxg    = (short*)alloc((size_t)4096 * XGLEN * 2);
  short* Wh0b   = (short*)alloc((size_t)HH * FF * 2);
  short* Wc0b   = (short*)alloc((size_t)HH * FF * 2);
  short* mfb    = (short*)alloc((size_t)BB * FF * 2);
  short* h0H    = (short*)alloc((size_t)BB * HH * 2);
  short* h0L    = (short*)alloc((size_t)BB * HH * 2);
  short* xgH    = (short*)alloc((size_t)2048 * XGLEN * 2);
  short* xgL    = (short*)alloc((size_t)2048 * XGLEN * 2);
  short* featpB = (short*)alloc((size_t)64 * 3136 * 16 * 2); // [nt][3136][16] bf16
  short* featCtx= (short*)alloc((size_t)64 * 3136 * 64 * 2);
  float* gxg    = (float*)alloc((size_t)2048 * 4096 * 4);    // xg@Wxg^T + bg
  float* ghh    = (float*)alloc((size_t)2 * 64 * 4096 * 4);  // h@Whb^T (2 K-partials)
  float* cbuf   = (float*)alloc((size_t)BB * HH * 4);
  float* partS  = (float*)alloc((size_t)64 * 3136 * 4);
  float* bg     = (float*)alloc(4096 * 4);
  // h history (= h(t) for t=0..31) aliases featb (dead after prep GEMMs).
  short* hallH = featb;
  short* hallL = featb + (size_t)TT * BB * HH;

  // ---- one-time prep: 2 dispatches ----
  prep_k<<<5120, 256, 0, stream>>>(
      features, fc_W, W_hh, Wh0, Wc0, W_ih, captions, emb, category,
      b_ih, b_hh, att_U, att_W, attUt, attWt,
      featb, fcWb, Whb, Wh0b, Wc0b, Wxg, Wctxb, xgH, xgL, bg, mfb);
  pgemm_k<<<1576, 256, 0, stream>>>(
      featb, attWt, Wctxb, featpB, featCtx,
      xgH, xgL, Wxg, bg, gxg,
      mfb, Wh0b, bh0, Wc0b, bc0, h0H, h0L, cbuf);

  // ---- timestep loop: 2 dispatches per step ----
  for (int t = 0; t < TT; ++t) {
    const short* hHi = (t == 0) ? h0H : hallH + (size_t)(t - 1) * BB * HH;
    const short* hLi = (t == 0) ? h0L : hallL + (size_t)(t - 1) * BB * HH;
    step1_k<<<768, 256, 0, stream>>>(
        hHi, hLi, attUt, featpB, att_v, Whb, partS, ghh);
    step2_k<<<256, 256, 0, stream>>>(
        featCtx, partS, ghh, gxg, cbuf,
        hallH + (size_t)t * BB * HH, hallL + (size_t)t * BB * HH, w_out, t);
  }

  // ---- deferred batched fc ----
  bgemm_k<<<dim3(16, 94), 256, 0, stream>>>(hallH, hallL, fcWb, fc_b, outs);
}